// Round 8
// baseline (1334.451 us; speedup 1.0000x reference)
//
#include <hip/hip_runtime.h>
#include <hip/hip_bf16.h>

#define NN 100000
#define NE 1600000
#define DIN 1000
#define BN_EPS 1e-3f
#define NB 391   // ceil(NN/256)

// output element offsets (concat of z, mu, logvar, de_feat, q, feat_x, gnn_z) — float32 out
#define OZ  ((size_t)0)
#define OMU ((size_t)NN*80)
#define OLV ((size_t)NN*96)
#define ODE ((size_t)NN*112)
#define OQ  ((size_t)NN*1112)
#define OFX ((size_t)NN*1127)
#define OGZ ((size_t)NN*1191)

typedef __attribute__((ext_vector_type(8))) short short8v;   // 8 bf16 (4 VGPRs)
typedef __attribute__((ext_vector_type(4))) float f32x4;     // MFMA accumulator

__device__ __forceinline__ float elu_f(float x) { return x > 0.f ? x : expf(x) - 1.f; }

// fp32 -> bf16 bits, round-to-nearest-even
__device__ __forceinline__ short f2bf(float f) {
    union { float f; unsigned u; } c; c.f = f;
    unsigned r = c.u + 0x7fffu + ((c.u >> 16) & 1u);
    return (short)(r >> 16);
}

// Edge index may arrive as int32 or int64; logical element idx in flat (2*E) array.
__device__ __forceinline__ int edge_at(const void* ei, int is64, size_t idx) {
    if (is64) return (int)((const long long*)ei)[idx];
    return ((const int*)ei)[idx];
}

// ---------------- dtype detection ----------------
__global__ __launch_bounds__(256) void k_detect(const int* __restrict__ ei, int* __restrict__ flag) {
    __shared__ int nz;
    if (threadIdx.x == 0) nz = 0;
    __syncthreads();
    for (int i = threadIdx.x; i < 2048; i += 256)
        if (ei[2 * i + 1] != 0) nz = 1;
    __syncthreads();
    if (threadIdx.x == 0) flag[0] = (nz == 0) ? 1 : 0;  // 1 => int64
}

// ---------------- degree ----------------
__global__ __launch_bounds__(256) void k_deg_init(float* __restrict__ deg) {
    int i = blockIdx.x * 256 + threadIdx.x;
    if (i < NN) deg[i] = 1.0f;
}

__global__ __launch_bounds__(256) void k_deg_accum(const void* __restrict__ ei, const int* __restrict__ flag,
                                                   float* __restrict__ deg) {
    const int is64 = flag[0];
    int e = blockIdx.x * 256 + threadIdx.x;
    if (e < NE) atomicAdd(&deg[edge_at(ei, is64, (size_t)NE + e)], 1.0f);
}

// ---------------- CSR build: exclusive scan of in-edge counts ----------------
__global__ __launch_bounds__(256) void k_scan1(const float* __restrict__ deg, int* __restrict__ off,
                                               int* __restrict__ bsum, int* __restrict__ cursor) {
    __shared__ int s[256];
    const int t = threadIdx.x;
    const int i = blockIdx.x * 256 + t;
    const int vv = (i < NN) ? ((int)deg[i]) - 1 : 0;
    if (i < NN) cursor[i] = 0;
    s[t] = vv;
    __syncthreads();
    for (int d = 1; d < 256; d <<= 1) {
        const int u = (t >= d) ? s[t - d] : 0;
        __syncthreads();
        s[t] += u;
        __syncthreads();
    }
    if (i < NN) off[i] = s[t] - vv;           // exclusive, pre-block-offset
    if (t == 255) bsum[blockIdx.x] = s[t];    // block total
}

__global__ __launch_bounds__(512) void k_scan2(int* __restrict__ bsum) {
    __shared__ int s[512];
    const int t = threadIdx.x;
    const int vv = (t < NB) ? bsum[t] : 0;
    s[t] = vv;
    __syncthreads();
    for (int d = 1; d < 512; d <<= 1) {
        const int u = (t >= d) ? s[t - d] : 0;
        __syncthreads();
        s[t] += u;
        __syncthreads();
    }
    if (t < NB) bsum[t] = s[t] - vv;          // exclusive block prefix
}

__global__ __launch_bounds__(256) void k_scan3(int* __restrict__ off, const int* __restrict__ bsum) {
    const int i = blockIdx.x * 256 + threadIdx.x;
    if (i < NN) off[i] += bsum[blockIdx.x];
}

__global__ __launch_bounds__(256) void k_fill(const void* __restrict__ ei, const int* __restrict__ flag,
                                              const float* __restrict__ deg, const int* __restrict__ off,
                                              int* __restrict__ cursor,
                                              int* __restrict__ csr_src, float* __restrict__ csr_w) {
    const int is64 = flag[0];
    const int e = blockIdx.x * 256 + threadIdx.x;
    if (e >= NE) return;
    const int r = edge_at(ei, is64, e);
    const int c = edge_at(ei, is64, (size_t)NE + e);
    const float w = rsqrtf(deg[r]) * rsqrtf(deg[c]);
    const int p = atomicAdd(&cursor[c], 1);
    const int slot = off[c] + p;
    csr_src[slot] = r;
    csr_w[slot] = w;
}

// ---------------- weight transpose+convert: enc0 w[1000][256] f32 -> wt[256][1024] bf16 (K zero-padded) ----------------
__global__ __launch_bounds__(256) void k_wt(const float* __restrict__ w, short* __restrict__ wt) {
    const int tid = blockIdx.x * 256 + threadIdx.x;   // 256*1024 elements
    const int c = tid >> 10;
    const int k = tid & 1023;
    wt[(size_t)c * 1024 + k] = (k < DIN) ? f2bf(w[(size_t)k * 256 + c]) : (short)0;
}

// ---------------- weight transpose+convert: dec1 w[64][1000] f32 -> wt2[1024][64] bf16 (cols zero-padded) ----------------
__global__ __launch_bounds__(256) void k_wt2(const float* __restrict__ w, short* __restrict__ wt2) {
    const int tid = blockIdx.x * 256 + threadIdx.x;   // 1024*64 elements
    const int c = tid >> 6;
    const int k = tid & 63;
    wt2[(size_t)c * 64 + k] = (c < DIN) ? f2bf(w[(size_t)k * DIN + c]) : (short)0;
}

// ---------------- encoder L0 via MFMA: h1 = ELU(BN(x @ w)) ----------------
// Block tile 128x128, 4 waves 2x2, wave tile 64x64 (4x4 frags of 16x16), K_STEP=32.
__global__ __launch_bounds__(256, 2) void k_enc0_mfma(
    const float* __restrict__ x, const short* __restrict__ wt, const float* __restrict__ bias,
    const float* __restrict__ g, const float* __restrict__ bb,
    const float* __restrict__ m, const float* __restrict__ v,
    float* __restrict__ h1)
{
    __shared__ short As[4 * 128 * 8];
    __shared__ short Bs[4 * 128 * 8];
    const int t = threadIdx.x;
    const int lane = t & 63;
    const int wave = t >> 6;
    const int wm = (wave >> 1) * 64;
    const int wn = (wave & 1) * 64;
    const int row0 = blockIdx.x * 128;
    const int col0 = blockIdx.y * 128;

    f32x4 acc[4][4];
    #pragma unroll
    for (int mi = 0; mi < 4; ++mi)
        #pragma unroll
        for (int ni = 0; ni < 4; ++ni)
            acc[mi][ni] = (f32x4){0.f, 0.f, 0.f, 0.f};

    const int srow = t >> 1;     // 0..127
    const int skc2 = t & 1;      // k-half: offset 16*skc2
    const bool arow_ok = (row0 + srow) < NN;
    const float* xrow = x + (size_t)(row0 + srow) * DIN;
    const short* wtrow = wt + (size_t)(col0 + srow) * 1024;

    const int kc = lane >> 4;    // 0..3
    const int lr = lane & 15;

    for (int ks = 0; ks < 32; ++ks) {
        const int k0 = ks * 32;
        __syncthreads();
        // ---- stage A (x -> bf16), 16 k per thread ----
        {
            short tmp[16];
            const int kbase = k0 + skc2 * 16;
            if (arow_ok) {
                if (kbase + 16 <= DIN) {
                    #pragma unroll
                    for (int q = 0; q < 4; ++q) {
                        const float4 fv = *reinterpret_cast<const float4*>(xrow + kbase + q * 4);
                        tmp[q * 4 + 0] = f2bf(fv.x);
                        tmp[q * 4 + 1] = f2bf(fv.y);
                        tmp[q * 4 + 2] = f2bf(fv.z);
                        tmp[q * 4 + 3] = f2bf(fv.w);
                    }
                } else {
                    #pragma unroll
                    for (int j = 0; j < 16; ++j) {
                        const int k = kbase + j;
                        tmp[j] = (k < DIN) ? f2bf(xrow[k]) : (short)0;
                    }
                }
            } else {
                #pragma unroll
                for (int j = 0; j < 16; ++j) tmp[j] = 0;
            }
            short8v p0, p1;
            #pragma unroll
            for (int j = 0; j < 8; ++j) { p0[j] = tmp[j]; p1[j] = tmp[8 + j]; }
            *reinterpret_cast<short8v*>(&As[((skc2 * 2 + 0) * 128 + srow) * 8]) = p0;
            *reinterpret_cast<short8v*>(&As[((skc2 * 2 + 1) * 128 + srow) * 8]) = p1;
        }
        // ---- stage B (wt already bf16, K padded) ----
        {
            const short8v g0 = *reinterpret_cast<const short8v*>(wtrow + k0 + skc2 * 16);
            const short8v g1 = *reinterpret_cast<const short8v*>(wtrow + k0 + skc2 * 16 + 8);
            *reinterpret_cast<short8v*>(&Bs[((skc2 * 2 + 0) * 128 + srow) * 8]) = g0;
            *reinterpret_cast<short8v*>(&Bs[((skc2 * 2 + 1) * 128 + srow) * 8]) = g1;
        }
        __syncthreads();
        // ---- fragments + MFMA ----
        short8v a[4], b[4];
        #pragma unroll
        for (int mi = 0; mi < 4; ++mi)
            a[mi] = *reinterpret_cast<const short8v*>(&As[(kc * 128 + wm + mi * 16 + lr) * 8]);
        #pragma unroll
        for (int ni = 0; ni < 4; ++ni)
            b[ni] = *reinterpret_cast<const short8v*>(&Bs[(kc * 128 + wn + ni * 16 + lr) * 8]);
        #pragma unroll
        for (int mi = 0; mi < 4; ++mi)
            #pragma unroll
            for (int ni = 0; ni < 4; ++ni)
                acc[mi][ni] = __builtin_amdgcn_mfma_f32_16x16x32_bf16(a[mi], b[ni], acc[mi][ni], 0, 0, 0);
    }

    // ---- epilogue: BN + ELU, C/D layout col=lane&15, row=(lane>>4)*4+reg ----
    float sc[4], sh[4];
    int cols[4];
    #pragma unroll
    for (int ni = 0; ni < 4; ++ni) {
        const int col = col0 + wn + ni * 16 + lr;
        cols[ni] = col;
        const float s = rsqrtf(v[col] + BN_EPS) * g[col];
        sc[ni] = s;
        sh[ni] = (bias[col] - m[col]) * s + bb[col];
    }
    #pragma unroll
    for (int mi = 0; mi < 4; ++mi) {
        #pragma unroll
        for (int j = 0; j < 4; ++j) {
            const int row = row0 + wm + mi * 16 + (lane >> 4) * 4 + j;
            if (row < NN) {
                #pragma unroll
                for (int ni = 0; ni < 4; ++ni) {
                    const float y = acc[mi][ni][j] * sc[ni] + sh[ni];
                    h1[(size_t)row * 256 + cols[ni]] = elu_f(y);
                }
            }
        }
    }
}

// ---------------- encoder L1: h1[N,256] @ w[256,64] + BN + ELU -> feat, out ----------------
__global__ __launch_bounds__(256) void k_enc1(
    const float* __restrict__ h1, const float* __restrict__ w, const float* __restrict__ bias,
    const float* __restrict__ g, const float* __restrict__ bb,
    const float* __restrict__ m, const float* __restrict__ v,
    float* __restrict__ feat, float* __restrict__ out)
{
    __shared__ float hs[32 * 256];
    const int t = threadIdx.x;
    const int row0 = blockIdx.x * 32;
    const int j0 = t & 31;
    const int r0 = (t >> 5) * 4;
    float acc[4][2] = {};
    for (int idx = t; idx < 2048; idx += 256) {
        const int r = idx >> 6, c4 = idx & 63;
        *reinterpret_cast<float4*>(&hs[r * 256 + c4 * 4]) =
            *reinterpret_cast<const float4*>(&h1[(size_t)(row0 + r) * 256 + c4 * 4]);
    }
    __syncthreads();
    #pragma unroll 1
    for (int k = 0; k < 256; k += 4) {
        float wv[4][2];
        #pragma unroll
        for (int kk = 0; kk < 4; ++kk) {
            wv[kk][0] = w[(k + kk) * 64 + j0];
            wv[kk][1] = w[(k + kk) * 64 + j0 + 32];
        }
        #pragma unroll
        for (int r = 0; r < 4; ++r) {
            const float4 xv = *reinterpret_cast<const float4*>(&hs[(r0 + r) * 256 + k]);
            const float xa[4] = {xv.x, xv.y, xv.z, xv.w};
            #pragma unroll
            for (int kk = 0; kk < 4; ++kk) {
                acc[r][0] = fmaf(xa[kk], wv[kk][0], acc[r][0]);
                acc[r][1] = fmaf(xa[kk], wv[kk][1], acc[r][1]);
            }
        }
    }
    #pragma unroll
    for (int c = 0; c < 2; ++c) {
        const int j = j0 + 32 * c;
        const float sc = rsqrtf(v[j] + BN_EPS) * g[j];
        const float sh = (bias[j] - m[j]) * sc + bb[j];
        #pragma unroll
        for (int r = 0; r < 4; ++r) {
            const size_t rowi = row0 + r0 + r;
            const float y = elu_f(acc[r][c] * sc + sh);
            feat[rowi * 64 + j] = y;
            out[OFX + rowi * 64 + j] = y;
            out[OZ + rowi * 80 + j] = y;
        }
    }
}

// ---------------- GCN projection: feat[N,64] @ conv_w[64,128] -> hc ----------------
__global__ __launch_bounds__(256) void k_conv_proj(
    const float* __restrict__ feat, const float* __restrict__ w,
    float* __restrict__ hc)
{
    __shared__ float fs[32 * 64];
    const int t = threadIdx.x;
    const int row0 = blockIdx.x * 32;
    const int j0 = t & 63;
    const int r0 = (t >> 6) * 8;
    float acc[8][2] = {};
    for (int idx = t; idx < 512; idx += 256) {
        const int r = idx >> 4, c4 = idx & 15;
        *reinterpret_cast<float4*>(&fs[r * 64 + c4 * 4]) =
            *reinterpret_cast<const float4*>(&feat[(size_t)(row0 + r) * 64 + c4 * 4]);
    }
    __syncthreads();
    #pragma unroll 1
    for (int k = 0; k < 64; k += 4) {
        float wv[4][2];
        #pragma unroll
        for (int kk = 0; kk < 4; ++kk) {
            wv[kk][0] = w[(k + kk) * 128 + j0];
            wv[kk][1] = w[(k + kk) * 128 + j0 + 64];
        }
        #pragma unroll
        for (int r = 0; r < 8; ++r) {
            const float4 xv = *reinterpret_cast<const float4*>(&fs[(r0 + r) * 64 + k]);
            const float xa[4] = {xv.x, xv.y, xv.z, xv.w};
            #pragma unroll
            for (int kk = 0; kk < 4; ++kk) {
                acc[r][0] = fmaf(xa[kk], wv[kk][0], acc[r][0]);
                acc[r][1] = fmaf(xa[kk], wv[kk][1], acc[r][1]);
            }
        }
    }
    #pragma unroll
    for (int r = 0; r < 8; ++r) {
        const size_t rowi = row0 + r0 + r;
        hc[rowi * 128 + j0] = acc[r][0];
        hc[rowi * 128 + j0 + 64] = acc[r][1];
    }
}

// ---------------- CSR gather for conv (128 feats) + self-loop + bias + BN + ReLU ----------------
__global__ __launch_bounds__(256) void k_conv_gather(
    const float* __restrict__ hc, const float* __restrict__ deg,
    const int* __restrict__ off, const int* __restrict__ csr_src, const float* __restrict__ csr_w,
    const float* __restrict__ cb,
    const float* __restrict__ g, const float* __restrict__ bb,
    const float* __restrict__ m, const float* __restrict__ v,
    float* __restrict__ cmat)
{
    const int t = threadIdx.x;
    const int node = blockIdx.x * 4 + (t >> 6);   // grid = NN/4
    const int f = (t & 63) * 2;
    const float dg = deg[node];
    const float dinv = 1.0f / dg;
    const float2 self = *reinterpret_cast<const float2*>(&hc[(size_t)node * 128 + f]);
    float ax = fmaf(self.x, dinv, cb[f]);
    float ay = fmaf(self.y, dinv, cb[f + 1]);
    const int beg = off[node];
    const int end = beg + ((int)dg - 1);
    for (int s = beg; s < end; ++s) {
        const int src = csr_src[s];
        const float w = csr_w[s];
        const float2 h = *reinterpret_cast<const float2*>(&hc[(size_t)src * 128 + f]);
        ax = fmaf(h.x, w, ax);
        ay = fmaf(h.y, w, ay);
    }
    const float sc0 = rsqrtf(v[f] + BN_EPS) * g[f];
    const float sh0 = bb[f] - m[f] * sc0;
    const float sc1 = rsqrtf(v[f + 1] + BN_EPS) * g[f + 1];
    const float sh1 = bb[f + 1] - m[f + 1] * sc1;
    float2 o;
    o.x = fmaxf(fmaf(ax, sc0, sh0), 0.f);
    o.y = fmaxf(fmaf(ay, sc1, sh1), 0.f);
    *reinterpret_cast<float2*>(&cmat[(size_t)node * 128 + f]) = o;
}

// ---------------- mean|logvar projection: c[N,128] @ [mw|lw][128,16+16] -> m2 ----------------
__global__ __launch_bounds__(256) void k_mlp_proj(
    const float* __restrict__ c, const float* __restrict__ mw, const float* __restrict__ lw,
    float* __restrict__ m2)
{
    __shared__ float cs[32 * 128];
    const int t = threadIdx.x;
    const int row0 = blockIdx.x * 32;
    const int j0 = t & 15;
    const int r0 = (t >> 4) * 2;
    float acc[2][2] = {};
    for (int idx = t; idx < 1024; idx += 256) {
        const int r = idx >> 5, c4 = idx & 31;
        *reinterpret_cast<float4*>(&cs[r * 128 + c4 * 4]) =
            *reinterpret_cast<const float4*>(&c[(size_t)(row0 + r) * 128 + c4 * 4]);
    }
    __syncthreads();
    #pragma unroll 1
    for (int k = 0; k < 128; k += 4) {
        float wv[4][2];
        #pragma unroll
        for (int kk = 0; kk < 4; ++kk) {
            wv[kk][0] = mw[(k + kk) * 16 + j0];
            wv[kk][1] = lw[(k + kk) * 16 + j0];
        }
        #pragma unroll
        for (int r = 0; r < 2; ++r) {
            const float4 xv = *reinterpret_cast<const float4*>(&cs[(r0 + r) * 128 + k]);
            const float xa[4] = {xv.x, xv.y, xv.z, xv.w};
            #pragma unroll
            for (int kk = 0; kk < 4; ++kk) {
                acc[r][0] = fmaf(xa[kk], wv[kk][0], acc[r][0]);
                acc[r][1] = fmaf(xa[kk], wv[kk][1], acc[r][1]);
            }
        }
    }
    #pragma unroll
    for (int r = 0; r < 2; ++r) {
        const size_t rowi = row0 + r0 + r;
        m2[rowi * 32 + j0] = acc[r][0];
        m2[rowi * 32 + 16 + j0] = acc[r][1];
    }
}

// ---------------- CSR gather for mean|logvar (32 feats) + self-loop + bias ----------------
__global__ __launch_bounds__(256) void k_mlp_gather(
    const float* __restrict__ m2, const float* __restrict__ deg,
    const int* __restrict__ off, const int* __restrict__ csr_src, const float* __restrict__ csr_w,
    const float* __restrict__ mb, const float* __restrict__ lb,
    float* __restrict__ agg2)
{
    const int t = threadIdx.x;
    const int node = blockIdx.x * 8 + (t >> 5);   // grid = NN/8
    const int lane = t & 31;
    const float dg = deg[node];
    const float dinv = 1.0f / dg;
    const float bias = (lane < 16) ? mb[lane] : lb[lane - 16];
    float acc = fmaf(m2[(size_t)node * 32 + lane], dinv, bias);
    const int beg = off[node];
    const int end = beg + ((int)dg - 1);
    for (int s = beg; s < end; ++s) {
        const int src = csr_src[s];
        const float w = csr_w[s];
        acc = fmaf(m2[(size_t)src * 32 + lane], w, acc);
    }
    agg2[(size_t)node * 32 + lane] = acc;
}

// ---------------- finalize pre: mu/logvar/z writes, dec0 -> d0bf (bf16), q ----------------
__global__ __launch_bounds__(256) void k_final_pre(
    const float* __restrict__ feat, const float* __restrict__ agg2,
    const float* __restrict__ d0w, const float* __restrict__ d0b,
    const float* __restrict__ g, const float* __restrict__ bb,
    const float* __restrict__ m, const float* __restrict__ v,
    const float* __restrict__ cluster,
    short* __restrict__ d0bf,
    float* __restrict__ out)
{
    __shared__ float zs[8][80];
    __shared__ float qs[8][15];
    const int t = threadIdx.x;
    const int row0 = blockIdx.x * 8;

    for (int idx = t; idx < 512; idx += 256) {
        const int r = idx >> 6, k = idx & 63;
        zs[r][k] = feat[(size_t)(row0 + r) * 64 + k];
    }
    if (t < 128) {
        const int r = t >> 4, k = t & 15;
        const size_t rowi = row0 + r;
        const float muv = agg2[rowi * 32 + k];
        const float lv = agg2[rowi * 32 + 16 + k];
        zs[r][64 + k] = muv;
        out[OMU + rowi * 16 + k] = muv;
        out[OGZ + rowi * 16 + k] = muv;
        out[OZ + rowi * 80 + 64 + k] = muv;
        out[OLV + rowi * 16 + k] = lv;
    }
    __syncthreads();

    // dec0: d0 = ELU(BN(z @ d0w + d0b)) -> bf16 global
    for (int idx = t; idx < 512; idx += 256) {
        const int r = idx >> 6, n = idx & 63;
        float acc = 0.f;
        #pragma unroll
        for (int k = 0; k < 80; k += 4) {
            const float4 zv = *reinterpret_cast<const float4*>(&zs[r][k]);
            acc = fmaf(zv.x, d0w[(k + 0) * 64 + n], acc);
            acc = fmaf(zv.y, d0w[(k + 1) * 64 + n], acc);
            acc = fmaf(zv.z, d0w[(k + 2) * 64 + n], acc);
            acc = fmaf(zv.w, d0w[(k + 3) * 64 + n], acc);
        }
        acc += d0b[n];
        const float sc = rsqrtf(v[n] + BN_EPS) * g[n];
        const float y = elu_f((acc - m[n]) * sc + bb[n]);
        d0bf[(size_t)(row0 + r) * 64 + n] = f2bf(y);
    }

    // student-t q
    if (t < 120) {
        const int r = t / 15, c = t % 15;
        float zz = 0.f, cc = 0.f, dot = 0.f;
        #pragma unroll 1
        for (int k = 0; k < 80; ++k) {
            const float zv = zs[r][k];
            const float cv = cluster[c * 80 + k];
            zz = fmaf(zv, zv, zz);
            cc = fmaf(cv, cv, cc);
            dot = fmaf(zv, cv, dot);
        }
        const float dist = fmaxf(zz + cc - 2.f * dot, 0.f);
        qs[r][c] = powf(1.0f / (1.0f + dist / 0.9f + 1e-8f), 0.95f);
    }
    __syncthreads();
    if (t < 120) {
        const int r = t / 15, c = t % 15;
        float s = 0.f;
        #pragma unroll
        for (int c2 = 0; c2 < 15; ++c2) s += qs[r][c2];
        out[OQ + (size_t)(row0 + r) * 15 + c] = qs[r][c] / s;
    }
}

// ---------------- dec1 via MFMA: de_feat = d0 @ d1w + d1b ----------------
// 128x128 tiles, 4 waves 2x2, K=64 (2 ksteps), fragments direct from global (L2-resident).
__global__ __launch_bounds__(256) void k_dec1_mfma(
    const short* __restrict__ d0bf, const short* __restrict__ wt2,
    const float* __restrict__ d1b, float* __restrict__ out)
{
    const int t = threadIdx.x;
    const int lane = t & 63;
    const int wave = t >> 6;
    const int wm = (wave >> 1) * 64;
    const int wn = (wave & 1) * 64;
    const int row0 = blockIdx.x * 128;
    const int col0 = blockIdx.y * 128;
    const int kc = lane >> 4;
    const int lr = lane & 15;

    f32x4 acc[4][4];
    #pragma unroll
    for (int mi = 0; mi < 4; ++mi)
        #pragma unroll
        for (int ni = 0; ni < 4; ++ni)
            acc[mi][ni] = (f32x4){0.f, 0.f, 0.f, 0.f};

    #pragma unroll
    for (int ks = 0; ks < 2; ++ks) {
        const int k0 = ks * 32 + kc * 8;
        short8v a[4], b[4];
        #pragma unroll
        for (int mi = 0; mi < 4; ++mi) {
            const int row = row0 + wm + mi * 16 + lr;
            if (row < NN)
                a[mi] = *reinterpret_cast<const short8v*>(&d0bf[(size_t)row * 64 + k0]);
            else
                a[mi] = (short8v){0, 0, 0, 0, 0, 0, 0, 0};
        }
        #pragma unroll
        for (int ni = 0; ni < 4; ++ni) {
            const int col = col0 + wn + ni * 16 + lr;
            b[ni] = *reinterpret_cast<const short8v*>(&wt2[(size_t)col * 64 + k0]);
        }
        #pragma unroll
        for (int mi = 0; mi < 4; ++mi)
            #pragma unroll
            for (int ni = 0; ni < 4; ++ni)
                acc[mi][ni] = __builtin_amdgcn_mfma_f32_16x16x32_bf16(a[mi], b[ni], acc[mi][ni], 0, 0, 0);
    }

    // epilogue: +bias, write de_feat (C/D: col=lane&15 within frag, row=(lane>>4)*4+j)
    #pragma unroll
    for (int ni = 0; ni < 4; ++ni) {
        const int col = col0 + wn + ni * 16 + lr;
        if (col < DIN) {
            const float bv = d1b[col];
            #pragma unroll
            for (int mi = 0; mi < 4; ++mi) {
                #pragma unroll
                for (int j = 0; j < 4; ++j) {
                    const int row = row0 + wm + mi * 16 + (lane >> 4) * 4 + j;
                    if (row < NN)
                        out[ODE + (size_t)row * DIN + col] = acc[mi][ni][j] + bv;
                }
            }
        }
    }
}

extern "C" void kernel_launch(void* const* d_in, const int* in_sizes, int n_in,
                              void* d_out, int out_size, void* d_ws, size_t ws_size,
                              hipStream_t stream)
{
    const float* x       = (const float*)d_in[0];
    const void*  ei      = d_in[1];
    const float* enc0_w  = (const float*)d_in[2];
    const float* enc0_b  = (const float*)d_in[3];
    const float* enc0_g  = (const float*)d_in[4];
    const float* enc0_bb = (const float*)d_in[5];
    const float* enc0_m  = (const float*)d_in[6];
    const float* enc0_v  = (const float*)d_in[7];
    const float* enc1_w  = (const float*)d_in[8];
    const float* enc1_b  = (const float*)d_in[9];
    const float* enc1_g  = (const float*)d_in[10];
    const float* enc1_bb = (const float*)d_in[11];
    const float* enc1_m  = (const float*)d_in[12];
    const float* enc1_v  = (const float*)d_in[13];
    const float* conv_w  = (const float*)d_in[14];
    const float* conv_b  = (const float*)d_in[15];
    const float* conv_g  = (const float*)d_in[16];
    const float* conv_bb = (const float*)d_in[17];
    const float* conv_m  = (const float*)d_in[18];
    const float* conv_v  = (const float*)d_in[19];
    const float* mean_w  = (const float*)d_in[20];
    const float* mean_b  = (const float*)d_in[21];
    const float* logvar_w = (const float*)d_in[22];
    const float* logvar_b = (const float*)d_in[23];
    const float* dec0_w  = (const float*)d_in[24];
    const float* dec0_b  = (const float*)d_in[25];
    const float* dec0_g  = (const float*)d_in[26];
    const float* dec0_bb = (const float*)d_in[27];
    const float* dec0_m  = (const float*)d_in[28];
    const float* dec0_v  = (const float*)d_in[29];
    const float* dec1_w  = (const float*)d_in[30];
    const float* dec1_b  = (const float*)d_in[31];
    const float* cluster = (const float*)d_in[32];

    float* ws = (float*)d_ws;
    float* deg  = ws;                              // N
    float* feat = ws + NN;                         // 64N
    float* A    = ws + (size_t)65 * NN;            // 256N: h1 | hc+cmat | m2+agg2+d0bf
    size_t base = (size_t)321 * NN;
    int*   off     = (int*)(ws + base);                        // N
    int*   cursor  = (int*)(ws + base + NN);                   // N
    int*   bsum    = (int*)(ws + base + 2 * (size_t)NN);       // 512
    int*   csr_src = (int*)(ws + base + 2 * (size_t)NN + 512);             // E
    float* csr_w   = (float*)(ws + base + 2 * (size_t)NN + 512 + NE);      // E
    short* wt      = (short*)(ws + base + 2 * (size_t)NN + 512 + 2 * (size_t)NE);  // 256*1024 bf16
    int*   flag    = (int*)(ws + base + 2 * (size_t)NN + 512 + 2 * (size_t)NE + 131072); // 1

    float* h1   = A;                      // N x 256
    float* hc   = A;                      // N x 128 (after h1 dead)
    float* cmat = A + (size_t)128 * NN;   // N x 128
    float* m2   = A;                      // N x 32 (after hc dead)
    float* agg2 = A + (size_t)32 * NN;    // N x 32
    short* d0bf = (short*)(A + (size_t)64 * NN);   // N x 64 bf16 (hc region, dead after conv_gather)
    short* wt2  = wt;                     // 1024 x 64 bf16 (reuses enc0 wt, dead after enc0_mfma)

    float* out = (float*)d_out;

    k_detect<<<1, 256, 0, stream>>>((const int*)ei, flag);
    k_deg_init<<<NB, 256, 0, stream>>>(deg);
    k_deg_accum<<<NE / 256, 256, 0, stream>>>(ei, flag, deg);

    // CSR build
    k_scan1<<<NB, 256, 0, stream>>>(deg, off, bsum, cursor);
    k_scan2<<<1, 512, 0, stream>>>(bsum);
    k_scan3<<<NB, 256, 0, stream>>>(off, bsum);
    k_fill<<<NE / 256, 256, 0, stream>>>(ei, flag, deg, off, cursor, csr_src, csr_w);

    // enc0 via MFMA
    k_wt<<<1024, 256, 0, stream>>>(enc0_w, wt);
    {
        dim3 grid((NN + 127) / 128, 2);
        k_enc0_mfma<<<grid, 256, 0, stream>>>(x, wt, enc0_b, enc0_g, enc0_bb, enc0_m, enc0_v, h1);
    }
    // dec1 weight prep (reuses wt buffer — enc0 done with it)
    k_wt2<<<256, 256, 0, stream>>>(dec1_w, wt2);

    k_enc1<<<NN / 32, 256, 0, stream>>>(h1, enc1_w, enc1_b, enc1_g, enc1_bb, enc1_m, enc1_v, feat, out);

    k_conv_proj<<<NN / 32, 256, 0, stream>>>(feat, conv_w, hc);
    k_conv_gather<<<NN / 4, 256, 0, stream>>>(hc, deg, off, csr_src, csr_w, conv_b,
                                              conv_g, conv_bb, conv_m, conv_v, cmat);

    k_mlp_proj<<<NN / 32, 256, 0, stream>>>(cmat, mean_w, logvar_w, m2);
    k_mlp_gather<<<NN / 8, 256, 0, stream>>>(m2, deg, off, csr_src, csr_w, mean_b, logvar_b, agg2);

    k_final_pre<<<NN / 8, 256, 0, stream>>>(feat, agg2, dec0_w, dec0_b, dec0_g, dec0_bb, dec0_m, dec0_v,
                                            cluster, d0bf, out);
    {
        dim3 grid((NN + 127) / 128, 8);
        k_dec1_mfma<<<grid, 256, 0, stream>>>(d0bf, wt2, dec1_b, out);
    }
}

// Round 9
// 1251.227 us; speedup vs baseline: 1.0665x; 1.0665x over previous
//
#include <hip/hip_runtime.h>
#include <hip/hip_bf16.h>

#define NN 100000
#define NE 1600000
#define DIN 1000
#define BN_EPS 1e-3f
#define NB 391   // ceil(NN/256)

// output element offsets (concat of z, mu, logvar, de_feat, q, feat_x, gnn_z) — float32 out
#define OZ  ((size_t)0)
#define OMU ((size_t)NN*80)
#define OLV ((size_t)NN*96)
#define ODE ((size_t)NN*112)
#define OQ  ((size_t)NN*1112)
#define OFX ((size_t)NN*1127)
#define OGZ ((size_t)NN*1191)

typedef __attribute__((ext_vector_type(8))) short short8v;   // 8 bf16 (4 VGPRs)
typedef __attribute__((ext_vector_type(4))) float f32x4;     // MFMA accumulator

__device__ __forceinline__ float elu_f(float x) { return x > 0.f ? x : expf(x) - 1.f; }

// fp32 -> bf16 bits, round-to-nearest-even
__device__ __forceinline__ short f2bf(float f) {
    union { float f; unsigned u; } c; c.f = f;
    unsigned r = c.u + 0x7fffu + ((c.u >> 16) & 1u);
    return (short)(r >> 16);
}

// Edge index may arrive as int32 or int64; logical element idx in flat (2*E) array.
__device__ __forceinline__ int edge_at(const void* ei, int is64, size_t idx) {
    if (is64) return (int)((const long long*)ei)[idx];
    return ((const int*)ei)[idx];
}

// ---------------- dtype detection ----------------
__global__ __launch_bounds__(256) void k_detect(const int* __restrict__ ei, int* __restrict__ flag) {
    __shared__ int nz;
    if (threadIdx.x == 0) nz = 0;
    __syncthreads();
    for (int i = threadIdx.x; i < 2048; i += 256)
        if (ei[2 * i + 1] != 0) nz = 1;
    __syncthreads();
    if (threadIdx.x == 0) flag[0] = (nz == 0) ? 1 : 0;  // 1 => int64
}

// ---------------- degree ----------------
__global__ __launch_bounds__(256) void k_deg_init(float* __restrict__ deg) {
    int i = blockIdx.x * 256 + threadIdx.x;
    if (i < NN) deg[i] = 1.0f;
}

__global__ __launch_bounds__(256) void k_deg_accum(const void* __restrict__ ei, const int* __restrict__ flag,
                                                   float* __restrict__ deg) {
    const int is64 = flag[0];
    int e = blockIdx.x * 256 + threadIdx.x;
    if (e < NE) atomicAdd(&deg[edge_at(ei, is64, (size_t)NE + e)], 1.0f);
}

// ---------------- CSR build: exclusive scan of in-edge counts ----------------
__global__ __launch_bounds__(256) void k_scan1(const float* __restrict__ deg, int* __restrict__ off,
                                               int* __restrict__ bsum, int* __restrict__ cursor) {
    __shared__ int s[256];
    const int t = threadIdx.x;
    const int i = blockIdx.x * 256 + t;
    const int vv = (i < NN) ? ((int)deg[i]) - 1 : 0;
    if (i < NN) cursor[i] = 0;
    s[t] = vv;
    __syncthreads();
    for (int d = 1; d < 256; d <<= 1) {
        const int u = (t >= d) ? s[t - d] : 0;
        __syncthreads();
        s[t] += u;
        __syncthreads();
    }
    if (i < NN) off[i] = s[t] - vv;           // exclusive, pre-block-offset
    if (t == 255) bsum[blockIdx.x] = s[t];    // block total
}

__global__ __launch_bounds__(512) void k_scan2(int* __restrict__ bsum) {
    __shared__ int s[512];
    const int t = threadIdx.x;
    const int vv = (t < NB) ? bsum[t] : 0;
    s[t] = vv;
    __syncthreads();
    for (int d = 1; d < 512; d <<= 1) {
        const int u = (t >= d) ? s[t - d] : 0;
        __syncthreads();
        s[t] += u;
        __syncthreads();
    }
    if (t < NB) bsum[t] = s[t] - vv;          // exclusive block prefix
}

__global__ __launch_bounds__(256) void k_scan3(int* __restrict__ off, const int* __restrict__ bsum) {
    const int i = blockIdx.x * 256 + threadIdx.x;
    if (i < NN) off[i] += bsum[blockIdx.x];
}

__global__ __launch_bounds__(256) void k_fill(const void* __restrict__ ei, const int* __restrict__ flag,
                                              const float* __restrict__ deg, const int* __restrict__ off,
                                              int* __restrict__ cursor,
                                              int* __restrict__ csr_src, float* __restrict__ csr_w) {
    const int is64 = flag[0];
    const int e = blockIdx.x * 256 + threadIdx.x;
    if (e >= NE) return;
    const int r = edge_at(ei, is64, e);
    const int c = edge_at(ei, is64, (size_t)NE + e);
    const float w = rsqrtf(deg[r]) * rsqrtf(deg[c]);
    const int p = atomicAdd(&cursor[c], 1);
    const int slot = off[c] + p;
    csr_src[slot] = r;
    csr_w[slot] = w;
}

// ---------------- enc0 weight prep: w[1000][256] f32 -> k-major bf16 granules ----------------
// Granule layout: wt[((k>>3)*256 + c)*8 + (k&7)], k zero-padded to 1024.
__global__ __launch_bounds__(256) void k_wt(const float* __restrict__ w, short* __restrict__ wt) {
    const int tid = blockIdx.x * 256 + threadIdx.x;   // 256*1024 elements
    const int c = tid >> 10;
    const int k = tid & 1023;
    wt[((size_t)(k >> 3) * 256 + c) * 8 + (k & 7)] = (k < DIN) ? f2bf(w[(size_t)k * 256 + c]) : (short)0;
}

// ---------------- dec1 weight prep: w[64][1000] f32 -> wt2[1024][64] bf16 (cols zero-padded) ----------------
__global__ __launch_bounds__(256) void k_wt2(const float* __restrict__ w, short* __restrict__ wt2) {
    const int tid = blockIdx.x * 256 + threadIdx.x;   // 1024*64 elements
    const int c = tid >> 6;
    const int k = tid & 63;
    wt2[(size_t)c * 64 + k] = (c < DIN) ? f2bf(w[(size_t)k * DIN + c]) : (short)0;
}

// ---------------- encoder L0 via MFMA: h1 = ELU(BN(x @ w)) ----------------
// Block tile 128x256 (ALL output cols -> x read once), 8 waves (2 row x 4 col),
// wave tile 64x64 (4x4 frags of 16x16x32), K_STEP=32.
// LDS granules (16B = 8 bf16): As[kc][row] (4x128), Bs[kc][col] (4x256).
__global__ __launch_bounds__(512, 2) void k_enc0_mfma(
    const float* __restrict__ x, const short* __restrict__ wt, const float* __restrict__ bias,
    const float* __restrict__ g, const float* __restrict__ bb,
    const float* __restrict__ m, const float* __restrict__ v,
    float* __restrict__ h1)
{
    __shared__ short As[4 * 128 * 8];
    __shared__ short Bs[4 * 256 * 8];
    const int t = threadIdx.x;           // 0..511
    const int lane = t & 63;
    const int wave = t >> 6;             // 0..7
    const int wm = (wave >> 2) * 64;     // 0,64
    const int wn = (wave & 3) * 64;      // 0,64,128,192
    const int row0 = blockIdx.x * 128;

    f32x4 acc[4][4];
    #pragma unroll
    for (int mi = 0; mi < 4; ++mi)
        #pragma unroll
        for (int ni = 0; ni < 4; ++ni)
            acc[mi][ni] = (f32x4){0.f, 0.f, 0.f, 0.f};

    // A staging: thread t owns granule (kcA = t>>7, rowA = t&127)
    const int rowA = t & 127;
    const int kcA = t >> 7;
    const bool rowA_ok = (row0 + rowA) < NN;
    const float* xrow = x + (size_t)(row0 + rowA) * DIN;
    short* aslot = &As[((size_t)kcA * 128 + rowA) * 8];
    // B staging: granules g = t (kc 0..1) and t+512 (kc 2..3)
    const int colB = t & 255;
    const int kcB0 = t >> 8;
    const int kcB1 = 2 + (t >> 8);

    const int kc = lane >> 4;    // 0..3
    const int lr = lane & 15;

    for (int ks = 0; ks < 32; ++ks) {
        const int k0 = ks * 32;
        __syncthreads();
        // ---- stage A (x fp32 -> bf16), 8 k per thread ----
        {
            const int kb = k0 + kcA * 8;
            short8v p;
            if (rowA_ok && kb + 8 <= DIN) {
                const float4 f0 = *reinterpret_cast<const float4*>(xrow + kb);
                const float4 f1 = *reinterpret_cast<const float4*>(xrow + kb + 4);
                p[0] = f2bf(f0.x); p[1] = f2bf(f0.y); p[2] = f2bf(f0.z); p[3] = f2bf(f0.w);
                p[4] = f2bf(f1.x); p[5] = f2bf(f1.y); p[6] = f2bf(f1.z); p[7] = f2bf(f1.w);
            } else if (rowA_ok) {
                #pragma unroll
                for (int j = 0; j < 8; ++j)
                    p[j] = (kb + j < DIN) ? f2bf(xrow[kb + j]) : (short)0;
            } else {
                #pragma unroll
                for (int j = 0; j < 8; ++j) p[j] = 0;
            }
            *reinterpret_cast<short8v*>(aslot) = p;
        }
        // ---- stage B (wt k-major granules, coalesced) ----
        {
            const int gbase = ks * 4;   // k0>>3
            *reinterpret_cast<short8v*>(&Bs[((size_t)kcB0 * 256 + colB) * 8]) =
                *reinterpret_cast<const short8v*>(&wt[((size_t)(gbase + kcB0) * 256 + colB) * 8]);
            *reinterpret_cast<short8v*>(&Bs[((size_t)kcB1 * 256 + colB) * 8]) =
                *reinterpret_cast<const short8v*>(&wt[((size_t)(gbase + kcB1) * 256 + colB) * 8]);
        }
        __syncthreads();
        // ---- fragments + MFMA ----
        short8v a[4], b[4];
        #pragma unroll
        for (int mi = 0; mi < 4; ++mi)
            a[mi] = *reinterpret_cast<const short8v*>(&As[((size_t)kc * 128 + wm + mi * 16 + lr) * 8]);
        #pragma unroll
        for (int ni = 0; ni < 4; ++ni)
            b[ni] = *reinterpret_cast<const short8v*>(&Bs[((size_t)kc * 256 + wn + ni * 16 + lr) * 8]);
        #pragma unroll
        for (int mi = 0; mi < 4; ++mi)
            #pragma unroll
            for (int ni = 0; ni < 4; ++ni)
                acc[mi][ni] = __builtin_amdgcn_mfma_f32_16x16x32_bf16(a[mi], b[ni], acc[mi][ni], 0, 0, 0);
    }

    // ---- epilogue: BN + ELU, C/D layout col=lane&15, row=(lane>>4)*4+reg ----
    float sc[4], sh[4];
    int cols[4];
    #pragma unroll
    for (int ni = 0; ni < 4; ++ni) {
        const int col = wn + ni * 16 + lr;
        cols[ni] = col;
        const float s = rsqrtf(v[col] + BN_EPS) * g[col];
        sc[ni] = s;
        sh[ni] = (bias[col] - m[col]) * s + bb[col];
    }
    #pragma unroll
    for (int mi = 0; mi < 4; ++mi) {
        #pragma unroll
        for (int j = 0; j < 4; ++j) {
            const int row = row0 + wm + mi * 16 + (lane >> 4) * 4 + j;
            if (row < NN) {
                #pragma unroll
                for (int ni = 0; ni < 4; ++ni) {
                    const float y = acc[mi][ni][j] * sc[ni] + sh[ni];
                    h1[(size_t)row * 256 + cols[ni]] = elu_f(y);
                }
            }
        }
    }
}

// ---------------- encoder L1: h1[N,256] @ w[256,64] + BN + ELU -> feat, out ----------------
__global__ __launch_bounds__(256) void k_enc1(
    const float* __restrict__ h1, const float* __restrict__ w, const float* __restrict__ bias,
    const float* __restrict__ g, const float* __restrict__ bb,
    const float* __restrict__ m, const float* __restrict__ v,
    float* __restrict__ feat, float* __restrict__ out)
{
    __shared__ float hs[32 * 256];
    const int t = threadIdx.x;
    const int row0 = blockIdx.x * 32;
    const int j0 = t & 31;
    const int r0 = (t >> 5) * 4;
    float acc[4][2] = {};
    for (int idx = t; idx < 2048; idx += 256) {
        const int r = idx >> 6, c4 = idx & 63;
        *reinterpret_cast<float4*>(&hs[r * 256 + c4 * 4]) =
            *reinterpret_cast<const float4*>(&h1[(size_t)(row0 + r) * 256 + c4 * 4]);
    }
    __syncthreads();
    #pragma unroll 1
    for (int k = 0; k < 256; k += 4) {
        float wv[4][2];
        #pragma unroll
        for (int kk = 0; kk < 4; ++kk) {
            wv[kk][0] = w[(k + kk) * 64 + j0];
            wv[kk][1] = w[(k + kk) * 64 + j0 + 32];
        }
        #pragma unroll
        for (int r = 0; r < 4; ++r) {
            const float4 xv = *reinterpret_cast<const float4*>(&hs[(r0 + r) * 256 + k]);
            const float xa[4] = {xv.x, xv.y, xv.z, xv.w};
            #pragma unroll
            for (int kk = 0; kk < 4; ++kk) {
                acc[r][0] = fmaf(xa[kk], wv[kk][0], acc[r][0]);
                acc[r][1] = fmaf(xa[kk], wv[kk][1], acc[r][1]);
            }
        }
    }
    #pragma unroll
    for (int c = 0; c < 2; ++c) {
        const int j = j0 + 32 * c;
        const float sc = rsqrtf(v[j] + BN_EPS) * g[j];
        const float sh = (bias[j] - m[j]) * sc + bb[j];
        #pragma unroll
        for (int r = 0; r < 4; ++r) {
            const size_t rowi = row0 + r0 + r;
            const float y = elu_f(acc[r][c] * sc + sh);
            feat[rowi * 64 + j] = y;
            out[OFX + rowi * 64 + j] = y;
            out[OZ + rowi * 80 + j] = y;
        }
    }
}

// ---------------- GCN projection: feat[N,64] @ conv_w[64,128] -> hc ----------------
__global__ __launch_bounds__(256) void k_conv_proj(
    const float* __restrict__ feat, const float* __restrict__ w,
    float* __restrict__ hc)
{
    __shared__ float fs[32 * 64];
    const int t = threadIdx.x;
    const int row0 = blockIdx.x * 32;
    const int j0 = t & 63;
    const int r0 = (t >> 6) * 8;
    float acc[8][2] = {};
    for (int idx = t; idx < 512; idx += 256) {
        const int r = idx >> 4, c4 = idx & 15;
        *reinterpret_cast<float4*>(&fs[r * 64 + c4 * 4]) =
            *reinterpret_cast<const float4*>(&feat[(size_t)(row0 + r) * 64 + c4 * 4]);
    }
    __syncthreads();
    #pragma unroll 1
    for (int k = 0; k < 64; k += 4) {
        float wv[4][2];
        #pragma unroll
        for (int kk = 0; kk < 4; ++kk) {
            wv[kk][0] = w[(k + kk) * 128 + j0];
            wv[kk][1] = w[(k + kk) * 128 + j0 + 64];
        }
        #pragma unroll
        for (int r = 0; r < 8; ++r) {
            const float4 xv = *reinterpret_cast<const float4*>(&fs[(r0 + r) * 64 + k]);
            const float xa[4] = {xv.x, xv.y, xv.z, xv.w};
            #pragma unroll
            for (int kk = 0; kk < 4; ++kk) {
                acc[r][0] = fmaf(xa[kk], wv[kk][0], acc[r][0]);
                acc[r][1] = fmaf(xa[kk], wv[kk][1], acc[r][1]);
            }
        }
    }
    #pragma unroll
    for (int r = 0; r < 8; ++r) {
        const size_t rowi = row0 + r0 + r;
        hc[rowi * 128 + j0] = acc[r][0];
        hc[rowi * 128 + j0 + 64] = acc[r][1];
    }
}

// ---------------- CSR gather for conv (128 feats) + self-loop + bias + BN + ReLU ----------------
__global__ __launch_bounds__(256) void k_conv_gather(
    const float* __restrict__ hc, const float* __restrict__ deg,
    const int* __restrict__ off, const int* __restrict__ csr_src, const float* __restrict__ csr_w,
    const float* __restrict__ cb,
    const float* __restrict__ g, const float* __restrict__ bb,
    const float* __restrict__ m, const float* __restrict__ v,
    float* __restrict__ cmat)
{
    const int t = threadIdx.x;
    const int node = blockIdx.x * 4 + (t >> 6);   // grid = NN/4
    const int f = (t & 63) * 2;
    const float dg = deg[node];
    const float dinv = 1.0f / dg;
    const float2 self = *reinterpret_cast<const float2*>(&hc[(size_t)node * 128 + f]);
    float ax = fmaf(self.x, dinv, cb[f]);
    float ay = fmaf(self.y, dinv, cb[f + 1]);
    const int beg = off[node];
    const int end = beg + ((int)dg - 1);
    for (int s = beg; s < end; ++s) {
        const int src = csr_src[s];
        const float w = csr_w[s];
        const float2 h = *reinterpret_cast<const float2*>(&hc[(size_t)src * 128 + f]);
        ax = fmaf(h.x, w, ax);
        ay = fmaf(h.y, w, ay);
    }
    const float sc0 = rsqrtf(v[f] + BN_EPS) * g[f];
    const float sh0 = bb[f] - m[f] * sc0;
    const float sc1 = rsqrtf(v[f + 1] + BN_EPS) * g[f + 1];
    const float sh1 = bb[f + 1] - m[f + 1] * sc1;
    float2 o;
    o.x = fmaxf(fmaf(ax, sc0, sh0), 0.f);
    o.y = fmaxf(fmaf(ay, sc1, sh1), 0.f);
    *reinterpret_cast<float2*>(&cmat[(size_t)node * 128 + f]) = o;
}

// ---------------- mean|logvar projection: c[N,128] @ [mw|lw][128,16+16] -> m2 ----------------
__global__ __launch_bounds__(256) void k_mlp_proj(
    const float* __restrict__ c, const float* __restrict__ mw, const float* __restrict__ lw,
    float* __restrict__ m2)
{
    __shared__ float cs[32 * 128];
    const int t = threadIdx.x;
    const int row0 = blockIdx.x * 32;
    const int j0 = t & 15;
    const int r0 = (t >> 4) * 2;
    float acc[2][2] = {};
    for (int idx = t; idx < 1024; idx += 256) {
        const int r = idx >> 5, c4 = idx & 31;
        *reinterpret_cast<float4*>(&cs[r * 128 + c4 * 4]) =
            *reinterpret_cast<const float4*>(&c[(size_t)(row0 + r) * 128 + c4 * 4]);
    }
    __syncthreads();
    #pragma unroll 1
    for (int k = 0; k < 128; k += 4) {
        float wv[4][2];
        #pragma unroll
        for (int kk = 0; kk < 4; ++kk) {
            wv[kk][0] = mw[(k + kk) * 16 + j0];
            wv[kk][1] = lw[(k + kk) * 16 + j0];
        }
        #pragma unroll
        for (int r = 0; r < 2; ++r) {
            const float4 xv = *reinterpret_cast<const float4*>(&cs[(r0 + r) * 128 + k]);
            const float xa[4] = {xv.x, xv.y, xv.z, xv.w};
            #pragma unroll
            for (int kk = 0; kk < 4; ++kk) {
                acc[r][0] = fmaf(xa[kk], wv[kk][0], acc[r][0]);
                acc[r][1] = fmaf(xa[kk], wv[kk][1], acc[r][1]);
            }
        }
    }
    #pragma unroll
    for (int r = 0; r < 2; ++r) {
        const size_t rowi = row0 + r0 + r;
        m2[rowi * 32 + j0] = acc[r][0];
        m2[rowi * 32 + 16 + j0] = acc[r][1];
    }
}

// ---------------- CSR gather for mean|logvar (32 feats) + self-loop + bias ----------------
__global__ __launch_bounds__(256) void k_mlp_gather(
    const float* __restrict__ m2, const float* __restrict__ deg,
    const int* __restrict__ off, const int* __restrict__ csr_src, const float* __restrict__ csr_w,
    const float* __restrict__ mb, const float* __restrict__ lb,
    float* __restrict__ agg2)
{
    const int t = threadIdx.x;
    const int node = blockIdx.x * 8 + (t >> 5);   // grid = NN/8
    const int lane = t & 31;
    const float dg = deg[node];
    const float dinv = 1.0f / dg;
    const float bias = (lane < 16) ? mb[lane] : lb[lane - 16];
    float acc = fmaf(m2[(size_t)node * 32 + lane], dinv, bias);
    const int beg = off[node];
    const int end = beg + ((int)dg - 1);
    for (int s = beg; s < end; ++s) {
        const int src = csr_src[s];
        const float w = csr_w[s];
        acc = fmaf(m2[(size_t)src * 32 + lane], w, acc);
    }
    agg2[(size_t)node * 32 + lane] = acc;
}

// ---------------- finalize pre: mu/logvar/z writes, dec0 -> d0bf (bf16), q ----------------
__global__ __launch_bounds__(256) void k_final_pre(
    const float* __restrict__ feat, const float* __restrict__ agg2,
    const float* __restrict__ d0w, const float* __restrict__ d0b,
    const float* __restrict__ g, const float* __restrict__ bb,
    const float* __restrict__ m, const float* __restrict__ v,
    const float* __restrict__ cluster,
    short* __restrict__ d0bf,
    float* __restrict__ out)
{
    __shared__ float zs[8][80];
    __shared__ float qs[8][15];
    const int t = threadIdx.x;
    const int row0 = blockIdx.x * 8;

    for (int idx = t; idx < 512; idx += 256) {
        const int r = idx >> 6, k = idx & 63;
        zs[r][k] = feat[(size_t)(row0 + r) * 64 + k];
    }
    if (t < 128) {
        const int r = t >> 4, k = t & 15;
        const size_t rowi = row0 + r;
        const float muv = agg2[rowi * 32 + k];
        const float lv = agg2[rowi * 32 + 16 + k];
        zs[r][64 + k] = muv;
        out[OMU + rowi * 16 + k] = muv;
        out[OGZ + rowi * 16 + k] = muv;
        out[OZ + rowi * 80 + 64 + k] = muv;
        out[OLV + rowi * 16 + k] = lv;
    }
    __syncthreads();

    // dec0: d0 = ELU(BN(z @ d0w + d0b)) -> bf16 global
    for (int idx = t; idx < 512; idx += 256) {
        const int r = idx >> 6, n = idx & 63;
        float acc = 0.f;
        #pragma unroll
        for (int k = 0; k < 80; k += 4) {
            const float4 zv = *reinterpret_cast<const float4*>(&zs[r][k]);
            acc = fmaf(zv.x, d0w[(k + 0) * 64 + n], acc);
            acc = fmaf(zv.y, d0w[(k + 1) * 64 + n], acc);
            acc = fmaf(zv.z, d0w[(k + 2) * 64 + n], acc);
            acc = fmaf(zv.w, d0w[(k + 3) * 64 + n], acc);
        }
        acc += d0b[n];
        const float sc = rsqrtf(v[n] + BN_EPS) * g[n];
        const float y = elu_f((acc - m[n]) * sc + bb[n]);
        d0bf[(size_t)(row0 + r) * 64 + n] = f2bf(y);
    }

    // student-t q
    if (t < 120) {
        const int r = t / 15, c = t % 15;
        float zz = 0.f, cc = 0.f, dot = 0.f;
        #pragma unroll 1
        for (int k = 0; k < 80; ++k) {
            const float zv = zs[r][k];
            const float cv = cluster[c * 80 + k];
            zz = fmaf(zv, zv, zz);
            cc = fmaf(cv, cv, cc);
            dot = fmaf(zv, cv, dot);
        }
        const float dist = fmaxf(zz + cc - 2.f * dot, 0.f);
        qs[r][c] = powf(1.0f / (1.0f + dist / 0.9f + 1e-8f), 0.95f);
    }
    __syncthreads();
    if (t < 120) {
        const int r = t / 15, c = t % 15;
        float s = 0.f;
        #pragma unroll
        for (int c2 = 0; c2 < 15; ++c2) s += qs[r][c2];
        out[OQ + (size_t)(row0 + r) * 15 + c] = qs[r][c] / s;
    }
}

// ---------------- dec1 via MFMA: de_feat = d0 @ d1w + d1b ----------------
// 128x128 tiles, 4 waves 2x2, K=64 (2 ksteps), fragments direct from global (L2-resident).
__global__ __launch_bounds__(256) void k_dec1_mfma(
    const short* __restrict__ d0bf, const short* __restrict__ wt2,
    const float* __restrict__ d1b, float* __restrict__ out)
{
    const int t = threadIdx.x;
    const int lane = t & 63;
    const int wave = t >> 6;
    const int wm = (wave >> 1) * 64;
    const int wn = (wave & 1) * 64;
    const int row0 = blockIdx.x * 128;
    const int col0 = blockIdx.y * 128;
    const int kc = lane >> 4;
    const int lr = lane & 15;

    f32x4 acc[4][4];
    #pragma unroll
    for (int mi = 0; mi < 4; ++mi)
        #pragma unroll
        for (int ni = 0; ni < 4; ++ni)
            acc[mi][ni] = (f32x4){0.f, 0.f, 0.f, 0.f};

    #pragma unroll
    for (int ks = 0; ks < 2; ++ks) {
        const int k0 = ks * 32 + kc * 8;
        short8v a[4], b[4];
        #pragma unroll
        for (int mi = 0; mi < 4; ++mi) {
            const int row = row0 + wm + mi * 16 + lr;
            if (row < NN)
                a[mi] = *reinterpret_cast<const short8v*>(&d0bf[(size_t)row * 64 + k0]);
            else
                a[mi] = (short8v){0, 0, 0, 0, 0, 0, 0, 0};
        }
        #pragma unroll
        for (int ni = 0; ni < 4; ++ni) {
            const int col = col0 + wn + ni * 16 + lr;
            b[ni] = *reinterpret_cast<const short8v*>(&wt2[(size_t)col * 64 + k0]);
        }
        #pragma unroll
        for (int mi = 0; mi < 4; ++mi)
            #pragma unroll
            for (int ni = 0; ni < 4; ++ni)
                acc[mi][ni] = __builtin_amdgcn_mfma_f32_16x16x32_bf16(a[mi], b[ni], acc[mi][ni], 0, 0, 0);
    }

    // epilogue: +bias, write de_feat (C/D: col=lane&15 within frag, row=(lane>>4)*4+j)
    #pragma unroll
    for (int ni = 0; ni < 4; ++ni) {
        const int col = col0 + wn + ni * 16 + lr;
        if (col < DIN) {
            const float bv = d1b[col];
            #pragma unroll
            for (int mi = 0; mi < 4; ++mi) {
                #pragma unroll
                for (int j = 0; j < 4; ++j) {
                    const int row = row0 + wm + mi * 16 + (lane >> 4) * 4 + j;
                    if (row < NN)
                        out[ODE + (size_t)row * DIN + col] = acc[mi][ni][j] + bv;
                }
            }
        }
    }
}

extern "C" void kernel_launch(void* const* d_in, const int* in_sizes, int n_in,
                              void* d_out, int out_size, void* d_ws, size_t ws_size,
                              hipStream_t stream)
{
    const float* x       = (const float*)d_in[0];
    const void*  ei      = d_in[1];
    const float* enc0_w  = (const float*)d_in[2];
    const float* enc0_b  = (const float*)d_in[3];
    const float* enc0_g  = (const float*)d_in[4];
    const float* enc0_bb = (const float*)d_in[5];
    const float* enc0_m  = (const float*)d_in[6];
    const float* enc0_v  = (const float*)d_in[7];
    const float* enc1_w  = (const float*)d_in[8];
    const float* enc1_b  = (const float*)d_in[9];
    const float* enc1_g  = (const float*)d_in[10];
    const float* enc1_bb = (const float*)d_in[11];
    const float* enc1_m  = (const float*)d_in[12];
    const float* enc1_v  = (const float*)d_in[13];
    const float* conv_w  = (const float*)d_in[14];
    const float* conv_b  = (const float*)d_in[15];
    const float* conv_g  = (const float*)d_in[16];
    const float* conv_bb = (const float*)d_in[17];
    const float* conv_m  = (const float*)d_in[18];
    const float* conv_v  = (const float*)d_in[19];
    const float* mean_w  = (const float*)d_in[20];
    const float* mean_b  = (const float*)d_in[21];
    const float* logvar_w = (const float*)d_in[22];
    const float* logvar_b = (const float*)d_in[23];
    const float* dec0_w  = (const float*)d_in[24];
    const float* dec0_b  = (const float*)d_in[25];
    const float* dec0_g  = (const float*)d_in[26];
    const float* dec0_bb = (const float*)d_in[27];
    const float* dec0_m  = (const float*)d_in[28];
    const float* dec0_v  = (const float*)d_in[29];
    const float* dec1_w  = (const float*)d_in[30];
    const float* dec1_b  = (const float*)d_in[31];
    const float* cluster = (const float*)d_in[32];

    float* ws = (float*)d_ws;
    float* deg  = ws;                              // N
    float* feat = ws + NN;                         // 64N
    float* A    = ws + (size_t)65 * NN;            // 256N: h1 | hc+cmat | m2+agg2+d0bf
    size_t base = (size_t)321 * NN;
    int*   off     = (int*)(ws + base);                        // N
    int*   cursor  = (int*)(ws + base + NN);                   // N
    int*   bsum    = (int*)(ws + base + 2 * (size_t)NN);       // 512
    int*   csr_src = (int*)(ws + base + 2 * (size_t)NN + 512);             // E
    float* csr_w   = (float*)(ws + base + 2 * (size_t)NN + 512 + NE);      // E
    short* wt      = (short*)(ws + base + 2 * (size_t)NN + 512 + 2 * (size_t)NE);  // 256*1024 bf16
    int*   flag    = (int*)(ws + base + 2 * (size_t)NN + 512 + 2 * (size_t)NE + 131072); // 1

    float* h1   = A;                      // N x 256
    float* hc   = A;                      // N x 128 (after h1 dead)
    float* cmat = A + (size_t)128 * NN;   // N x 128
    float* m2   = A;                      // N x 32 (after hc dead)
    float* agg2 = A + (size_t)32 * NN;    // N x 32
    short* d0bf = (short*)(A + (size_t)64 * NN);   // N x 64 bf16 (hc region, dead after conv_gather)
    short* wt2  = wt;                     // 1024 x 64 bf16 (reuses enc0 wt, dead after enc0_mfma)

    float* out = (float*)d_out;

    k_detect<<<1, 256, 0, stream>>>((const int*)ei, flag);
    k_deg_init<<<NB, 256, 0, stream>>>(deg);
    k_deg_accum<<<NE / 256, 256, 0, stream>>>(ei, flag, deg);

    // CSR build
    k_scan1<<<NB, 256, 0, stream>>>(deg, off, bsum, cursor);
    k_scan2<<<1, 512, 0, stream>>>(bsum);
    k_scan3<<<NB, 256, 0, stream>>>(off, bsum);
    k_fill<<<NE / 256, 256, 0, stream>>>(ei, flag, deg, off, cursor, csr_src, csr_w);

    // enc0 via MFMA (single pass over x: block tile 128x256)
    k_wt<<<1024, 256, 0, stream>>>(enc0_w, wt);
    k_enc0_mfma<<<(NN + 127) / 128, 512, 0, stream>>>(x, wt, enc0_b, enc0_g, enc0_bb, enc0_m, enc0_v, h1);
    // dec1 weight prep (reuses wt buffer — enc0 done with it)
    k_wt2<<<256, 256, 0, stream>>>(dec1_w, wt2);

    k_enc1<<<NN / 32, 256, 0, stream>>>(h1, enc1_w, enc1_b, enc1_g, enc1_bb, enc1_m, enc1_v, feat, out);

    k_conv_proj<<<NN / 32, 256, 0, stream>>>(feat, conv_w, hc);
    k_conv_gather<<<NN / 4, 256, 0, stream>>>(hc, deg, off, csr_src, csr_w, conv_b,
                                              conv_g, conv_bb, conv_m, conv_v, cmat);

    k_mlp_proj<<<NN / 32, 256, 0, stream>>>(cmat, mean_w, logvar_w, m2);
    k_mlp_gather<<<NN / 8, 256, 0, stream>>>(m2, deg, off, csr_src, csr_w, mean_b, logvar_b, agg2);

    k_final_pre<<<NN / 8, 256, 0, stream>>>(feat, agg2, dec0_w, dec0_b, dec0_g, dec0_bb, dec0_m, dec0_v,
                                            cluster, d0bf, out);
    {
        dim3 grid((NN + 127) / 128, 8);
        k_dec1_mfma<<<grid, 256, 0, stream>>>(d0bf, wt2, dec1_b, out);
    }
}

// Round 11
// 1230.373 us; speedup vs baseline: 1.0846x; 1.0169x over previous
//
#include <hip/hip_runtime.h>
#include <hip/hip_bf16.h>

#define NN 100000
#define NE 1600000
#define DIN 1000
#define BN_EPS 1e-3f
#define NB 391   // ceil(NN/256)

// output element offsets (concat of z, mu, logvar, de_feat, q, feat_x, gnn_z) — float32 out
#define OZ  ((size_t)0)
#define OMU ((size_t)NN*80)
#define OLV ((size_t)NN*96)
#define ODE ((size_t)NN*112)
#define OQ  ((size_t)NN*1112)
#define OFX ((size_t)NN*1127)
#define OGZ ((size_t)NN*1191)

typedef __attribute__((ext_vector_type(8))) short short8v;   // 8 bf16 (4 VGPRs)
typedef __attribute__((ext_vector_type(4))) float f32x4;     // MFMA accumulator

__device__ __forceinline__ float elu_f(float x) { return x > 0.f ? x : expf(x) - 1.f; }

// fp32 -> bf16 bits, round-to-nearest-even
__device__ __forceinline__ short f2bf(float f) {
    union { float f; unsigned u; } c; c.f = f;
    unsigned r = c.u + 0x7fffu + ((c.u >> 16) & 1u);
    return (short)(r >> 16);
}

// Edge index may arrive as int32 or int64; logical element idx in flat (2*E) array.
__device__ __forceinline__ int edge_at(const void* ei, int is64, size_t idx) {
    if (is64) return (int)((const long long*)ei)[idx];
    return ((const int*)ei)[idx];
}

// ---------------- dtype detection ----------------
__global__ __launch_bounds__(256) void k_detect(const int* __restrict__ ei, int* __restrict__ flag) {
    __shared__ int nz;
    if (threadIdx.x == 0) nz = 0;
    __syncthreads();
    for (int i = threadIdx.x; i < 2048; i += 256)
        if (ei[2 * i + 1] != 0) nz = 1;
    __syncthreads();
    if (threadIdx.x == 0) flag[0] = (nz == 0) ? 1 : 0;  // 1 => int64
}

// ---------------- degree ----------------
__global__ __launch_bounds__(256) void k_deg_init(float* __restrict__ deg) {
    int i = blockIdx.x * 256 + threadIdx.x;
    if (i < NN) deg[i] = 1.0f;
}

__global__ __launch_bounds__(256) void k_deg_accum(const void* __restrict__ ei, const int* __restrict__ flag,
                                                   float* __restrict__ deg) {
    const int is64 = flag[0];
    int e = blockIdx.x * 256 + threadIdx.x;
    if (e < NE) atomicAdd(&deg[edge_at(ei, is64, (size_t)NE + e)], 1.0f);
}

// ---------------- CSR build: exclusive scan of in-edge counts ----------------
__global__ __launch_bounds__(256) void k_scan1(const float* __restrict__ deg, int* __restrict__ off,
                                               int* __restrict__ bsum, int* __restrict__ cursor) {
    __shared__ int s[256];
    const int t = threadIdx.x;
    const int i = blockIdx.x * 256 + t;
    const int vv = (i < NN) ? ((int)deg[i]) - 1 : 0;
    if (i < NN) cursor[i] = 0;
    s[t] = vv;
    __syncthreads();
    for (int d = 1; d < 256; d <<= 1) {
        const int u = (t >= d) ? s[t - d] : 0;
        __syncthreads();
        s[t] += u;
        __syncthreads();
    }
    if (i < NN) off[i] = s[t] - vv;           // exclusive, pre-block-offset
    if (t == 255) bsum[blockIdx.x] = s[t];    // block total
}

__global__ __launch_bounds__(512) void k_scan2(int* __restrict__ bsum) {
    __shared__ int s[512];
    const int t = threadIdx.x;
    const int vv = (t < NB) ? bsum[t] : 0;
    s[t] = vv;
    __syncthreads();
    for (int d = 1; d < 512; d <<= 1) {
        const int u = (t >= d) ? s[t - d] : 0;
        __syncthreads();
        s[t] += u;
        __syncthreads();
    }
    if (t < NB) bsum[t] = s[t] - vv;          // exclusive block prefix
}

__global__ __launch_bounds__(256) void k_scan3(int* __restrict__ off, const int* __restrict__ bsum) {
    const int i = blockIdx.x * 256 + threadIdx.x;
    if (i < NN) off[i] += bsum[blockIdx.x];
}

__global__ __launch_bounds__(256) void k_fill(const void* __restrict__ ei, const int* __restrict__ flag,
                                              const float* __restrict__ deg, const int* __restrict__ off,
                                              int* __restrict__ cursor,
                                              int* __restrict__ csr_src, float* __restrict__ csr_w) {
    const int is64 = flag[0];
    const int e = blockIdx.x * 256 + threadIdx.x;
    if (e >= NE) return;
    const int r = edge_at(ei, is64, e);
    const int c = edge_at(ei, is64, (size_t)NE + e);
    const float w = rsqrtf(deg[r]) * rsqrtf(deg[c]);
    const int p = atomicAdd(&cursor[c], 1);
    const int slot = off[c] + p;
    csr_src[slot] = r;
    csr_w[slot] = w;
}

// ---------------- enc0 weight prep: w[1000][256] f32 -> k-major bf16 granules ----------------
// Granule layout: wt[((k>>3)*256 + c)*8 + (k&7)], k zero-padded to 1024.
__global__ __launch_bounds__(256) void k_wt(const float* __restrict__ w, short* __restrict__ wt) {
    const int tid = blockIdx.x * 256 + threadIdx.x;   // 256*1024 elements
    const int c = tid >> 10;
    const int k = tid & 1023;
    wt[((size_t)(k >> 3) * 256 + c) * 8 + (k & 7)] = (k < DIN) ? f2bf(w[(size_t)k * 256 + c]) : (short)0;
}

// ---------------- dec1 weight prep: w[64][1000] f32 -> wt2[1024][64] bf16 (cols zero-padded) ----------------
__global__ __launch_bounds__(256) void k_wt2(const float* __restrict__ w, short* __restrict__ wt2) {
    const int tid = blockIdx.x * 256 + threadIdx.x;   // 1024*64 elements
    const int c = tid >> 6;
    const int k = tid & 63;
    wt2[(size_t)c * 64 + k] = (c < DIN) ? f2bf(w[(size_t)k * DIN + c]) : (short)0;
}

// ---------------- encoder L0 via MFMA: h1 = ELU(BN(x @ w)) ----------------
// Block tile 128x256 (ALL output cols -> x read once), 8 waves (2 row x 4 col),
// wave tile 64x64 (4x4 frags of 16x16x32), K_STEP=32.
__global__ __launch_bounds__(512, 2) void k_enc0_mfma(
    const float* __restrict__ x, const short* __restrict__ wt, const float* __restrict__ bias,
    const float* __restrict__ g, const float* __restrict__ bb,
    const float* __restrict__ m, const float* __restrict__ v,
    float* __restrict__ h1)
{
    __shared__ short As[4 * 128 * 8];
    __shared__ short Bs[4 * 256 * 8];
    const int t = threadIdx.x;           // 0..511
    const int lane = t & 63;
    const int wave = t >> 6;             // 0..7
    const int wm = (wave >> 2) * 64;     // 0,64
    const int wn = (wave & 3) * 64;      // 0,64,128,192
    const int row0 = blockIdx.x * 128;

    f32x4 acc[4][4];
    #pragma unroll
    for (int mi = 0; mi < 4; ++mi)
        #pragma unroll
        for (int ni = 0; ni < 4; ++ni)
            acc[mi][ni] = (f32x4){0.f, 0.f, 0.f, 0.f};

    const int rowA = t & 127;
    const int kcA = t >> 7;
    const bool rowA_ok = (row0 + rowA) < NN;
    const float* xrow = x + (size_t)(row0 + rowA) * DIN;
    short* aslot = &As[((size_t)kcA * 128 + rowA) * 8];
    const int colB = t & 255;
    const int kcB0 = t >> 8;
    const int kcB1 = 2 + (t >> 8);

    const int kc = lane >> 4;    // 0..3
    const int lr = lane & 15;

    for (int ks = 0; ks < 32; ++ks) {
        const int k0 = ks * 32;
        __syncthreads();
        // ---- stage A (x fp32 -> bf16), 8 k per thread ----
        {
            const int kb = k0 + kcA * 8;
            short8v p;
            if (rowA_ok && kb + 8 <= DIN) {
                const float4 f0 = *reinterpret_cast<const float4*>(xrow + kb);
                const float4 f1 = *reinterpret_cast<const float4*>(xrow + kb + 4);
                p[0] = f2bf(f0.x); p[1] = f2bf(f0.y); p[2] = f2bf(f0.z); p[3] = f2bf(f0.w);
                p[4] = f2bf(f1.x); p[5] = f2bf(f1.y); p[6] = f2bf(f1.z); p[7] = f2bf(f1.w);
            } else if (rowA_ok) {
                #pragma unroll
                for (int j = 0; j < 8; ++j)
                    p[j] = (kb + j < DIN) ? f2bf(xrow[kb + j]) : (short)0;
            } else {
                #pragma unroll
                for (int j = 0; j < 8; ++j) p[j] = 0;
            }
            *reinterpret_cast<short8v*>(aslot) = p;
        }
        // ---- stage B (wt k-major granules, coalesced) ----
        {
            const int gbase = ks * 4;   // k0>>3
            *reinterpret_cast<short8v*>(&Bs[((size_t)kcB0 * 256 + colB) * 8]) =
                *reinterpret_cast<const short8v*>(&wt[((size_t)(gbase + kcB0) * 256 + colB) * 8]);
            *reinterpret_cast<short8v*>(&Bs[((size_t)kcB1 * 256 + colB) * 8]) =
                *reinterpret_cast<const short8v*>(&wt[((size_t)(gbase + kcB1) * 256 + colB) * 8]);
        }
        __syncthreads();
        // ---- fragments + MFMA ----
        short8v a[4], b[4];
        #pragma unroll
        for (int mi = 0; mi < 4; ++mi)
            a[mi] = *reinterpret_cast<const short8v*>(&As[((size_t)kc * 128 + wm + mi * 16 + lr) * 8]);
        #pragma unroll
        for (int ni = 0; ni < 4; ++ni)
            b[ni] = *reinterpret_cast<const short8v*>(&Bs[((size_t)kc * 256 + wn + ni * 16 + lr) * 8]);
        #pragma unroll
        for (int mi = 0; mi < 4; ++mi)
            #pragma unroll
            for (int ni = 0; ni < 4; ++ni)
                acc[mi][ni] = __builtin_amdgcn_mfma_f32_16x16x32_bf16(a[mi], b[ni], acc[mi][ni], 0, 0, 0);
    }

    // ---- epilogue: BN + ELU, C/D layout col=lane&15, row=(lane>>4)*4+reg ----
    float sc[4], sh[4];
    int cols[4];
    #pragma unroll
    for (int ni = 0; ni < 4; ++ni) {
        const int col = wn + ni * 16 + lr;
        cols[ni] = col;
        const float s = rsqrtf(v[col] + BN_EPS) * g[col];
        sc[ni] = s;
        sh[ni] = (bias[col] - m[col]) * s + bb[col];
    }
    #pragma unroll
    for (int mi = 0; mi < 4; ++mi) {
        #pragma unroll
        for (int j = 0; j < 4; ++j) {
            const int row = row0 + wm + mi * 16 + (lane >> 4) * 4 + j;
            if (row < NN) {
                #pragma unroll
                for (int ni = 0; ni < 4; ++ni) {
                    const float y = acc[mi][ni][j] * sc[ni] + sh[ni];
                    h1[(size_t)row * 256 + cols[ni]] = elu_f(y);
                }
            }
        }
    }
}

// ---------------- encoder L1: h1[N,256] @ w[256,64] + BN + ELU -> feat, out ----------------
__global__ __launch_bounds__(256) void k_enc1(
    const float* __restrict__ h1, const float* __restrict__ w, const float* __restrict__ bias,
    const float* __restrict__ g, const float* __restrict__ bb,
    const float* __restrict__ m, const float* __restrict__ v,
    float* __restrict__ feat, float* __restrict__ out)
{
    __shared__ float hs[32 * 256];
    const int t = threadIdx.x;
    const int row0 = blockIdx.x * 32;
    const int j0 = t & 31;
    const int r0 = (t >> 5) * 4;
    float acc[4][2] = {};
    for (int idx = t; idx < 2048; idx += 256) {
        const int r = idx >> 6, c4 = idx & 63;
        *reinterpret_cast<float4*>(&hs[r * 256 + c4 * 4]) =
            *reinterpret_cast<const float4*>(&h1[(size_t)(row0 + r) * 256 + c4 * 4]);
    }
    __syncthreads();
    #pragma unroll 1
    for (int k = 0; k < 256; k += 4) {
        float wv[4][2];
        #pragma unroll
        for (int kk = 0; kk < 4; ++kk) {
            wv[kk][0] = w[(k + kk) * 64 + j0];
            wv[kk][1] = w[(k + kk) * 64 + j0 + 32];
        }
        #pragma unroll
        for (int r = 0; r < 4; ++r) {
            const float4 xv = *reinterpret_cast<const float4*>(&hs[(r0 + r) * 256 + k]);
            const float xa[4] = {xv.x, xv.y, xv.z, xv.w};
            #pragma unroll
            for (int kk = 0; kk < 4; ++kk) {
                acc[r][0] = fmaf(xa[kk], wv[kk][0], acc[r][0]);
                acc[r][1] = fmaf(xa[kk], wv[kk][1], acc[r][1]);
            }
        }
    }
    #pragma unroll
    for (int c = 0; c < 2; ++c) {
        const int j = j0 + 32 * c;
        const float sc = rsqrtf(v[j] + BN_EPS) * g[j];
        const float sh = (bias[j] - m[j]) * sc + bb[j];
        #pragma unroll
        for (int r = 0; r < 4; ++r) {
            const size_t rowi = row0 + r0 + r;
            const float y = elu_f(acc[r][c] * sc + sh);
            feat[rowi * 64 + j] = y;
            out[OFX + rowi * 64 + j] = y;
            out[OZ + rowi * 80 + j] = y;
        }
    }
}

// ---------------- GCN: gather feat (64-dim) FIRST (linearity of aggregation) ----------------
// aggF[node] = feat[node]/deg + sum_e ew*feat[src]
__global__ __launch_bounds__(256) void k_feat_gather(
    const float* __restrict__ feat, const float* __restrict__ deg,
    const int* __restrict__ off, const int* __restrict__ csr_src, const float* __restrict__ csr_w,
    float* __restrict__ aggF)
{
    const int t = threadIdx.x;
    const int node = blockIdx.x * 4 + (t >> 6);   // grid = NN/4
    const int lane = t & 63;
    const float dg = deg[node];
    float acc = feat[(size_t)node * 64 + lane] * (1.0f / dg);
    const int beg = off[node];
    const int end = beg + ((int)dg - 1);
    for (int s = beg; s < end; ++s) {
        const int src = csr_src[s];
        const float w = csr_w[s];
        acc = fmaf(feat[(size_t)src * 64 + lane], w, acc);
    }
    aggF[(size_t)node * 64 + lane] = acc;
}

// ---------------- conv projection fused: cmat = ReLU(BN(aggF @ conv_w + cb)) ----------------
__global__ __launch_bounds__(256) void k_conv_proj(
    const float* __restrict__ aggF, const float* __restrict__ w, const float* __restrict__ cb,
    const float* __restrict__ g, const float* __restrict__ bb,
    const float* __restrict__ m, const float* __restrict__ v,
    float* __restrict__ cmat)
{
    __shared__ float fs[32 * 64];
    const int t = threadIdx.x;
    const int row0 = blockIdx.x * 32;
    const int j0 = t & 63;
    const int r0 = (t >> 6) * 8;
    float acc[8][2] = {};
    for (int idx = t; idx < 512; idx += 256) {
        const int r = idx >> 4, c4 = idx & 15;
        *reinterpret_cast<float4*>(&fs[r * 64 + c4 * 4]) =
            *reinterpret_cast<const float4*>(&aggF[(size_t)(row0 + r) * 64 + c4 * 4]);
    }
    __syncthreads();
    #pragma unroll 1
    for (int k = 0; k < 64; k += 4) {
        float wv[4][2];
        #pragma unroll
        for (int kk = 0; kk < 4; ++kk) {
            wv[kk][0] = w[(k + kk) * 128 + j0];
            wv[kk][1] = w[(k + kk) * 128 + j0 + 64];
        }
        #pragma unroll
        for (int r = 0; r < 8; ++r) {
            const float4 xv = *reinterpret_cast<const float4*>(&fs[(r0 + r) * 64 + k]);
            const float xa[4] = {xv.x, xv.y, xv.z, xv.w};
            #pragma unroll
            for (int kk = 0; kk < 4; ++kk) {
                acc[r][0] = fmaf(xa[kk], wv[kk][0], acc[r][0]);
                acc[r][1] = fmaf(xa[kk], wv[kk][1], acc[r][1]);
            }
        }
    }
    #pragma unroll
    for (int c = 0; c < 2; ++c) {
        const int j = j0 + 64 * c;
        const float sc = rsqrtf(v[j] + BN_EPS) * g[j];
        const float sh = bb[j] - m[j] * sc;
        const float cbj = cb[j];
        #pragma unroll
        for (int r = 0; r < 8; ++r) {
            const size_t rowi = row0 + r0 + r;
            const float val = acc[r][c] + cbj;
            cmat[rowi * 128 + j] = fmaxf(fmaf(val, sc, sh), 0.f);
        }
    }
}

// ---------------- mean|logvar projection: c[N,128] @ [mw|lw][128,16+16] -> m2 ----------------
__global__ __launch_bounds__(256) void k_mlp_proj(
    const float* __restrict__ c, const float* __restrict__ mw, const float* __restrict__ lw,
    float* __restrict__ m2)
{
    __shared__ float cs[32 * 128];
    const int t = threadIdx.x;
    const int row0 = blockIdx.x * 32;
    const int j0 = t & 15;
    const int r0 = (t >> 4) * 2;
    float acc[2][2] = {};
    for (int idx = t; idx < 1024; idx += 256) {
        const int r = idx >> 5, c4 = idx & 31;
        *reinterpret_cast<float4*>(&cs[r * 128 + c4 * 4]) =
            *reinterpret_cast<const float4*>(&c[(size_t)(row0 + r) * 128 + c4 * 4]);
    }
    __syncthreads();
    #pragma unroll 1
    for (int k = 0; k < 128; k += 4) {
        float wv[4][2];
        #pragma unroll
        for (int kk = 0; kk < 4; ++kk) {
            wv[kk][0] = mw[(k + kk) * 16 + j0];
            wv[kk][1] = lw[(k + kk) * 16 + j0];
        }
        #pragma unroll
        for (int r = 0; r < 2; ++r) {
            const float4 xv = *reinterpret_cast<const float4*>(&cs[(r0 + r) * 128 + k]);
            const float xa[4] = {xv.x, xv.y, xv.z, xv.w};
            #pragma unroll
            for (int kk = 0; kk < 4; ++kk) {
                acc[r][0] = fmaf(xa[kk], wv[kk][0], acc[r][0]);
                acc[r][1] = fmaf(xa[kk], wv[kk][1], acc[r][1]);
            }
        }
    }
    #pragma unroll
    for (int r = 0; r < 2; ++r) {
        const size_t rowi = row0 + r0 + r;
        m2[rowi * 32 + j0] = acc[r][0];
        m2[rowi * 32 + 16 + j0] = acc[r][1];
    }
}

// ---------------- CSR gather for mean|logvar (32 feats) + self-loop + bias ----------------
__global__ __launch_bounds__(256) void k_mlp_gather(
    const float* __restrict__ m2, const float* __restrict__ deg,
    const int* __restrict__ off, const int* __restrict__ csr_src, const float* __restrict__ csr_w,
    const float* __restrict__ mb, const float* __restrict__ lb,
    float* __restrict__ agg2)
{
    const int t = threadIdx.x;
    const int node = blockIdx.x * 8 + (t >> 5);   // grid = NN/8
    const int lane = t & 31;
    const float dg = deg[node];
    const float dinv = 1.0f / dg;
    const float bias = (lane < 16) ? mb[lane] : lb[lane - 16];
    float acc = fmaf(m2[(size_t)node * 32 + lane], dinv, bias);
    const int beg = off[node];
    const int end = beg + ((int)dg - 1);
    for (int s = beg; s < end; ++s) {
        const int src = csr_src[s];
        const float w = csr_w[s];
        acc = fmaf(m2[(size_t)src * 32 + lane], w, acc);
    }
    agg2[(size_t)node * 32 + lane] = acc;
}

// ---------------- finalize pre: mu/logvar/z writes, dec0 -> d0bf (bf16), q ----------------
__global__ __launch_bounds__(256) void k_final_pre(
    const float* __restrict__ feat, const float* __restrict__ agg2,
    const float* __restrict__ d0w, const float* __restrict__ d0b,
    const float* __restrict__ g, const float* __restrict__ bb,
    const float* __restrict__ m, const float* __restrict__ v,
    const float* __restrict__ cluster,
    short* __restrict__ d0bf,
    float* __restrict__ out)
{
    __shared__ float zs[8][80];
    __shared__ float qs[8][15];
    const int t = threadIdx.x;
    const int row0 = blockIdx.x * 8;

    for (int idx = t; idx < 512; idx += 256) {
        const int r = idx >> 6, k = idx & 63;
        zs[r][k] = feat[(size_t)(row0 + r) * 64 + k];
    }
    if (t < 128) {
        const int r = t >> 4, k = t & 15;
        const size_t rowi = row0 + r;
        const float muv = agg2[rowi * 32 + k];
        const float lv = agg2[rowi * 32 + 16 + k];
        zs[r][64 + k] = muv;
        out[OMU + rowi * 16 + k] = muv;
        out[OGZ + rowi * 16 + k] = muv;
        out[OZ + rowi * 80 + 64 + k] = muv;
        out[OLV + rowi * 16 + k] = lv;
    }
    __syncthreads();

    // dec0: d0 = ELU(BN(z @ d0w + d0b)) -> bf16 global
    for (int idx = t; idx < 512; idx += 256) {
        const int r = idx >> 6, n = idx & 63;
        float acc = 0.f;
        #pragma unroll
        for (int k = 0; k < 80; k += 4) {
            const float4 zv = *reinterpret_cast<const float4*>(&zs[r][k]);
            acc = fmaf(zv.x, d0w[(k + 0) * 64 + n], acc);
            acc = fmaf(zv.y, d0w[(k + 1) * 64 + n], acc);
            acc = fmaf(zv.z, d0w[(k + 2) * 64 + n], acc);
            acc = fmaf(zv.w, d0w[(k + 3) * 64 + n], acc);
        }
        acc += d0b[n];
        const float sc = rsqrtf(v[n] + BN_EPS) * g[n];
        const float y = elu_f((acc - m[n]) * sc + bb[n]);
        d0bf[(size_t)(row0 + r) * 64 + n] = f2bf(y);
    }

    // student-t q
    if (t < 120) {
        const int r = t / 15, c = t % 15;
        float zz = 0.f, cc = 0.f, dot = 0.f;
        #pragma unroll 1
        for (int k = 0; k < 80; ++k) {
            const float zv = zs[r][k];
            const float cv = cluster[c * 80 + k];
            zz = fmaf(zv, zv, zz);
            cc = fmaf(cv, cv, cc);
            dot = fmaf(zv, cv, dot);
        }
        const float dist = fmaxf(zz + cc - 2.f * dot, 0.f);
        qs[r][c] = powf(1.0f / (1.0f + dist / 0.9f + 1e-8f), 0.95f);
    }
    __syncthreads();
    if (t < 120) {
        const int r = t / 15, c = t % 15;
        float s = 0.f;
        #pragma unroll
        for (int c2 = 0; c2 < 15; ++c2) s += qs[r][c2];
        out[OQ + (size_t)(row0 + r) * 15 + c] = qs[r][c] / s;
    }
}

// ---------------- dec1 via MFMA: de_feat = d0 @ d1w + d1b ----------------
// 128x128 tiles, 4 waves 2x2, K=64 (2 ksteps), fragments direct from global (L2-resident).
__global__ __launch_bounds__(256) void k_dec1_mfma(
    const short* __restrict__ d0bf, const short* __restrict__ wt2,
    const float* __restrict__ d1b, float* __restrict__ out)
{
    const int t = threadIdx.x;
    const int lane = t & 63;
    const int wave = t >> 6;
    const int wm = (wave >> 1) * 64;
    const int wn = (wave & 1) * 64;
    const int row0 = blockIdx.x * 128;
    const int col0 = blockIdx.y * 128;
    const int kc = lane >> 4;
    const int lr = lane & 15;

    f32x4 acc[4][4];
    #pragma unroll
    for (int mi = 0; mi < 4; ++mi)
        #pragma unroll
        for (int ni = 0; ni < 4; ++ni)
            acc[mi][ni] = (f32x4){0.f, 0.f, 0.f, 0.f};

    #pragma unroll
    for (int ks = 0; ks < 2; ++ks) {
        const int k0 = ks * 32 + kc * 8;
        short8v a[4], b[4];
        #pragma unroll
        for (int mi = 0; mi < 4; ++mi) {
            const int row = row0 + wm + mi * 16 + lr;
            if (row < NN)
                a[mi] = *reinterpret_cast<const short8v*>(&d0bf[(size_t)row * 64 + k0]);
            else
                a[mi] = (short8v){0, 0, 0, 0, 0, 0, 0, 0};
        }
        #pragma unroll
        for (int ni = 0; ni < 4; ++ni) {
            const int col = col0 + wn + ni * 16 + lr;
            b[ni] = *reinterpret_cast<const short8v*>(&wt2[(size_t)col * 64 + k0]);
        }
        #pragma unroll
        for (int mi = 0; mi < 4; ++mi)
            #pragma unroll
            for (int ni = 0; ni < 4; ++ni)
                acc[mi][ni] = __builtin_amdgcn_mfma_f32_16x16x32_bf16(a[mi], b[ni], acc[mi][ni], 0, 0, 0);
    }

    // epilogue: +bias, write de_feat (C/D: col=lane&15 within frag, row=(lane>>4)*4+j)
    #pragma unroll
    for (int ni = 0; ni < 4; ++ni) {
        const int col = col0 + wn + ni * 16 + lr;
        if (col < DIN) {
            const float bv = d1b[col];
            #pragma unroll
            for (int mi = 0; mi < 4; ++mi) {
                #pragma unroll
                for (int j = 0; j < 4; ++j) {
                    const int row = row0 + wm + mi * 16 + (lane >> 4) * 4 + j;
                    if (row < NN)
                        out[ODE + (size_t)row * DIN + col] = acc[mi][ni][j] + bv;
                }
            }
        }
    }
}

extern "C" void kernel_launch(void* const* d_in, const int* in_sizes, int n_in,
                              void* d_out, int out_size, void* d_ws, size_t ws_size,
                              hipStream_t stream)
{
    const float* x       = (const float*)d_in[0];
    const void*  ei      = d_in[1];
    const float* enc0_w  = (const float*)d_in[2];
    const float* enc0_b  = (const float*)d_in[3];
    const float* enc0_g  = (const float*)d_in[4];
    const float* enc0_bb = (const float*)d_in[5];
    const float* enc0_m  = (const float*)d_in[6];
    const float* enc0_v  = (const float*)d_in[7];
    const float* enc1_w  = (const float*)d_in[8];
    const float* enc1_b  = (const float*)d_in[9];
    const float* enc1_g  = (const float*)d_in[10];
    const float* enc1_bb = (const float*)d_in[11];
    const float* enc1_m  = (const float*)d_in[12];
    const float* enc1_v  = (const float*)d_in[13];
    const float* conv_w  = (const float*)d_in[14];
    const float* conv_b  = (const float*)d_in[15];
    const float* conv_g  = (const float*)d_in[16];
    const float* conv_bb = (const float*)d_in[17];
    const float* conv_m  = (const float*)d_in[18];
    const float* conv_v  = (const float*)d_in[19];
    const float* mean_w  = (const float*)d_in[20];
    const float* mean_b  = (const float*)d_in[21];
    const float* logvar_w = (const float*)d_in[22];
    const float* logvar_b = (const float*)d_in[23];
    const float* dec0_w  = (const float*)d_in[24];
    const float* dec0_b  = (const float*)d_in[25];
    const float* dec0_g  = (const float*)d_in[26];
    const float* dec0_bb = (const float*)d_in[27];
    const float* dec0_m  = (const float*)d_in[28];
    const float* dec0_v  = (const float*)d_in[29];
    const float* dec1_w  = (const float*)d_in[30];
    const float* dec1_b  = (const float*)d_in[31];
    const float* cluster = (const float*)d_in[32];

    float* ws = (float*)d_ws;
    float* deg  = ws;                              // N
    float* feat = ws + NN;                         // 64N
    float* A    = ws + (size_t)65 * NN;            // 256N: h1 | aggF+cmat | m2+agg2+d0bf
    size_t base = (size_t)321 * NN;
    int*   off     = (int*)(ws + base);                        // N
    int*   cursor  = (int*)(ws + base + NN);                   // N
    int*   bsum    = (int*)(ws + base + 2 * (size_t)NN);       // 512
    int*   csr_src = (int*)(ws + base + 2 * (size_t)NN + 512);             // E
    float* csr_w   = (float*)(ws + base + 2 * (size_t)NN + 512 + NE);      // E
    short* wt      = (short*)(ws + base + 2 * (size_t)NN + 512 + 2 * (size_t)NE);  // 256*1024 bf16
    int*   flag    = (int*)(ws + base + 2 * (size_t)NN + 512 + 2 * (size_t)NE + 131072); // 1

    float* h1   = A;                      // N x 256
    float* aggF = A;                      // N x 64 (after h1 dead)
    float* cmat = A + (size_t)128 * NN;   // N x 128
    float* m2   = A;                      // N x 32 (after aggF dead)
    float* agg2 = A + (size_t)32 * NN;    // N x 32
    short* d0bf = (short*)(A + (size_t)64 * NN);   // N x 64 bf16
    short* wt2  = wt;                     // 1024 x 64 bf16 (reuses enc0 wt)

    float* out = (float*)d_out;

    k_detect<<<1, 256, 0, stream>>>((const int*)ei, flag);
    k_deg_init<<<NB, 256, 0, stream>>>(deg);
    k_deg_accum<<<NE / 256, 256, 0, stream>>>(ei, flag, deg);

    // CSR build
    k_scan1<<<NB, 256, 0, stream>>>(deg, off, bsum, cursor);
    k_scan2<<<1, 512, 0, stream>>>(bsum);
    k_scan3<<<NB, 256, 0, stream>>>(off, bsum);
    k_fill<<<NE / 256, 256, 0, stream>>>(ei, flag, deg, off, cursor, csr_src, csr_w);

    // enc0 via MFMA (single pass over x: block tile 128x256)
    k_wt<<<1024, 256, 0, stream>>>(enc0_w, wt);
    k_enc0_mfma<<<(NN + 127) / 128, 512, 0, stream>>>(x, wt, enc0_b, enc0_g, enc0_bb, enc0_m, enc0_v, h1);
    // dec1 weight prep (reuses wt buffer — enc0 done with it)
    k_wt2<<<256, 256, 0, stream>>>(dec1_w, wt2);

    k_enc1<<<NN / 32, 256, 0, stream>>>(h1, enc1_w, enc1_b, enc1_g, enc1_bb, enc1_m, enc1_v, feat, out);

    // GCN conv: aggregate 64-dim feat first (linearity), then fused proj+BN+ReLU
    k_feat_gather<<<NN / 4, 256, 0, stream>>>(feat, deg, off, csr_src, csr_w, aggF);
    k_conv_proj<<<NN / 32, 256, 0, stream>>>(aggF, conv_w, conv_b,
                                             conv_g, conv_bb, conv_m, conv_v, cmat);

    k_mlp_proj<<<NN / 32, 256, 0, stream>>>(cmat, mean_w, logvar_w, m2);
    k_mlp_gather<<<NN / 8, 256, 0, stream>>>(m2, deg, off, csr_src, csr_w, mean_b, logvar_b, agg2);

    k_final_pre<<<NN / 8, 256, 0, stream>>>(feat, agg2, dec0_w, dec0_b, dec0_g, dec0_bb, dec0_m, dec0_v,
                                            cluster, d0bf, out);
    {
        dim3 grid((NN + 127) / 128, 8);
        k_dec1_mfma<<<grid, 256, 0, stream>>>(d0bf, wt2, dec1_b, out);
    }
}

// Round 14
// 1215.320 us; speedup vs baseline: 1.0980x; 1.0124x over previous
//
#include <hip/hip_runtime.h>
#include <hip/hip_bf16.h>

#define NN 100000
#define NE 1600000
#define DIN 1000
#define BN_EPS 1e-3f
#define NB 391   // ceil(NN/256)

// output element offsets (concat of z, mu, logvar, de_feat, q, feat_x, gnn_z) — float32 out
#define OZ  ((size_t)0)
#define OMU ((size_t)NN*80)
#define OLV ((size_t)NN*96)
#define ODE ((size_t)NN*112)
#define OQ  ((size_t)NN*1112)
#define OFX ((size_t)NN*1127)
#define OGZ ((size_t)NN*1191)

typedef __attribute__((ext_vector_type(8))) short short8v;   // 8 bf16 (4 VGPRs)
typedef __attribute__((ext_vector_type(4))) float f32x4;     // MFMA accumulator

__device__ __forceinline__ float elu_f(float x) { return x > 0.f ? x : expf(x) - 1.f; }

// fp32 -> bf16 bits, round-to-nearest-even
__device__ __forceinline__ short f2bf(float f) {
    union { float f; unsigned u; } c; c.f = f;
    unsigned r = c.u + 0x7fffu + ((c.u >> 16) & 1u);
    return (short)(r >> 16);
}
// bf16 bits -> fp32
__device__ __forceinline__ float b2f(short s) {
    union { unsigned u; float f; } c; c.u = ((unsigned)(unsigned short)s) << 16; return c.f;
}

// Edge index may arrive as int32 or int64; logical element idx in flat (2*E) array.
__device__ __forceinline__ int edge_at(const void* ei, int is64, size_t idx) {
    if (is64) return (int)((const long long*)ei)[idx];
    return ((const int*)ei)[idx];
}

// ---------------- dtype detection ----------------
__global__ __launch_bounds__(256) void k_detect(const int* __restrict__ ei, int* __restrict__ flag) {
    __shared__ int nz;
    if (threadIdx.x == 0) nz = 0;
    __syncthreads();
    for (int i = threadIdx.x; i < 2048; i += 256)
        if (ei[2 * i + 1] != 0) nz = 1;
    __syncthreads();
    if (threadIdx.x == 0) flag[0] = (nz == 0) ? 1 : 0;  // 1 => int64
}

// ---------------- degree ----------------
__global__ __launch_bounds__(256) void k_deg_init(float* __restrict__ deg) {
    int i = blockIdx.x * 256 + threadIdx.x;
    if (i < NN) deg[i] = 1.0f;
}

__global__ __launch_bounds__(256) void k_deg_accum(const void* __restrict__ ei, const int* __restrict__ flag,
                                                   float* __restrict__ deg) {
    const int is64 = flag[0];
    int e = blockIdx.x * 256 + threadIdx.x;
    if (e < NE) atomicAdd(&deg[edge_at(ei, is64, (size_t)NE + e)], 1.0f);
}

// ---------------- CSR build: exclusive scan of in-edge counts ----------------
__global__ __launch_bounds__(256) void k_scan1(const float* __restrict__ deg, int* __restrict__ off,
                                               int* __restrict__ bsum, int* __restrict__ cursor) {
    __shared__ int s[256];
    const int t = threadIdx.x;
    const int i = blockIdx.x * 256 + t;
    const int vv = (i < NN) ? ((int)deg[i]) - 1 : 0;
    if (i < NN) cursor[i] = 0;
    s[t] = vv;
    __syncthreads();
    for (int d = 1; d < 256; d <<= 1) {
        const int u = (t >= d) ? s[t - d] : 0;
        __syncthreads();
        s[t] += u;
        __syncthreads();
    }
    if (i < NN) off[i] = s[t] - vv;           // exclusive, pre-block-offset
    if (t == 255) bsum[blockIdx.x] = s[t];    // block total
}

__global__ __launch_bounds__(512) void k_scan2(int* __restrict__ bsum) {
    __shared__ int s[512];
    const int t = threadIdx.x;
    const int vv = (t < NB) ? bsum[t] : 0;
    s[t] = vv;
    __syncthreads();
    for (int d = 1; d < 512; d <<= 1) {
        const int u = (t >= d) ? s[t - d] : 0;
        __syncthreads();
        s[t] += u;
        __syncthreads();
    }
    if (t < NB) bsum[t] = s[t] - vv;          // exclusive block prefix
}

__global__ __launch_bounds__(256) void k_scan3(int* __restrict__ off, const int* __restrict__ bsum) {
    const int i = blockIdx.x * 256 + threadIdx.x;
    if (i < NN) off[i] += bsum[blockIdx.x];
}

__global__ __launch_bounds__(256) void k_fill(const void* __restrict__ ei, const int* __restrict__ flag,
                                              const float* __restrict__ deg, const int* __restrict__ off,
                                              int* __restrict__ cursor,
                                              int* __restrict__ csr_src, float* __restrict__ csr_w) {
    const int is64 = flag[0];
    const int e = blockIdx.x * 256 + threadIdx.x;
    if (e >= NE) return;
    const int r = edge_at(ei, is64, e);
    const int c = edge_at(ei, is64, (size_t)NE + e);
    const float w = rsqrtf(deg[r]) * rsqrtf(deg[c]);
    const int p = atomicAdd(&cursor[c], 1);
    const int slot = off[c] + p;
    csr_src[slot] = r;
    csr_w[slot] = w;
}

// ---------------- enc0 weight prep: w[1000][256] f32 -> k-major bf16 granules ----------------
// Granule layout: wt[((k>>3)*256 + c)*8 + (k&7)], k zero-padded to 1024.
__global__ __launch_bounds__(256) void k_wt(const float* __restrict__ w, short* __restrict__ wt) {
    const int tid = blockIdx.x * 256 + threadIdx.x;   // 256*1024 elements
    const int c = tid >> 10;
    const int k = tid & 1023;
    wt[((size_t)(k >> 3) * 256 + c) * 8 + (k & 7)] = (k < DIN) ? f2bf(w[(size_t)k * 256 + c]) : (short)0;
}

// ---------------- dec1 weight prep: w[64][1000] f32 -> wt2[1024][64] bf16 (cols zero-padded) ----------------
__global__ __launch_bounds__(256) void k_wt2(const float* __restrict__ w, short* __restrict__ wt2) {
    const int tid = blockIdx.x * 256 + threadIdx.x;   // 1024*64 elements
    const int c = tid >> 6;
    const int k = tid & 63;
    wt2[(size_t)c * 64 + k] = (c < DIN) ? f2bf(w[(size_t)k * DIN + c]) : (short)0;
}

// ---------------- encoder L0 via MFMA: h1bf = bf16(ELU(BN(x @ w))) ----------------
// Block tile 128x256, 8 waves (2 row x 4 col), wave tile 64x64, K_STEP=32.
// A-stream register-prefetch (T14): issue ks+1 x-loads into VGPRs before the
// compute barrier; __syncthreads does not drain VGPR-destination loads, so the
// ~900cy HBM latency hides under the 64 MFMAs of step ks.
__global__ __launch_bounds__(512, 2) void k_enc0_mfma(
    const float* __restrict__ x, const short* __restrict__ wt, const float* __restrict__ bias,
    const float* __restrict__ g, const float* __restrict__ bb,
    const float* __restrict__ m, const float* __restrict__ v,
    short* __restrict__ h1bf)
{
    __shared__ short As[4 * 128 * 8];
    __shared__ short Bs[4 * 256 * 8];
    const int t = threadIdx.x;           // 0..511
    const int lane = t & 63;
    const int wave = t >> 6;             // 0..7
    const int wm = (wave >> 2) * 64;     // 0,64
    const int wn = (wave & 3) * 64;      // 0,64,128,192
    const int row0 = blockIdx.x * 128;

    f32x4 acc[4][4];
    #pragma unroll
    for (int mi = 0; mi < 4; ++mi)
        #pragma unroll
        for (int ni = 0; ni < 4; ++ni)
            acc[mi][ni] = (f32x4){0.f, 0.f, 0.f, 0.f};

    // A staging: thread t owns granule (kcA = t>>7, rowA = t&127); DIN=1000 is
    // granule-aligned (125 granules) so every granule is fully in or fully out.
    const int rowA = t & 127;
    const int kcA = t >> 7;
    const int rowclamp = (row0 + rowA < NN) ? (row0 + rowA) : (NN - 1);
    const float* xrow = x + (size_t)rowclamp * DIN;
    short* aslot = &As[((size_t)kcA * 128 + rowA) * 8];
    const int colB = t & 255;
    const int kcB0 = t >> 8;
    const int kcB1 = 2 + (t >> 8);

    const int kc = lane >> 4;    // 0..3
    const int lr = lane & 15;

    // prologue: prefetch ks=0 (kb = kcA*8 <= 24, always in-bounds)
    float4 pf0 = *reinterpret_cast<const float4*>(xrow + kcA * 8);
    float4 pf1 = *reinterpret_cast<const float4*>(xrow + kcA * 8 + 4);

    for (int ks = 0; ks < 32; ++ks) {
        __syncthreads();   // LDS free to overwrite
        // ---- store A granule from prefetch regs (convert fp32->bf16) ----
        {
            const int kb = ks * 32 + kcA * 8;
            short8v p;
            if (kb + 8 <= DIN) {
                p[0] = f2bf(pf0.x); p[1] = f2bf(pf0.y); p[2] = f2bf(pf0.z); p[3] = f2bf(pf0.w);
                p[4] = f2bf(pf1.x); p[5] = f2bf(pf1.y); p[6] = f2bf(pf1.z); p[7] = f2bf(pf1.w);
            } else {
                #pragma unroll
                for (int j = 0; j < 8; ++j) p[j] = 0;
            }
            *reinterpret_cast<short8v*>(aslot) = p;
        }
        // ---- stage B (wt k-major granules, L2-resident) ----
        {
            const int gbase = ks * 4;   // k0>>3
            *reinterpret_cast<short8v*>(&Bs[((size_t)kcB0 * 256 + colB) * 8]) =
                *reinterpret_cast<const short8v*>(&wt[((size_t)(gbase + kcB0) * 256 + colB) * 8]);
            *reinterpret_cast<short8v*>(&Bs[((size_t)kcB1 * 256 + colB) * 8]) =
                *reinterpret_cast<const short8v*>(&wt[((size_t)(gbase + kcB1) * 256 + colB) * 8]);
        }
        // ---- issue A prefetch for ks+1 (register dest: stays in flight across barrier) ----
        if (ks + 1 < 32) {
            const int kb2 = (ks + 1) * 32 + kcA * 8;
            const int ksafe = (kb2 + 8 <= DIN) ? kb2 : 0;   // clamped, always in-bounds
            pf0 = *reinterpret_cast<const float4*>(xrow + ksafe);
            pf1 = *reinterpret_cast<const float4*>(xrow + ksafe + 4);
        }
        __syncthreads();
        // ---- fragments + MFMA ----
        short8v a[4], b[4];
        #pragma unroll
        for (int mi = 0; mi < 4; ++mi)
            a[mi] = *reinterpret_cast<const short8v*>(&As[((size_t)kc * 128 + wm + mi * 16 + lr) * 8]);
        #pragma unroll
        for (int ni = 0; ni < 4; ++ni)
            b[ni] = *reinterpret_cast<const short8v*>(&Bs[((size_t)kc * 256 + wn + ni * 16 + lr) * 8]);
        #pragma unroll
        for (int mi = 0; mi < 4; ++mi)
            #pragma unroll
            for (int ni = 0; ni < 4; ++ni)
                acc[mi][ni] = __builtin_amdgcn_mfma_f32_16x16x32_bf16(a[mi], b[ni], acc[mi][ni], 0, 0, 0);
    }

    // ---- epilogue: BN + ELU -> bf16, C/D layout col=lane&15, row=(lane>>4)*4+reg ----
    float sc[4], sh[4];
    int cols[4];
    #pragma unroll
    for (int ni = 0; ni < 4; ++ni) {
        const int col = wn + ni * 16 + lr;
        cols[ni] = col;
        const float s = rsqrtf(v[col] + BN_EPS) * g[col];
        sc[ni] = s;
        sh[ni] = (bias[col] - m[col]) * s + bb[col];
    }
    #pragma unroll
    for (int mi = 0; mi < 4; ++mi) {
        #pragma unroll
        for (int j = 0; j < 4; ++j) {
            const int row = row0 + wm + mi * 16 + (lane >> 4) * 4 + j;
            if (row < NN) {
                #pragma unroll
                for (int ni = 0; ni < 4; ++ni) {
                    const float y = acc[mi][ni][j] * sc[ni] + sh[ni];
                    h1bf[(size_t)row * 256 + cols[ni]] = f2bf(elu_f(y));
                }
            }
        }
    }
}

// ---------------- encoder L1: h1bf[N,256] @ w[256,64] + BN + ELU -> feat, out ----------------
__global__ __launch_bounds__(256) void k_enc1(
    const short* __restrict__ h1bf, const float* __restrict__ w, const float* __restrict__ bias,
    const float* __restrict__ g, const float* __restrict__ bb,
    const float* __restrict__ m, const float* __restrict__ v,
    float* __restrict__ feat, float* __restrict__ out)
{
    __shared__ short hs[32 * 256];
    const int t = threadIdx.x;
    const int row0 = blockIdx.x * 32;
    const int j0 = t & 31;
    const int r0 = (t >> 5) * 4;
    float acc[4][2] = {};
    for (int idx = t; idx < 1024; idx += 256) {
        const int r = idx >> 5, c8 = idx & 31;
        *reinterpret_cast<short8v*>(&hs[r * 256 + c8 * 8]) =
            *reinterpret_cast<const short8v*>(&h1bf[(size_t)(row0 + r) * 256 + c8 * 8]);
    }
    __syncthreads();
    #pragma unroll 1
    for (int k = 0; k < 256; k += 8) {
        float wv[8][2];
        #pragma unroll
        for (int kk = 0; kk < 8; ++kk) {
            wv[kk][0] = w[(k + kk) * 64 + j0];
            wv[kk][1] = w[(k + kk) * 64 + j0 + 32];
        }
        #pragma unroll
        for (int r = 0; r < 4; ++r) {
            const short8v hv = *reinterpret_cast<const short8v*>(&hs[(r0 + r) * 256 + k]);
            #pragma unroll
            for (int kk = 0; kk < 8; ++kk) {
                const float xa = b2f(hv[kk]);
                acc[r][0] = fmaf(xa, wv[kk][0], acc[r][0]);
                acc[r][1] = fmaf(xa, wv[kk][1], acc[r][1]);
            }
        }
    }
    #pragma unroll
    for (int c = 0; c < 2; ++c) {
        const int j = j0 + 32 * c;
        const float sc = rsqrtf(v[j] + BN_EPS) * g[j];
        const float sh = (bias[j] - m[j]) * sc + bb[j];
        #pragma unroll
        for (int r = 0; r < 4; ++r) {
            const size_t rowi = row0 + r0 + r;
            const float y = elu_f(acc[r][c] * sc + sh);
            feat[rowi * 64 + j] = y;
            out[OFX + rowi * 64 + j] = y;
            out[OZ + rowi * 80 + j] = y;
        }
    }
}

// ---------------- GCN: gather feat (64-dim) FIRST (linearity of aggregation) ----------------
// aggF[node] = feat[node]/deg + sum_e ew*feat[src]
__global__ __launch_bounds__(256) void k_feat_gather(
    const float* __restrict__ feat, const float* __restrict__ deg,
    const int* __restrict__ off, const int* __restrict__ csr_src, const float* __restrict__ csr_w,
    float* __restrict__ aggF)
{
    const int t = threadIdx.x;
    const int node = blockIdx.x * 4 + (t >> 6);   // grid = NN/4
    const int lane = t & 63;
    const float dg = deg[node];
    float acc = feat[(size_t)node * 64 + lane] * (1.0f / dg);
    const int beg = off[node];
    const int end = beg + ((int)dg - 1);
    for (int s = beg; s < end; ++s) {
        const int src = csr_src[s];
        const float w = csr_w[s];
        acc = fmaf(feat[(size_t)src * 64 + lane], w, acc);
    }
    aggF[(size_t)node * 64 + lane] = acc;
}

// ---------------- conv projection fused: cmat = ReLU(BN(aggF @ conv_w + cb)) ----------------
__global__ __launch_bounds__(256) void k_conv_proj(
    const float* __restrict__ aggF, const float* __restrict__ w, const float* __restrict__ cb,
    const float* __restrict__ g, const float* __restrict__ bb,
    const float* __restrict__ m, const float* __restrict__ v,
    float* __restrict__ cmat)
{
    __shared__ float fs[32 * 64];
    const int t = threadIdx.x;
    const int row0 = blockIdx.x * 32;
    const int j0 = t & 63;
    const int r0 = (t >> 6) * 8;
    float acc[8][2] = {};
    for (int idx = t; idx < 512; idx += 256) {
        const int r = idx >> 4, c4 = idx & 15;
        *reinterpret_cast<float4*>(&fs[r * 64 + c4 * 4]) =
            *reinterpret_cast<const float4*>(&aggF[(size_t)(row0 + r) * 64 + c4 * 4]);
    }
    __syncthreads();
    #pragma unroll 1
    for (int k = 0; k < 64; k += 4) {
        float wv[4][2];
        #pragma unroll
        for (int kk = 0; kk < 4; ++kk) {
            wv[kk][0] = w[(k + kk) * 128 + j0];
            wv[kk][1] = w[(k + kk) * 128 + j0 + 64];
        }
        #pragma unroll
        for (int r = 0; r < 8; ++r) {
            const float4 xv = *reinterpret_cast<const float4*>(&fs[(r0 + r) * 64 + k]);
            const float xa[4] = {xv.x, xv.y, xv.z, xv.w};
            #pragma unroll
            for (int kk = 0; kk < 4; ++kk) {
                acc[r][0] = fmaf(xa[kk], wv[kk][0], acc[r][0]);
                acc[r][1] = fmaf(xa[kk], wv[kk][1], acc[r][1]);
            }
        }
    }
    #pragma unroll
    for (int c = 0; c < 2; ++c) {
        const int j = j0 + 64 * c;
        const float sc = rsqrtf(v[j] + BN_EPS) * g[j];
        const float sh = bb[j] - m[j] * sc;
        const float cbj = cb[j];
        #pragma unroll
        for (int r = 0; r < 8; ++r) {
            const size_t rowi = row0 + r0 + r;
            const float val = acc[r][c] + cbj;
            cmat[rowi * 128 + j] = fmaxf(fmaf(val, sc, sh), 0.f);
        }
    }
}

// ---------------- mean|logvar projection: c[N,128] @ [mw|lw][128,16+16] -> m2 ----------------
__global__ __launch_bounds__(256) void k_mlp_proj(
    const float* __restrict__ c, const float* __restrict__ mw, const float* __restrict__ lw,
    float* __restrict__ m2)
{
    __shared__ float cs[32 * 128];
    const int t = threadIdx.x;
    const int row0 = blockIdx.x * 32;
    const int j0 = t & 15;
    const int r0 = (t >> 4) * 2;
    float acc[2][2] = {};
    for (int idx = t; idx < 1024; idx += 256) {
        const int r = idx >> 5, c4 = idx & 31;
        *reinterpret_cast<float4*>(&cs[r * 128 + c4 * 4]) =
            *reinterpret_cast<const float4*>(&c[(size_t)(row0 + r) * 128 + c4 * 4]);
    }
    __syncthreads();
    #pragma unroll 1
    for (int k = 0; k < 128; k += 4) {
        float wv[4][2];
        #pragma unroll
        for (int kk = 0; kk < 4; ++kk) {
            wv[kk][0] = mw[(k + kk) * 16 + j0];
            wv[kk][1] = lw[(k + kk) * 16 + j0];
        }
        #pragma unroll
        for (int r = 0; r < 2; ++r) {
            const float4 xv = *reinterpret_cast<const float4*>(&cs[(r0 + r) * 128 + k]);
            const float xa[4] = {xv.x, xv.y, xv.z, xv.w};
            #pragma unroll
            for (int kk = 0; kk < 4; ++kk) {
                acc[r][0] = fmaf(xa[kk], wv[kk][0], acc[r][0]);
                acc[r][1] = fmaf(xa[kk], wv[kk][1], acc[r][1]);
            }
        }
    }
    #pragma unroll
    for (int r = 0; r < 2; ++r) {
        const size_t rowi = row0 + r0 + r;
        m2[rowi * 32 + j0] = acc[r][0];
        m2[rowi * 32 + 16 + j0] = acc[r][1];
    }
}

// ---------------- CSR gather for mean|logvar (32 feats) + self-loop + bias ----------------
__global__ __launch_bounds__(256) void k_mlp_gather(
    const float* __restrict__ m2, const float* __restrict__ deg,
    const int* __restrict__ off, const int* __restrict__ csr_src, const float* __restrict__ csr_w,
    const float* __restrict__ mb, const float* __restrict__ lb,
    float* __restrict__ agg2)
{
    const int t = threadIdx.x;
    const int node = blockIdx.x * 8 + (t >> 5);   // grid = NN/8
    const int lane = t & 31;
    const float dg = deg[node];
    const float dinv = 1.0f / dg;
    const float bias = (lane < 16) ? mb[lane] : lb[lane - 16];
    float acc = fmaf(m2[(size_t)node * 32 + lane], dinv, bias);
    const int beg = off[node];
    const int end = beg + ((int)dg - 1);
    for (int s = beg; s < end; ++s) {
        const int src = csr_src[s];
        const float w = csr_w[s];
        acc = fmaf(m2[(size_t)src * 32 + lane], w, acc);
    }
    agg2[(size_t)node * 32 + lane] = acc;
}

// ---------------- finalize pre: mu/logvar/z writes, dec0 -> d0bf (bf16), q ----------------
__global__ __launch_bounds__(256) void k_final_pre(
    const float* __restrict__ feat, const float* __restrict__ agg2,
    const float* __restrict__ d0w, const float* __restrict__ d0b,
    const float* __restrict__ g, const float* __restrict__ bb,
    const float* __restrict__ m, const float* __restrict__ v,
    const float* __restrict__ cluster,
    short* __restrict__ d0bf,
    float* __restrict__ out)
{
    __shared__ float zs[8][80];
    __shared__ float qs[8][15];
    const int t = threadIdx.x;
    const int row0 = blockIdx.x * 8;

    for (int idx = t; idx < 512; idx += 256) {
        const int r = idx >> 6, k = idx & 63;
        zs[r][k] = feat[(size_t)(row0 + r) * 64 + k];
    }
    if (t < 128) {
        const int r = t >> 4, k = t & 15;
        const size_t rowi = row0 + r;
        const float muv = agg2[rowi * 32 + k];
        const float lv = agg2[rowi * 32 + 16 + k];
        zs[r][64 + k] = muv;
        out[OMU + rowi * 16 + k] = muv;
        out[OGZ + rowi * 16 + k] = muv;
        out[OZ + rowi * 80 + 64 + k] = muv;
        out[OLV + rowi * 16 + k] = lv;
    }
    __syncthreads();

    // dec0: d0 = ELU(BN(z @ d0w + d0b)) -> bf16 global
    for (int idx = t; idx < 512; idx += 256) {
        const int r = idx >> 6, n = idx & 63;
        float acc = 0.f;
        #pragma unroll
        for (int k = 0; k < 80; k += 4) {
            const float4 zv = *reinterpret_cast<const float4*>(&zs[r][k]);
            acc = fmaf(zv.x, d0w[(k + 0) * 64 + n], acc);
            acc = fmaf(zv.y, d0w[(k + 1) * 64 + n], acc);
            acc = fmaf(zv.z, d0w[(k + 2) * 64 + n], acc);
            acc = fmaf(zv.w, d0w[(k + 3) * 64 + n], acc);
        }
        acc += d0b[n];
        const float sc = rsqrtf(v[n] + BN_EPS) * g[n];
        const float y = elu_f((acc - m[n]) * sc + bb[n]);
        d0bf[(size_t)(row0 + r) * 64 + n] = f2bf(y);
    }

    // student-t q
    if (t < 120) {
        const int r = t / 15, c = t % 15;
        float zz = 0.f, cc = 0.f, dot = 0.f;
        #pragma unroll 1
        for (int k = 0; k < 80; ++k) {
            const float zv = zs[r][k];
            const float cv = cluster[c * 80 + k];
            zz = fmaf(zv, zv, zz);
            cc = fmaf(cv, cv, cc);
            dot = fmaf(zv, cv, dot);
        }
        const float dist = fmaxf(zz + cc - 2.f * dot, 0.f);
        qs[r][c] = powf(1.0f / (1.0f + dist / 0.9f + 1e-8f), 0.95f);
    }
    __syncthreads();
    if (t < 120) {
        const int r = t / 15, c = t % 15;
        float s = 0.f;
        #pragma unroll
        for (int c2 = 0; c2 < 15; ++c2) s += qs[r][c2];
        out[OQ + (size_t)(row0 + r) * 15 + c] = qs[r][c] / s;
    }
}

// ---------------- dec1 via MFMA: de_feat = d0 @ d1w + d1b ----------------
// 128x128 tiles, 4 waves 2x2, K=64 (2 ksteps), fragments direct from global (L2-resident).
__global__ __launch_bounds__(256) void k_dec1_mfma(
    const short* __restrict__ d0bf, const short* __restrict__ wt2,
    const float* __restrict__ d1b, float* __restrict__ out)
{
    const int t = threadIdx.x;
    const int lane = t & 63;
    const int wave = t >> 6;
    const int wm = (wave >> 1) * 64;
    const int wn = (wave & 1) * 64;
    const int row0 = blockIdx.x * 128;
    const int col0 = blockIdx.y * 128;
    const int kc = lane >> 4;
    const int lr = lane & 15;

    f32x4 acc[4][4];
    #pragma unroll
    for (int mi = 0; mi < 4; ++mi)
        #pragma unroll
        for (int ni = 0; ni < 4; ++ni)
            acc[mi][ni] = (f32x4){0.f, 0.f, 0.f, 0.f};

    #pragma unroll
    for (int ks = 0; ks < 2; ++ks) {
        const int k0 = ks * 32 + kc * 8;
        short8v a[4], b[4];
        #pragma unroll
        for (int mi = 0; mi < 4; ++mi) {
            const int row = row0 + wm + mi * 16 + lr;
            if (row < NN)
                a[mi] = *reinterpret_cast<const short8v*>(&d0bf[(size_t)row * 64 + k0]);
            else
                a[mi] = (short8v){0, 0, 0, 0, 0, 0, 0, 0};
        }
        #pragma unroll
        for (int ni = 0; ni < 4; ++ni) {
            const int col = col0 + wn + ni * 16 + lr;
            b[ni] = *reinterpret_cast<const short8v*>(&wt2[(size_t)col * 64 + k0]);
        }
        #pragma unroll
        for (int mi = 0; mi < 4; ++mi)
            #pragma unroll
            for (int ni = 0; ni < 4; ++ni)
                acc[mi][ni] = __builtin_amdgcn_mfma_f32_16x16x32_bf16(a[mi], b[ni], acc[mi][ni], 0, 0, 0);
    }

    // epilogue: +bias, write de_feat (C/D: col=lane&15 within frag, row=(lane>>4)*4+j)
    #pragma unroll
    for (int ni = 0; ni < 4; ++ni) {
        const int col = col0 + wn + ni * 16 + lr;
        if (col < DIN) {
            const float bv = d1b[col];
            #pragma unroll
            for (int mi = 0; mi < 4; ++mi) {
                #pragma unroll
                for (int j = 0; j < 4; ++j) {
                    const int row = row0 + wm + mi * 16 + (lane >> 4) * 4 + j;
                    if (row < NN)
                        out[ODE + (size_t)row * DIN + col] = acc[mi][ni][j] + bv;
                }
            }
        }
    }
}

extern "C" void kernel_launch(void* const* d_in, const int* in_sizes, int n_in,
                              void* d_out, int out_size, void* d_ws, size_t ws_size,
                              hipStream_t stream)
{
    const float* x       = (const float*)d_in[0];
    const void*  ei      = d_in[1];
    const float* enc0_w  = (const float*)d_in[2];
    const float* enc0_b  = (const float*)d_in[3];
    const float* enc0_g  = (const float*)d_in[4];
    const float* enc0_bb = (const float*)d_in[5];
    const float* enc0_m  = (const float*)d_in[6];
    const float* enc0_v  = (const float*)d_in[7];
    const float* enc1_w  = (const float*)d_in[8];
    const float* enc1_b  = (const float*)d_in[9];
    const float* enc1_g  = (const float*)d_in[10];
    const float* enc1_bb = (const float*)d_in[11];
    const float* enc1_m  = (const float*)d_in[12];
    const float* enc1_v  = (const float*)d_in[13];
    const float* conv_w  = (const float*)d_in[14];
    const float* conv_b  = (const float*)d_in[15];
    const float* conv_g  = (const float*)d_in[16];
    const float* conv_bb = (const float*)d_in[17];
    const float* conv_m  = (const float*)d_in[18];
    const float* conv_v  = (const float*)d_in[19];
    const float* mean_w  = (const float*)d_in[20];
    const float* mean_b  = (const float*)d_in[21];
    const float* logvar_w = (const float*)d_in[22];
    const float* logvar_b = (const float*)d_in[23];
    const float* dec0_w  = (const float*)d_in[24];
    const float* dec0_b  = (const float*)d_in[25];
    const float* dec0_g  = (const float*)d_in[26];
    const float* dec0_bb = (const float*)d_in[27];
    const float* dec0_m  = (const float*)d_in[28];
    const float* dec0_v  = (const float*)d_in[29];
    const float* dec1_w  = (const float*)d_in[30];
    const float* dec1_b  = (const float*)d_in[31];
    const float* cluster = (const float*)d_in[32];

    float* ws = (float*)d_ws;
    float* deg  = ws;                              // N
    float* feat = ws + NN;                         // 64N
    float* A    = ws + (size_t)65 * NN;            // 256N: h1bf | aggF+cmat | m2+agg2+d0bf
    size_t base = (size_t)321 * NN;
    int*   off     = (int*)(ws + base);                        // N
    int*   cursor  = (int*)(ws + base + NN);                   // N
    int*   bsum    = (int*)(ws + base + 2 * (size_t)NN);       // 512
    int*   csr_src = (int*)(ws + base + 2 * (size_t)NN + 512);             // E
    float* csr_w   = (float*)(ws + base + 2 * (size_t)NN + 512 + NE);      // E
    short* wt      = (short*)(ws + base + 2 * (size_t)NN + 512 + 2 * (size_t)NE);  // 256*1024 bf16
    int*   flag    = (int*)(ws + base + 2 * (size_t)NN + 512 + 2 * (size_t)NE + 131072); // 1

    short* h1bf = (short*)A;              // N x 256 bf16 (spans A[0..128N) float-units)
    float* aggF = A;                      // N x 64 (after h1bf dead)
    float* cmat = A + (size_t)128 * NN;   // N x 128
    float* m2   = A;                      // N x 32 (after aggF dead)
    float* agg2 = A + (size_t)32 * NN;    // N x 32
    short* d0bf = (short*)(A + (size_t)64 * NN);   // N x 64 bf16
    short* wt2  = wt;                     // 1024 x 64 bf16 (reuses enc0 wt)

    float* out = (float*)d_out;

    k_detect<<<1, 256, 0, stream>>>((const int*)ei, flag);
    k_deg_init<<<NB, 256, 0, stream>>>(deg);
    k_deg_accum<<<NE / 256, 256, 0, stream>>>(ei, flag, deg);

    // CSR build
    k_scan1<<<NB, 256, 0, stream>>>(deg, off, bsum, cursor);
    k_scan2<<<1, 512, 0, stream>>>(bsum);
    k_scan3<<<NB, 256, 0, stream>>>(off, bsum);
    k_fill<<<NE / 256, 256, 0, stream>>>(ei, flag, deg, off, cursor, csr_src, csr_w);

    // enc0 via MFMA (single pass over x, A-stream register prefetch)
    k_wt<<<1024, 256, 0, stream>>>(enc0_w, wt);
    k_enc0_mfma<<<(NN + 127) / 128, 512, 0, stream>>>(x, wt, enc0_b, enc0_g, enc0_bb, enc0_m, enc0_v, h1bf);
    // dec1 weight prep (reuses wt buffer — enc0 done with it)
    k_wt2<<<256, 256, 0, stream>>>(dec1_w, wt2);

    k_enc1<<<NN / 32, 256, 0, stream>>>(h1bf, enc1_w, enc1_b, enc1_g, enc1_bb, enc1_m, enc1_v, feat, out);

    // GCN conv: aggregate 64-dim feat first (linearity), then fused proj+BN+ReLU
    k_feat_gather<<<NN / 4, 256, 0, stream>>>(feat, deg, off, csr_src, csr_w, aggF);
    k_conv_proj<<<NN / 32, 256, 0, stream>>>(aggF, conv_w, conv_b,
                                             conv_g, conv_bb, conv_m, conv_v, cmat);

    k_mlp_proj<<<NN / 32, 256, 0, stream>>>(cmat, mean_w, logvar_w, m2);
    k_mlp_gather<<<NN / 8, 256, 0, stream>>>(m2, deg, off, csr_src, csr_w, mean_b, logvar_b, agg2);

    k_final_pre<<<NN / 8, 256, 0, stream>>>(feat, agg2, dec0_w, dec0_b, dec0_g, dec0_bb, dec0_m, dec0_v,
                                            cluster, d0bf, out);
    {
        dim3 grid((NN + 127) / 128, 8);
        k_dec1_mfma<<<grid, 256, 0, stream>>>(d0bf, wt2, dec1_b, out);
    }
}

// Round 15
// 1123.014 us; speedup vs baseline: 1.1883x; 1.0822x over previous
//
#include <hip/hip_runtime.h>
#include <hip/hip_bf16.h>

#define NN 100000
#define NE 1600000
#define DIN 1000
#define BN_EPS 1e-3f
#define NB 391   // ceil(NN/256)

// output element offsets (concat of z, mu, logvar, de_feat, q, feat_x, gnn_z) — float32 out
#define OZ  ((size_t)0)
#define OMU ((size_t)NN*80)
#define OLV ((size_t)NN*96)
#define ODE ((size_t)NN*112)
#define OQ  ((size_t)NN*1112)
#define OFX ((size_t)NN*1127)
#define OGZ ((size_t)NN*1191)

typedef __attribute__((ext_vector_type(8))) short short8v;   // 8 bf16 (4 VGPRs)
typedef __attribute__((ext_vector_type(4))) float f32x4;     // MFMA accumulator

__device__ __forceinline__ float elu_f(float x) { return x > 0.f ? x : expf(x) - 1.f; }

// fp32 -> bf16 bits, round-to-nearest-even
__device__ __forceinline__ short f2bf(float f) {
    union { float f; unsigned u; } c; c.f = f;
    unsigned r = c.u + 0x7fffu + ((c.u >> 16) & 1u);
    return (short)(r >> 16);
}
// bf16 bits -> fp32
__device__ __forceinline__ float b2f(short s) {
    union { unsigned u; float f; } c; c.u = ((unsigned)(unsigned short)s) << 16; return c.f;
}
__device__ __forceinline__ float b2f_lo(unsigned p) {
    union { unsigned u; float f; } c; c.u = p << 16; return c.f;
}
__device__ __forceinline__ float b2f_hi(unsigned p) {
    union { unsigned u; float f; } c; c.u = p & 0xffff0000u; return c.f;
}

// Edge index may arrive as int32 or int64; logical element idx in flat (2*E) array.
__device__ __forceinline__ int edge_at(const void* ei, int is64, size_t idx) {
    if (is64) return (int)((const long long*)ei)[idx];
    return ((const int*)ei)[idx];
}

// ---------------- dtype detection ----------------
__global__ __launch_bounds__(256) void k_detect(const int* __restrict__ ei, int* __restrict__ flag) {
    __shared__ int nz;
    if (threadIdx.x == 0) nz = 0;
    __syncthreads();
    for (int i = threadIdx.x; i < 2048; i += 256)
        if (ei[2 * i + 1] != 0) nz = 1;
    __syncthreads();
    if (threadIdx.x == 0) flag[0] = (nz == 0) ? 1 : 0;  // 1 => int64
}

// ---------------- degree ----------------
__global__ __launch_bounds__(256) void k_deg_init(float* __restrict__ deg) {
    int i = blockIdx.x * 256 + threadIdx.x;
    if (i < NN) deg[i] = 1.0f;
}

__global__ __launch_bounds__(256) void k_deg_accum(const void* __restrict__ ei, const int* __restrict__ flag,
                                                   float* __restrict__ deg) {
    const int is64 = flag[0];
    int e = blockIdx.x * 256 + threadIdx.x;
    if (e < NE) atomicAdd(&deg[edge_at(ei, is64, (size_t)NE + e)], 1.0f);
}

// ---------------- CSR build: exclusive scan of in-edge counts ----------------
__global__ __launch_bounds__(256) void k_scan1(const float* __restrict__ deg, int* __restrict__ off,
                                               int* __restrict__ bsum, int* __restrict__ cursor) {
    __shared__ int s[256];
    const int t = threadIdx.x;
    const int i = blockIdx.x * 256 + t;
    const int vv = (i < NN) ? ((int)deg[i]) - 1 : 0;
    if (i < NN) cursor[i] = 0;
    s[t] = vv;
    __syncthreads();
    for (int d = 1; d < 256; d <<= 1) {
        const int u = (t >= d) ? s[t - d] : 0;
        __syncthreads();
        s[t] += u;
        __syncthreads();
    }
    if (i < NN) off[i] = s[t] - vv;           // exclusive, pre-block-offset
    if (t == 255) bsum[blockIdx.x] = s[t];    // block total
}

__global__ __launch_bounds__(512) void k_scan2(int* __restrict__ bsum) {
    __shared__ int s[512];
    const int t = threadIdx.x;
    const int vv = (t < NB) ? bsum[t] : 0;
    s[t] = vv;
    __syncthreads();
    for (int d = 1; d < 512; d <<= 1) {
        const int u = (t >= d) ? s[t - d] : 0;
        __syncthreads();
        s[t] += u;
        __syncthreads();
    }
    if (t < NB) bsum[t] = s[t] - vv;          // exclusive block prefix
}

__global__ __launch_bounds__(256) void k_scan3(int* __restrict__ off, const int* __restrict__ bsum) {
    const int i = blockIdx.x * 256 + threadIdx.x;
    if (i < NN) off[i] += bsum[blockIdx.x];
}

__global__ __launch_bounds__(256) void k_fill(const void* __restrict__ ei, const int* __restrict__ flag,
                                              const float* __restrict__ deg, const int* __restrict__ off,
                                              int* __restrict__ cursor,
                                              int* __restrict__ csr_src, float* __restrict__ csr_w) {
    const int is64 = flag[0];
    const int e = blockIdx.x * 256 + threadIdx.x;
    if (e >= NE) return;
    const int r = edge_at(ei, is64, e);
    const int c = edge_at(ei, is64, (size_t)NE + e);
    const float w = rsqrtf(deg[r]) * rsqrtf(deg[c]);
    const int p = atomicAdd(&cursor[c], 1);
    const int slot = off[c] + p;
    csr_src[slot] = r;
    csr_w[slot] = w;
}

// ---------------- enc0 weight prep: w[1000][256] f32 -> k-major bf16 granules ----------------
// Granule layout: wt[((k>>3)*256 + c)*8 + (k&7)], k zero-padded to 1024.
__global__ __launch_bounds__(256) void k_wt(const float* __restrict__ w, short* __restrict__ wt) {
    const int tid = blockIdx.x * 256 + threadIdx.x;   // 256*1024 elements
    const int c = tid >> 10;
    const int k = tid & 1023;
    wt[((size_t)(k >> 3) * 256 + c) * 8 + (k & 7)] = (k < DIN) ? f2bf(w[(size_t)k * 256 + c]) : (short)0;
}

// ---------------- dec1 weight prep: w[64][1000] f32 -> wt2[1024][64] bf16 (cols zero-padded) ----------------
__global__ __launch_bounds__(256) void k_wt2(const float* __restrict__ w, short* __restrict__ wt2) {
    const int tid = blockIdx.x * 256 + threadIdx.x;   // 1024*64 elements
    const int c = tid >> 6;
    const int k = tid & 63;
    wt2[(size_t)c * 64 + k] = (c < DIN) ? f2bf(w[(size_t)k * DIN + c]) : (short)0;
}

// ---------------- encoder L0 via MFMA: h1bf = bf16(ELU(BN(x @ w))) ----------------
// Block tile 128x256, 8 waves (2 row x 4 col), wave tile 64x64, K_STEP=32.
__global__ __launch_bounds__(512, 2) void k_enc0_mfma(
    const float* __restrict__ x, const short* __restrict__ wt, const float* __restrict__ bias,
    const float* __restrict__ g, const float* __restrict__ bb,
    const float* __restrict__ m, const float* __restrict__ v,
    short* __restrict__ h1bf)
{
    __shared__ short As[4 * 128 * 8];
    __shared__ short Bs[4 * 256 * 8];
    const int t = threadIdx.x;           // 0..511
    const int lane = t & 63;
    const int wave = t >> 6;             // 0..7
    const int wm = (wave >> 2) * 64;     // 0,64
    const int wn = (wave & 3) * 64;      // 0,64,128,192
    const int row0 = blockIdx.x * 128;

    f32x4 acc[4][4];
    #pragma unroll
    for (int mi = 0; mi < 4; ++mi)
        #pragma unroll
        for (int ni = 0; ni < 4; ++ni)
            acc[mi][ni] = (f32x4){0.f, 0.f, 0.f, 0.f};

    const int rowA = t & 127;
    const int kcA = t >> 7;
    const int rowclamp = (row0 + rowA < NN) ? (row0 + rowA) : (NN - 1);
    const float* xrow = x + (size_t)rowclamp * DIN;
    short* aslot = &As[((size_t)kcA * 128 + rowA) * 8];
    const int colB = t & 255;
    const int kcB0 = t >> 8;
    const int kcB1 = 2 + (t >> 8);

    const int kc = lane >> 4;    // 0..3
    const int lr = lane & 15;

    // prologue: prefetch ks=0 (kb = kcA*8 <= 24, always in-bounds)
    float4 pf0 = *reinterpret_cast<const float4*>(xrow + kcA * 8);
    float4 pf1 = *reinterpret_cast<const float4*>(xrow + kcA * 8 + 4);

    for (int ks = 0; ks < 32; ++ks) {
        __syncthreads();   // LDS free to overwrite
        // ---- store A granule from prefetch regs (convert fp32->bf16) ----
        {
            const int kb = ks * 32 + kcA * 8;
            short8v p;
            if (kb + 8 <= DIN) {
                p[0] = f2bf(pf0.x); p[1] = f2bf(pf0.y); p[2] = f2bf(pf0.z); p[3] = f2bf(pf0.w);
                p[4] = f2bf(pf1.x); p[5] = f2bf(pf1.y); p[6] = f2bf(pf1.z); p[7] = f2bf(pf1.w);
            } else {
                #pragma unroll
                for (int j = 0; j < 8; ++j) p[j] = 0;
            }
            *reinterpret_cast<short8v*>(aslot) = p;
        }
        // ---- stage B (wt k-major granules, L2-resident) ----
        {
            const int gbase = ks * 4;   // k0>>3
            *reinterpret_cast<short8v*>(&Bs[((size_t)kcB0 * 256 + colB) * 8]) =
                *reinterpret_cast<const short8v*>(&wt[((size_t)(gbase + kcB0) * 256 + colB) * 8]);
            *reinterpret_cast<short8v*>(&Bs[((size_t)kcB1 * 256 + colB) * 8]) =
                *reinterpret_cast<const short8v*>(&wt[((size_t)(gbase + kcB1) * 256 + colB) * 8]);
        }
        // ---- issue A prefetch for ks+1 ----
        if (ks + 1 < 32) {
            const int kb2 = (ks + 1) * 32 + kcA * 8;
            const int ksafe = (kb2 + 8 <= DIN) ? kb2 : 0;   // clamped, always in-bounds
            pf0 = *reinterpret_cast<const float4*>(xrow + ksafe);
            pf1 = *reinterpret_cast<const float4*>(xrow + ksafe + 4);
        }
        __syncthreads();
        // ---- fragments + MFMA ----
        short8v a[4], b[4];
        #pragma unroll
        for (int mi = 0; mi < 4; ++mi)
            a[mi] = *reinterpret_cast<const short8v*>(&As[((size_t)kc * 128 + wm + mi * 16 + lr) * 8]);
        #pragma unroll
        for (int ni = 0; ni < 4; ++ni)
            b[ni] = *reinterpret_cast<const short8v*>(&Bs[((size_t)kc * 256 + wn + ni * 16 + lr) * 8]);
        #pragma unroll
        for (int mi = 0; mi < 4; ++mi)
            #pragma unroll
            for (int ni = 0; ni < 4; ++ni)
                acc[mi][ni] = __builtin_amdgcn_mfma_f32_16x16x32_bf16(a[mi], b[ni], acc[mi][ni], 0, 0, 0);
    }

    // ---- epilogue: BN + ELU -> bf16, C/D layout col=lane&15, row=(lane>>4)*4+reg ----
    float sc[4], sh[4];
    int cols[4];
    #pragma unroll
    for (int ni = 0; ni < 4; ++ni) {
        const int col = wn + ni * 16 + lr;
        cols[ni] = col;
        const float s = rsqrtf(v[col] + BN_EPS) * g[col];
        sc[ni] = s;
        sh[ni] = (bias[col] - m[col]) * s + bb[col];
    }
    #pragma unroll
    for (int mi = 0; mi < 4; ++mi) {
        #pragma unroll
        for (int j = 0; j < 4; ++j) {
            const int row = row0 + wm + mi * 16 + (lane >> 4) * 4 + j;
            if (row < NN) {
                #pragma unroll
                for (int ni = 0; ni < 4; ++ni) {
                    const float y = acc[mi][ni][j] * sc[ni] + sh[ni];
                    h1bf[(size_t)row * 256 + cols[ni]] = f2bf(elu_f(y));
                }
            }
        }
    }
}

// ---------------- encoder L1: h1bf[N,256] @ w[256,64] + BN + ELU -> feat, featbf, out ----------------
__global__ __launch_bounds__(256) void k_enc1(
    const short* __restrict__ h1bf, const float* __restrict__ w, const float* __restrict__ bias,
    const float* __restrict__ g, const float* __restrict__ bb,
    const float* __restrict__ m, const float* __restrict__ v,
    float* __restrict__ feat, short* __restrict__ featbf, float* __restrict__ out)
{
    __shared__ short hs[32 * 256];
    const int t = threadIdx.x;
    const int row0 = blockIdx.x * 32;
    const int j0 = t & 31;
    const int r0 = (t >> 5) * 4;
    float acc[4][2] = {};
    for (int idx = t; idx < 1024; idx += 256) {
        const int r = idx >> 5, c8 = idx & 31;
        *reinterpret_cast<short8v*>(&hs[r * 256 + c8 * 8]) =
            *reinterpret_cast<const short8v*>(&h1bf[(size_t)(row0 + r) * 256 + c8 * 8]);
    }
    __syncthreads();
    #pragma unroll 1
    for (int k = 0; k < 256; k += 8) {
        float wv[8][2];
        #pragma unroll
        for (int kk = 0; kk < 8; ++kk) {
            wv[kk][0] = w[(k + kk) * 64 + j0];
            wv[kk][1] = w[(k + kk) * 64 + j0 + 32];
        }
        #pragma unroll
        for (int r = 0; r < 4; ++r) {
            const short8v hv = *reinterpret_cast<const short8v*>(&hs[(r0 + r) * 256 + k]);
            #pragma unroll
            for (int kk = 0; kk < 8; ++kk) {
                const float xa = b2f(hv[kk]);
                acc[r][0] = fmaf(xa, wv[kk][0], acc[r][0]);
                acc[r][1] = fmaf(xa, wv[kk][1], acc[r][1]);
            }
        }
    }
    #pragma unroll
    for (int c = 0; c < 2; ++c) {
        const int j = j0 + 32 * c;
        const float sc = rsqrtf(v[j] + BN_EPS) * g[j];
        const float sh = (bias[j] - m[j]) * sc + bb[j];
        #pragma unroll
        for (int r = 0; r < 4; ++r) {
            const size_t rowi = row0 + r0 + r;
            const float y = elu_f(acc[r][c] * sc + sh);
            feat[rowi * 64 + j] = y;
            featbf[rowi * 64 + j] = f2bf(y);
            out[OFX + rowi * 64 + j] = y;
            out[OZ + rowi * 80 + j] = y;
        }
    }
}

// ---------------- GCN: gather featbf (64-dim bf16) FIRST (linearity) ----------------
// aggF[node] = feat[node]/deg + sum_e ew*feat[src]; 32 lanes/node, uint = 2 bf16.
__global__ __launch_bounds__(256) void k_feat_gather(
    const unsigned* __restrict__ featp, const float* __restrict__ deg,
    const int* __restrict__ off, const int* __restrict__ csr_src, const float* __restrict__ csr_w,
    float* __restrict__ aggF)
{
    const int t = threadIdx.x;
    const int node = blockIdx.x * 8 + (t >> 5);   // grid = NN/8
    const int lane = t & 31;                       // feats 2*lane, 2*lane+1
    const float dg = deg[node];
    const float dinv = 1.0f / dg;
    const unsigned ps = featp[(size_t)node * 32 + lane];
    float a0 = b2f_lo(ps) * dinv;
    float a1 = b2f_hi(ps) * dinv;
    const int beg = off[node];
    const int end = beg + ((int)dg - 1);
    for (int s = beg; s < end; ++s) {
        const int src = csr_src[s];
        const float w = csr_w[s];
        const unsigned p = featp[(size_t)src * 32 + lane];
        a0 = fmaf(b2f_lo(p), w, a0);
        a1 = fmaf(b2f_hi(p), w, a1);
    }
    float2 o; o.x = a0; o.y = a1;
    *reinterpret_cast<float2*>(&aggF[(size_t)node * 64 + lane * 2]) = o;
}

// ---------------- conv projection fused: cmat = ReLU(BN(aggF @ conv_w + cb)) ----------------
__global__ __launch_bounds__(256) void k_conv_proj(
    const float* __restrict__ aggF, const float* __restrict__ w, const float* __restrict__ cb,
    const float* __restrict__ g, const float* __restrict__ bb,
    const float* __restrict__ m, const float* __restrict__ v,
    float* __restrict__ cmat)
{
    __shared__ float fs[32 * 64];
    const int t = threadIdx.x;
    const int row0 = blockIdx.x * 32;
    const int j0 = t & 63;
    const int r0 = (t >> 6) * 8;
    float acc[8][2] = {};
    for (int idx = t; idx < 512; idx += 256) {
        const int r = idx >> 4, c4 = idx & 15;
        *reinterpret_cast<float4*>(&fs[r * 64 + c4 * 4]) =
            *reinterpret_cast<const float4*>(&aggF[(size_t)(row0 + r) * 64 + c4 * 4]);
    }
    __syncthreads();
    #pragma unroll 1
    for (int k = 0; k < 64; k += 4) {
        float wv[4][2];
        #pragma unroll
        for (int kk = 0; kk < 4; ++kk) {
            wv[kk][0] = w[(k + kk) * 128 + j0];
            wv[kk][1] = w[(k + kk) * 128 + j0 + 64];
        }
        #pragma unroll
        for (int r = 0; r < 8; ++r) {
            const float4 xv = *reinterpret_cast<const float4*>(&fs[(r0 + r) * 64 + k]);
            const float xa[4] = {xv.x, xv.y, xv.z, xv.w};
            #pragma unroll
            for (int kk = 0; kk < 4; ++kk) {
                acc[r][0] = fmaf(xa[kk], wv[kk][0], acc[r][0]);
                acc[r][1] = fmaf(xa[kk], wv[kk][1], acc[r][1]);
            }
        }
    }
    #pragma unroll
    for (int c = 0; c < 2; ++c) {
        const int j = j0 + 64 * c;
        const float sc = rsqrtf(v[j] + BN_EPS) * g[j];
        const float sh = bb[j] - m[j] * sc;
        const float cbj = cb[j];
        #pragma unroll
        for (int r = 0; r < 8; ++r) {
            const size_t rowi = row0 + r0 + r;
            const float val = acc[r][c] + cbj;
            cmat[rowi * 128 + j] = fmaxf(fmaf(val, sc, sh), 0.f);
        }
    }
}

// ---------------- mean|logvar projection: cmat @ [mw|lw] -> m2bf (bf16) ----------------
__global__ __launch_bounds__(256) void k_mlp_proj(
    const float* __restrict__ c, const float* __restrict__ mw, const float* __restrict__ lw,
    short* __restrict__ m2bf)
{
    __shared__ float cs[32 * 128];
    const int t = threadIdx.x;
    const int row0 = blockIdx.x * 32;
    const int j0 = t & 15;
    const int r0 = (t >> 4) * 2;
    float acc[2][2] = {};
    for (int idx = t; idx < 1024; idx += 256) {
        const int r = idx >> 5, c4 = idx & 31;
        *reinterpret_cast<float4*>(&cs[r * 128 + c4 * 4]) =
            *reinterpret_cast<const float4*>(&c[(size_t)(row0 + r) * 128 + c4 * 4]);
    }
    __syncthreads();
    #pragma unroll 1
    for (int k = 0; k < 128; k += 4) {
        float wv[4][2];
        #pragma unroll
        for (int kk = 0; kk < 4; ++kk) {
            wv[kk][0] = mw[(k + kk) * 16 + j0];
            wv[kk][1] = lw[(k + kk) * 16 + j0];
        }
        #pragma unroll
        for (int r = 0; r < 2; ++r) {
            const float4 xv = *reinterpret_cast<const float4*>(&cs[(r0 + r) * 128 + k]);
            const float xa[4] = {xv.x, xv.y, xv.z, xv.w};
            #pragma unroll
            for (int kk = 0; kk < 4; ++kk) {
                acc[r][0] = fmaf(xa[kk], wv[kk][0], acc[r][0]);
                acc[r][1] = fmaf(xa[kk], wv[kk][1], acc[r][1]);
            }
        }
    }
    #pragma unroll
    for (int r = 0; r < 2; ++r) {
        const size_t rowi = row0 + r0 + r;
        m2bf[rowi * 32 + j0] = f2bf(acc[r][0]);
        m2bf[rowi * 32 + 16 + j0] = f2bf(acc[r][1]);
    }
}

// ---------------- CSR gather mean|logvar (32 bf16 feats) + self-loop + bias ----------------
// 16 lanes/node, uint = 2 bf16.
__global__ __launch_bounds__(256) void k_mlp_gather(
    const unsigned* __restrict__ m2p, const float* __restrict__ deg,
    const int* __restrict__ off, const int* __restrict__ csr_src, const float* __restrict__ csr_w,
    const float* __restrict__ mb, const float* __restrict__ lb,
    float* __restrict__ agg2)
{
    const int t = threadIdx.x;
    const int node = blockIdx.x * 16 + (t >> 4);   // grid = NN/16
    const int lane = t & 15;                        // feats 2*lane, 2*lane+1
    const int f0 = lane * 2, f1 = lane * 2 + 1;
    const float dg = deg[node];
    const float dinv = 1.0f / dg;
    const float b0 = (f0 < 16) ? mb[f0] : lb[f0 - 16];
    const float b1 = (f1 < 16) ? mb[f1] : lb[f1 - 16];
    const unsigned ps = m2p[(size_t)node * 16 + lane];
    float a0 = fmaf(b2f_lo(ps), dinv, b0);
    float a1 = fmaf(b2f_hi(ps), dinv, b1);
    const int beg = off[node];
    const int end = beg + ((int)dg - 1);
    for (int s = beg; s < end; ++s) {
        const int src = csr_src[s];
        const float w = csr_w[s];
        const unsigned p = m2p[(size_t)src * 16 + lane];
        a0 = fmaf(b2f_lo(p), w, a0);
        a1 = fmaf(b2f_hi(p), w, a1);
    }
    float2 o; o.x = a0; o.y = a1;
    *reinterpret_cast<float2*>(&agg2[(size_t)node * 32 + lane * 2]) = o;
}

// ---------------- finalize pre: mu/logvar/z writes, dec0 -> d0bf (bf16), q ----------------
__global__ __launch_bounds__(256) void k_final_pre(
    const float* __restrict__ feat, const float* __restrict__ agg2,
    const float* __restrict__ d0w, const float* __restrict__ d0b,
    const float* __restrict__ g, const float* __restrict__ bb,
    const float* __restrict__ m, const float* __restrict__ v,
    const float* __restrict__ cluster,
    short* __restrict__ d0bf,
    float* __restrict__ out)
{
    __shared__ float zs[8][80];
    __shared__ float qs[8][15];
    const int t = threadIdx.x;
    const int row0 = blockIdx.x * 8;

    for (int idx = t; idx < 512; idx += 256) {
        const int r = idx >> 6, k = idx & 63;
        zs[r][k] = feat[(size_t)(row0 + r) * 64 + k];
    }
    if (t < 128) {
        const int r = t >> 4, k = t & 15;
        const size_t rowi = row0 + r;
        const float muv = agg2[rowi * 32 + k];
        const float lv = agg2[rowi * 32 + 16 + k];
        zs[r][64 + k] = muv;
        out[OMU + rowi * 16 + k] = muv;
        out[OGZ + rowi * 16 + k] = muv;
        out[OZ + rowi * 80 + 64 + k] = muv;
        out[OLV + rowi * 16 + k] = lv;
    }
    __syncthreads();

    // dec0: d0 = ELU(BN(z @ d0w + d0b)) -> bf16 global
    for (int idx = t; idx < 512; idx += 256) {
        const int r = idx >> 6, n = idx & 63;
        float acc = 0.f;
        #pragma unroll
        for (int k = 0; k < 80; k += 4) {
            const float4 zv = *reinterpret_cast<const float4*>(&zs[r][k]);
            acc = fmaf(zv.x, d0w[(k + 0) * 64 + n], acc);
            acc = fmaf(zv.y, d0w[(k + 1) * 64 + n], acc);
            acc = fmaf(zv.z, d0w[(k + 2) * 64 + n], acc);
            acc = fmaf(zv.w, d0w[(k + 3) * 64 + n], acc);
        }
        acc += d0b[n];
        const float sc = rsqrtf(v[n] + BN_EPS) * g[n];
        const float y = elu_f((acc - m[n]) * sc + bb[n]);
        d0bf[(size_t)(row0 + r) * 64 + n] = f2bf(y);
    }

    // student-t q
    if (t < 120) {
        const int r = t / 15, c = t % 15;
        float zz = 0.f, cc = 0.f, dot = 0.f;
        #pragma unroll 1
        for (int k = 0; k < 80; ++k) {
            const float zv = zs[r][k];
            const float cv = cluster[c * 80 + k];
            zz = fmaf(zv, zv, zz);
            cc = fmaf(cv, cv, cc);
            dot = fmaf(zv, cv, dot);
        }
        const float dist = fmaxf(zz + cc - 2.f * dot, 0.f);
        qs[r][c] = powf(1.0f / (1.0f + dist / 0.9f + 1e-8f), 0.95f);
    }
    __syncthreads();
    if (t < 120) {
        const int r = t / 15, c = t % 15;
        float s = 0.f;
        #pragma unroll
        for (int c2 = 0; c2 < 15; ++c2) s += qs[r][c2];
        out[OQ + (size_t)(row0 + r) * 15 + c] = qs[r][c] / s;
    }
}

// ---------------- dec1 via MFMA: de_feat = d0 @ d1w + d1b ----------------
__global__ __launch_bounds__(256) void k_dec1_mfma(
    const short* __restrict__ d0bf, const short* __restrict__ wt2,
    const float* __restrict__ d1b, float* __restrict__ out)
{
    const int t = threadIdx.x;
    const int lane = t & 63;
    const int wave = t >> 6;
    const int wm = (wave >> 1) * 64;
    const int wn = (wave & 1) * 64;
    const int row0 = blockIdx.x * 128;
    const int col0 = blockIdx.y * 128;
    const int kc = lane >> 4;
    const int lr = lane & 15;

    f32x4 acc[4][4];
    #pragma unroll
    for (int mi = 0; mi < 4; ++mi)
        #pragma unroll
        for (int ni = 0; ni < 4; ++ni)
            acc[mi][ni] = (f32x4){0.f, 0.f, 0.f, 0.f};

    #pragma unroll
    for (int ks = 0; ks < 2; ++ks) {
        const int k0 = ks * 32 + kc * 8;
        short8v a[4], b[4];
        #pragma unroll
        for (int mi = 0; mi < 4; ++mi) {
            const int row = row0 + wm + mi * 16 + lr;
            if (row < NN)
                a[mi] = *reinterpret_cast<const short8v*>(&d0bf[(size_t)row * 64 + k0]);
            else
                a[mi] = (short8v){0, 0, 0, 0, 0, 0, 0, 0};
        }
        #pragma unroll
        for (int ni = 0; ni < 4; ++ni) {
            const int col = col0 + wn + ni * 16 + lr;
            b[ni] = *reinterpret_cast<const short8v*>(&wt2[(size_t)col * 64 + k0]);
        }
        #pragma unroll
        for (int mi = 0; mi < 4; ++mi)
            #pragma unroll
            for (int ni = 0; ni < 4; ++ni)
                acc[mi][ni] = __builtin_amdgcn_mfma_f32_16x16x32_bf16(a[mi], b[ni], acc[mi][ni], 0, 0, 0);
    }

    // epilogue: +bias, write de_feat (C/D: col=lane&15 within frag, row=(lane>>4)*4+j)
    #pragma unroll
    for (int ni = 0; ni < 4; ++ni) {
        const int col = col0 + wn + ni * 16 + lr;
        if (col < DIN) {
            const float bv = d1b[col];
            #pragma unroll
            for (int mi = 0; mi < 4; ++mi) {
                #pragma unroll
                for (int j = 0; j < 4; ++j) {
                    const int row = row0 + wm + mi * 16 + (lane >> 4) * 4 + j;
                    if (row < NN)
                        out[ODE + (size_t)row * DIN + col] = acc[mi][ni][j] + bv;
                }
            }
        }
    }
}

extern "C" void kernel_launch(void* const* d_in, const int* in_sizes, int n_in,
                              void* d_out, int out_size, void* d_ws, size_t ws_size,
                              hipStream_t stream)
{
    const float* x       = (const float*)d_in[0];
    const void*  ei      = d_in[1];
    const float* enc0_w  = (const float*)d_in[2];
    const float* enc0_b  = (const float*)d_in[3];
    const float* enc0_g  = (const float*)d_in[4];
    const float* enc0_bb = (const float*)d_in[5];
    const float* enc0_m  = (const float*)d_in[6];
    const float* enc0_v  = (const float*)d_in[7];
    const float* enc1_w  = (const float*)d_in[8];
    const float* enc1_b  = (const float*)d_in[9];
    const float* enc1_g  = (const float*)d_in[10];
    const float* enc1_bb = (const float*)d_in[11];
    const float* enc1_m  = (const float*)d_in[12];
    const float* enc1_v  = (const float*)d_in[13];
    const float* conv_w  = (const float*)d_in[14];
    const float* conv_b  = (const float*)d_in[15];
    const float* conv_g  = (const float*)d_in[16];
    const float* conv_bb = (const float*)d_in[17];
    const float* conv_m  = (const float*)d_in[18];
    const float* conv_v  = (const float*)d_in[19];
    const float* mean_w  = (const float*)d_in[20];
    const float* mean_b  = (const float*)d_in[21];
    const float* logvar_w = (const float*)d_in[22];
    const float* logvar_b = (const float*)d_in[23];
    const float* dec0_w  = (const float*)d_in[24];
    const float* dec0_b  = (const float*)d_in[25];
    const float* dec0_g  = (const float*)d_in[26];
    const float* dec0_bb = (const float*)d_in[27];
    const float* dec0_m  = (const float*)d_in[28];
    const float* dec0_v  = (const float*)d_in[29];
    const float* dec1_w  = (const float*)d_in[30];
    const float* dec1_b  = (const float*)d_in[31];
    const float* cluster = (const float*)d_in[32];

    float* ws = (float*)d_ws;
    float* deg  = ws;                              // N
    float* feat = ws + NN;                         // 64N
    float* A    = ws + (size_t)65 * NN;            // 256N region, multi-use
    size_t base = (size_t)321 * NN;
    int*   off     = (int*)(ws + base);                        // N
    int*   cursor  = (int*)(ws + base + NN);                   // N
    int*   bsum    = (int*)(ws + base + 2 * (size_t)NN);       // 512
    int*   csr_src = (int*)(ws + base + 2 * (size_t)NN + 512);             // E
    float* csr_w   = (float*)(ws + base + 2 * (size_t)NN + 512 + NE);      // E
    short* wt      = (short*)(ws + base + 2 * (size_t)NN + 512 + 2 * (size_t)NE);  // 256*1024 bf16
    int*   flag    = (int*)(ws + base + 2 * (size_t)NN + 512 + 2 * (size_t)NE + 131072); // 1

    short* h1bf   = (short*)A;                     // N x 256 bf16 (A[0..128N) floats)
    short* featbf = (short*)(A + (size_t)128 * NN); // N x 64 bf16 (dead after feat_gather; cmat overwrites)
    float* aggF   = A;                             // N x 64 f32 (after h1bf dead)
    float* cmat   = A + (size_t)128 * NN;          // N x 128 f32
    short* m2bf   = (short*)A;                     // N x 32 bf16 (after aggF dead)
    float* agg2   = A + (size_t)32 * NN;           // N x 32 f32
    short* d0bf   = (short*)(A + (size_t)64 * NN); // N x 64 bf16
    short* wt2    = wt;                            // 1024 x 64 bf16 (reuses enc0 wt)

    float* out = (float*)d_out;

    k_detect<<<1, 256, 0, stream>>>((const int*)ei, flag);
    k_deg_init<<<NB, 256, 0, stream>>>(deg);
    k_deg_accum<<<NE / 256, 256, 0, stream>>>(ei, flag, deg);

    // CSR build
    k_scan1<<<NB, 256, 0, stream>>>(deg, off, bsum, cursor);
    k_scan2<<<1, 512, 0, stream>>>(bsum);
    k_scan3<<<NB, 256, 0, stream>>>(off, bsum);
    k_fill<<<NE / 256, 256, 0, stream>>>(ei, flag, deg, off, cursor, csr_src, csr_w);

    // enc0 via MFMA (single pass over x)
    k_wt<<<1024, 256, 0, stream>>>(enc0_w, wt);
    k_enc0_mfma<<<(NN + 127) / 128, 512, 0, stream>>>(x, wt, enc0_b, enc0_g, enc0_bb, enc0_m, enc0_v, h1bf);
    // dec1 weight prep (reuses wt buffer — enc0 done with it)
    k_wt2<<<256, 256, 0, stream>>>(dec1_w, wt2);

    k_enc1<<<NN / 32, 256, 0, stream>>>(h1bf, enc1_w, enc1_b, enc1_g, enc1_bb, enc1_m, enc1_v,
                                        feat, featbf, out);

    // GCN conv: aggregate bf16 feat first (linearity), then fused proj+BN+ReLU
    k_feat_gather<<<NN / 8, 256, 0, stream>>>((const unsigned*)featbf, deg, off, csr_src, csr_w, aggF);
    k_conv_proj<<<NN / 32, 256, 0, stream>>>(aggF, conv_w, conv_b,
                                             conv_g, conv_bb, conv_m, conv_v, cmat);

    k_mlp_proj<<<NN / 32, 256, 0, stream>>>(cmat, mean_w, logvar_w, m2bf);
    k_mlp_gather<<<NN / 16, 256, 0, stream>>>((const unsigned*)m2bf, deg, off, csr_src, csr_w,
                                              mean_b, logvar_b, agg2);

    k_final_pre<<<NN / 8, 256, 0, stream>>>(feat, agg2, dec0_w, dec0_b, dec0_g, dec0_bb, dec0_m, dec0_v,
                                            cluster, d0bf, out);
    {
        dim3 grid((NN + 127) / 128, 8);
        k_dec1_mfma<<<grid, 256, 0, stream>>>(d0bf, wt2, dec1_b, out);
    }
}

// Round 16
// 1092.277 us; speedup vs baseline: 1.2217x; 1.0281x over previous
//
#include <hip/hip_runtime.h>
#include <hip/hip_bf16.h>

#define NN 100000
#define NE 1600000
#define DIN 1000
#define BN_EPS 1e-3f
#define NB 391   // ceil(NN/256)

// output element offsets (concat of z, mu, logvar, de_feat, q, feat_x, gnn_z) — float32 out
#define OZ  ((size_t)0)
#define OMU ((size_t)NN*80)
#define OLV ((size_t)NN*96)
#define ODE ((size_t)NN*112)
#define OQ  ((size_t)NN*1112)
#define OFX ((size_t)NN*1127)
#define OGZ ((size_t)NN*1191)

typedef __attribute__((ext_vector_type(8))) short short8v;   // 8 bf16 (4 VGPRs)
typedef __attribute__((ext_vector_type(4))) short short4v;   // 4 bf16 (2 VGPRs)
typedef __attribute__((ext_vector_type(4))) float f32x4;     // MFMA accumulator

__device__ __forceinline__ float elu_f(float x) { return x > 0.f ? x : expf(x) - 1.f; }

// fp32 -> bf16 bits, round-to-nearest-even
__device__ __forceinline__ short f2bf(float f) {
    union { float f; unsigned u; } c; c.f = f;
    unsigned r = c.u + 0x7fffu + ((c.u >> 16) & 1u);
    return (short)(r >> 16);
}
// bf16 bits -> fp32
__device__ __forceinline__ float b2f(short s) {
    union { unsigned u; float f; } c; c.u = ((unsigned)(unsigned short)s) << 16; return c.f;
}
__device__ __forceinline__ float b2f_lo(unsigned p) {
    union { unsigned u; float f; } c; c.u = p << 16; return c.f;
}
__device__ __forceinline__ float b2f_hi(unsigned p) {
    union { unsigned u; float f; } c; c.u = p & 0xffff0000u; return c.f;
}

// Edge index may arrive as int32 or int64; logical element idx in flat (2*E) array.
__device__ __forceinline__ int edge_at(const void* ei, int is64, size_t idx) {
    if (is64) return (int)((const long long*)ei)[idx];
    return ((const int*)ei)[idx];
}

// ---------------- dtype detection ----------------
__global__ __launch_bounds__(256) void k_detect(const int* __restrict__ ei, int* __restrict__ flag) {
    __shared__ int nz;
    if (threadIdx.x == 0) nz = 0;
    __syncthreads();
    for (int i = threadIdx.x; i < 2048; i += 256)
        if (ei[2 * i + 1] != 0) nz = 1;
    __syncthreads();
    if (threadIdx.x == 0) flag[0] = (nz == 0) ? 1 : 0;  // 1 => int64
}

// ---------------- degree ----------------
__global__ __launch_bounds__(256) void k_deg_init(float* __restrict__ deg) {
    int i = blockIdx.x * 256 + threadIdx.x;
    if (i < NN) deg[i] = 1.0f;
}

__global__ __launch_bounds__(256) void k_deg_accum(const void* __restrict__ ei, const int* __restrict__ flag,
                                                   float* __restrict__ deg) {
    const int is64 = flag[0];
    int e = blockIdx.x * 256 + threadIdx.x;
    if (e < NE) atomicAdd(&deg[edge_at(ei, is64, (size_t)NE + e)], 1.0f);
}

// ---------------- CSR build: exclusive scan of in-edge counts ----------------
__global__ __launch_bounds__(256) void k_scan1(const float* __restrict__ deg, int* __restrict__ off,
                                               int* __restrict__ bsum, int* __restrict__ cursor) {
    __shared__ int s[256];
    const int t = threadIdx.x;
    const int i = blockIdx.x * 256 + t;
    const int vv = (i < NN) ? ((int)deg[i]) - 1 : 0;
    if (i < NN) cursor[i] = 0;
    s[t] = vv;
    __syncthreads();
    for (int d = 1; d < 256; d <<= 1) {
        const int u = (t >= d) ? s[t - d] : 0;
        __syncthreads();
        s[t] += u;
        __syncthreads();
    }
    if (i < NN) off[i] = s[t] - vv;           // exclusive, pre-block-offset
    if (t == 255) bsum[blockIdx.x] = s[t];    // block total
}

__global__ __launch_bounds__(512) void k_scan2(int* __restrict__ bsum) {
    __shared__ int s[512];
    const int t = threadIdx.x;
    const int vv = (t < NB) ? bsum[t] : 0;
    s[t] = vv;
    __syncthreads();
    for (int d = 1; d < 512; d <<= 1) {
        const int u = (t >= d) ? s[t - d] : 0;
        __syncthreads();
        s[t] += u;
        __syncthreads();
    }
    if (t < NB) bsum[t] = s[t] - vv;          // exclusive block prefix
}

__global__ __launch_bounds__(256) void k_scan3(int* __restrict__ off, const int* __restrict__ bsum) {
    const int i = blockIdx.x * 256 + threadIdx.x;
    if (i < NN) off[i] += bsum[blockIdx.x];
}

__global__ __launch_bounds__(256) void k_fill(const void* __restrict__ ei, const int* __restrict__ flag,
                                              const float* __restrict__ deg, const int* __restrict__ off,
                                              int* __restrict__ cursor,
                                              int* __restrict__ csr_src, float* __restrict__ csr_w) {
    const int is64 = flag[0];
    const int e = blockIdx.x * 256 + threadIdx.x;
    if (e >= NE) return;
    const int r = edge_at(ei, is64, e);
    const int c = edge_at(ei, is64, (size_t)NE + e);
    const float w = rsqrtf(deg[r]) * rsqrtf(deg[c]);
    const int p = atomicAdd(&cursor[c], 1);
    const int slot = off[c] + p;
    csr_src[slot] = r;
    csr_w[slot] = w;
}

// ---------------- enc0 weight prep: w[1000][256] f32 -> k-major bf16 granules ----------------
// Granule layout: wt[((k>>3)*256 + c)*8 + (k&7)], k zero-padded to 1024.
__global__ __launch_bounds__(256) void k_wt(const float* __restrict__ w, short* __restrict__ wt) {
    const int tid = blockIdx.x * 256 + threadIdx.x;   // 256*1024 elements
    const int c = tid >> 10;
    const int k = tid & 1023;
    wt[((size_t)(k >> 3) * 256 + c) * 8 + (k & 7)] = (k < DIN) ? f2bf(w[(size_t)k * 256 + c]) : (short)0;
}

// ---------------- dec1 weight prep: w[64][1000] f32 -> wt2[1024][64] bf16 (cols zero-padded) ----------------
__global__ __launch_bounds__(256) void k_wt2(const float* __restrict__ w, short* __restrict__ wt2) {
    const int tid = blockIdx.x * 256 + threadIdx.x;   // 1024*64 elements
    const int c = tid >> 6;
    const int k = tid & 63;
    wt2[(size_t)c * 64 + k] = (c < DIN) ? f2bf(w[(size_t)k * DIN + c]) : (short)0;
}

// ---------------- encoder L0 via MFMA: h1bf = bf16(ELU(BN(x @ w))) ----------------
// Block tile 128x256, 8 waves (2 row x 4 col), wave tile 64x64, K_STEP=32.
// A-stage COALESCED: thread t = (row t>>3, float4-slot t&7) for rows t>>3 and
// t>>3+64 — each wave-load covers 8 rows x 128 contiguous bytes (full sectors).
__global__ __launch_bounds__(512, 2) void k_enc0_mfma(
    const float* __restrict__ x, const short* __restrict__ wt, const float* __restrict__ bias,
    const float* __restrict__ g, const float* __restrict__ bb,
    const float* __restrict__ m, const float* __restrict__ v,
    short* __restrict__ h1bf)
{
    __shared__ short As[4 * 128 * 8];
    __shared__ short Bs[4 * 256 * 8];
    const int t = threadIdx.x;           // 0..511
    const int lane = t & 63;
    const int wave = t >> 6;             // 0..7
    const int wm = (wave >> 2) * 64;     // 0,64
    const int wn = (wave & 3) * 64;      // 0,64,128,192
    const int row0 = blockIdx.x * 128;

    f32x4 acc[4][4];
    #pragma unroll
    for (int mi = 0; mi < 4; ++mi)
        #pragma unroll
        for (int ni = 0; ni < 4; ++ni)
            acc[mi][ni] = (f32x4){0.f, 0.f, 0.f, 0.f};

    // A staging mapping: kq = float4 slot in 32-float k-window; rows rA0, rA0+64.
    const int kq = t & 7;
    const int rA0 = t >> 3;              // 0..63
    const int rA1 = rA0 + 64;            // 64..127
    const int gr0 = (row0 + rA0 < NN) ? (row0 + rA0) : (NN - 1);
    const int gr1 = (row0 + rA1 < NN) ? (row0 + rA1) : (NN - 1);
    const float* xb0 = x + (size_t)gr0 * DIN;
    const float* xb1 = x + (size_t)gr1 * DIN;
    short4v* aslot0 = reinterpret_cast<short4v*>(&As[(((kq >> 1) * 128) + rA0) * 8 + (kq & 1) * 4]);
    short4v* aslot1 = reinterpret_cast<short4v*>(&As[(((kq >> 1) * 128) + rA1) * 8 + (kq & 1) * 4]);

    const int colB = t & 255;
    const int kcB0 = t >> 8;
    const int kcB1 = 2 + (t >> 8);

    const int kc = lane >> 4;    // 0..3
    const int lr = lane & 15;

    // prologue: prefetch ks=0 (kb = kq*4 <= 28, in-bounds)
    float4 pf0 = *reinterpret_cast<const float4*>(xb0 + kq * 4);
    float4 pf1 = *reinterpret_cast<const float4*>(xb1 + kq * 4);

    for (int ks = 0; ks < 32; ++ks) {
        __syncthreads();   // LDS free to overwrite
        // ---- store A granule-halves from prefetch regs (fp32->bf16) ----
        {
            const int kb = ks * 32 + kq * 4;
            short4v p0, p1;
            if (kb + 4 <= DIN) {
                p0[0] = f2bf(pf0.x); p0[1] = f2bf(pf0.y); p0[2] = f2bf(pf0.z); p0[3] = f2bf(pf0.w);
                p1[0] = f2bf(pf1.x); p1[1] = f2bf(pf1.y); p1[2] = f2bf(pf1.z); p1[3] = f2bf(pf1.w);
            } else {
                p0 = (short4v){0, 0, 0, 0};
                p1 = (short4v){0, 0, 0, 0};
            }
            *aslot0 = p0;
            *aslot1 = p1;
        }
        // ---- stage B (wt k-major granules, L2-resident) ----
        {
            const int gbase = ks * 4;   // k0>>3
            *reinterpret_cast<short8v*>(&Bs[((size_t)kcB0 * 256 + colB) * 8]) =
                *reinterpret_cast<const short8v*>(&wt[((size_t)(gbase + kcB0) * 256 + colB) * 8]);
            *reinterpret_cast<short8v*>(&Bs[((size_t)kcB1 * 256 + colB) * 8]) =
                *reinterpret_cast<const short8v*>(&wt[((size_t)(gbase + kcB1) * 256 + colB) * 8]);
        }
        // ---- issue A prefetch for ks+1 (coalesced: 8 rows x 128 B per wave) ----
        if (ks + 1 < 32) {
            const int kb2 = (ks + 1) * 32 + kq * 4;
            const int ko = (kb2 + 4 <= DIN) ? kb2 : 0;   // clamped, in-bounds
            pf0 = *reinterpret_cast<const float4*>(xb0 + ko);
            pf1 = *reinterpret_cast<const float4*>(xb1 + ko);
        }
        __syncthreads();
        // ---- fragments + MFMA ----
        short8v a[4], b[4];
        #pragma unroll
        for (int mi = 0; mi < 4; ++mi)
            a[mi] = *reinterpret_cast<const short8v*>(&As[((size_t)kc * 128 + wm + mi * 16 + lr) * 8]);
        #pragma unroll
        for (int ni = 0; ni < 4; ++ni)
            b[ni] = *reinterpret_cast<const short8v*>(&Bs[((size_t)kc * 256 + wn + ni * 16 + lr) * 8]);
        #pragma unroll
        for (int mi = 0; mi < 4; ++mi)
            #pragma unroll
            for (int ni = 0; ni < 4; ++ni)
                acc[mi][ni] = __builtin_amdgcn_mfma_f32_16x16x32_bf16(a[mi], b[ni], acc[mi][ni], 0, 0, 0);
    }

    // ---- epilogue: BN + ELU -> bf16, C/D layout col=lane&15, row=(lane>>4)*4+reg ----
    float sc[4], sh[4];
    int cols[4];
    #pragma unroll
    for (int ni = 0; ni < 4; ++ni) {
        const int col = wn + ni * 16 + lr;
        cols[ni] = col;
        const float s = rsqrtf(v[col] + BN_EPS) * g[col];
        sc[ni] = s;
        sh[ni] = (bias[col] - m[col]) * s + bb[col];
    }
    #pragma unroll
    for (int mi = 0; mi < 4; ++mi) {
        #pragma unroll
        for (int j = 0; j < 4; ++j) {
            const int row = row0 + wm + mi * 16 + (lane >> 4) * 4 + j;
            if (row < NN) {
                #pragma unroll
                for (int ni = 0; ni < 4; ++ni) {
                    const float y = acc[mi][ni][j] * sc[ni] + sh[ni];
                    h1bf[(size_t)row * 256 + cols[ni]] = f2bf(elu_f(y));
                }
            }
        }
    }
}

// ---------------- encoder L1: h1bf[N,256] @ w[256,64] + BN + ELU -> feat, featbf, out ----------------
__global__ __launch_bounds__(256) void k_enc1(
    const short* __restrict__ h1bf, const float* __restrict__ w, const float* __restrict__ bias,
    const float* __restrict__ g, const float* __restrict__ bb,
    const float* __restrict__ m, const float* __restrict__ v,
    float* __restrict__ feat, short* __restrict__ featbf, float* __restrict__ out)
{
    __shared__ short hs[32 * 256];
    const int t = threadIdx.x;
    const int row0 = blockIdx.x * 32;
    const int j0 = t & 31;
    const int r0 = (t >> 5) * 4;
    float acc[4][2] = {};
    for (int idx = t; idx < 1024; idx += 256) {
        const int r = idx >> 5, c8 = idx & 31;
        *reinterpret_cast<short8v*>(&hs[r * 256 + c8 * 8]) =
            *reinterpret_cast<const short8v*>(&h1bf[(size_t)(row0 + r) * 256 + c8 * 8]);
    }
    __syncthreads();
    #pragma unroll 1
    for (int k = 0; k < 256; k += 8) {
        float wv[8][2];
        #pragma unroll
        for (int kk = 0; kk < 8; ++kk) {
            wv[kk][0] = w[(k + kk) * 64 + j0];
            wv[kk][1] = w[(k + kk) * 64 + j0 + 32];
        }
        #pragma unroll
        for (int r = 0; r < 4; ++r) {
            const short8v hv = *reinterpret_cast<const short8v*>(&hs[(r0 + r) * 256 + k]);
            #pragma unroll
            for (int kk = 0; kk < 8; ++kk) {
                const float xa = b2f(hv[kk]);
                acc[r][0] = fmaf(xa, wv[kk][0], acc[r][0]);
                acc[r][1] = fmaf(xa, wv[kk][1], acc[r][1]);
            }
        }
    }
    #pragma unroll
    for (int c = 0; c < 2; ++c) {
        const int j = j0 + 32 * c;
        const float sc = rsqrtf(v[j] + BN_EPS) * g[j];
        const float sh = (bias[j] - m[j]) * sc + bb[j];
        #pragma unroll
        for (int r = 0; r < 4; ++r) {
            const size_t rowi = row0 + r0 + r;
            const float y = elu_f(acc[r][c] * sc + sh);
            feat[rowi * 64 + j] = y;
            featbf[rowi * 64 + j] = f2bf(y);
            out[OFX + rowi * 64 + j] = y;
            out[OZ + rowi * 80 + j] = y;
        }
    }
}

// ---------------- GCN: gather featbf (64-dim bf16) FIRST (linearity) ----------------
// aggF[node] = feat[node]/deg + sum_e ew*feat[src]; 32 lanes/node, uint = 2 bf16.
__global__ __launch_bounds__(256) void k_feat_gather(
    const unsigned* __restrict__ featp, const float* __restrict__ deg,
    const int* __restrict__ off, const int* __restrict__ csr_src, const float* __restrict__ csr_w,
    float* __restrict__ aggF)
{
    const int t = threadIdx.x;
    const int node = blockIdx.x * 8 + (t >> 5);   // grid = NN/8
    const int lane = t & 31;                       // feats 2*lane, 2*lane+1
    const float dg = deg[node];
    const float dinv = 1.0f / dg;
    const unsigned ps = featp[(size_t)node * 32 + lane];
    float a0 = b2f_lo(ps) * dinv;
    float a1 = b2f_hi(ps) * dinv;
    const int beg = off[node];
    const int end = beg + ((int)dg - 1);
    for (int s = beg; s < end; ++s) {
        const int src = csr_src[s];
        const float w = csr_w[s];
        const unsigned p = featp[(size_t)src * 32 + lane];
        a0 = fmaf(b2f_lo(p), w, a0);
        a1 = fmaf(b2f_hi(p), w, a1);
    }
    float2 o; o.x = a0; o.y = a1;
    *reinterpret_cast<float2*>(&aggF[(size_t)node * 64 + lane * 2]) = o;
}

// ---------------- conv projection fused: cmat = ReLU(BN(aggF @ conv_w + cb)) ----------------
__global__ __launch_bounds__(256) void k_conv_proj(
    const float* __restrict__ aggF, const float* __restrict__ w, const float* __restrict__ cb,
    const float* __restrict__ g, const float* __restrict__ bb,
    const float* __restrict__ m, const float* __restrict__ v,
    float* __restrict__ cmat)
{
    __shared__ float fs[32 * 64];
    const int t = threadIdx.x;
    const int row0 = blockIdx.x * 32;
    const int j0 = t & 63;
    const int r0 = (t >> 6) * 8;
    float acc[8][2] = {};
    for (int idx = t; idx < 512; idx += 256) {
        const int r = idx >> 4, c4 = idx & 15;
        *reinterpret_cast<float4*>(&fs[r * 64 + c4 * 4]) =
            *reinterpret_cast<const float4*>(&aggF[(size_t)(row0 + r) * 64 + c4 * 4]);
    }
    __syncthreads();
    #pragma unroll 1
    for (int k = 0; k < 64; k += 4) {
        float wv[4][2];
        #pragma unroll
        for (int kk = 0; kk < 4; ++kk) {
            wv[kk][0] = w[(k + kk) * 128 + j0];
            wv[kk][1] = w[(k + kk) * 128 + j0 + 64];
        }
        #pragma unroll
        for (int r = 0; r < 8; ++r) {
            const float4 xv = *reinterpret_cast<const float4*>(&fs[(r0 + r) * 64 + k]);
            const float xa[4] = {xv.x, xv.y, xv.z, xv.w};
            #pragma unroll
            for (int kk = 0; kk < 4; ++kk) {
                acc[r][0] = fmaf(xa[kk], wv[kk][0], acc[r][0]);
                acc[r][1] = fmaf(xa[kk], wv[kk][1], acc[r][1]);
            }
        }
    }
    #pragma unroll
    for (int c = 0; c < 2; ++c) {
        const int j = j0 + 64 * c;
        const float sc = rsqrtf(v[j] + BN_EPS) * g[j];
        const float sh = bb[j] - m[j] * sc;
        const float cbj = cb[j];
        #pragma unroll
        for (int r = 0; r < 8; ++r) {
            const size_t rowi = row0 + r0 + r;
            const float val = acc[r][c] + cbj;
            cmat[rowi * 128 + j] = fmaxf(fmaf(val, sc, sh), 0.f);
        }
    }
}

// ---------------- mean|logvar projection: cmat @ [mw|lw] -> m2bf (bf16) ----------------
__global__ __launch_bounds__(256) void k_mlp_proj(
    const float* __restrict__ c, const float* __restrict__ mw, const float* __restrict__ lw,
    short* __restrict__ m2bf)
{
    __shared__ float cs[32 * 128];
    const int t = threadIdx.x;
    const int row0 = blockIdx.x * 32;
    const int j0 = t & 15;
    const int r0 = (t >> 4) * 2;
    float acc[2][2] = {};
    for (int idx = t; idx < 1024; idx += 256) {
        const int r = idx >> 5, c4 = idx & 31;
        *reinterpret_cast<float4*>(&cs[r * 128 + c4 * 4]) =
            *reinterpret_cast<const float4*>(&c[(size_t)(row0 + r) * 128 + c4 * 4]);
    }
    __syncthreads();
    #pragma unroll 1
    for (int k = 0; k < 128; k += 4) {
        float wv[4][2];
        #pragma unroll
        for (int kk = 0; kk < 4; ++kk) {
            wv[kk][0] = mw[(k + kk) * 16 + j0];
            wv[kk][1] = lw[(k + kk) * 16 + j0];
        }
        #pragma unroll
        for (int r = 0; r < 2; ++r) {
            const float4 xv = *reinterpret_cast<const float4*>(&cs[(r0 + r) * 128 + k]);
            const float xa[4] = {xv.x, xv.y, xv.z, xv.w};
            #pragma unroll
            for (int kk = 0; kk < 4; ++kk) {
                acc[r][0] = fmaf(xa[kk], wv[kk][0], acc[r][0]);
                acc[r][1] = fmaf(xa[kk], wv[kk][1], acc[r][1]);
            }
        }
    }
    #pragma unroll
    for (int r = 0; r < 2; ++r) {
        const size_t rowi = row0 + r0 + r;
        m2bf[rowi * 32 + j0] = f2bf(acc[r][0]);
        m2bf[rowi * 32 + 16 + j0] = f2bf(acc[r][1]);
    }
}

// ---------------- CSR gather mean|logvar (32 bf16 feats) + self-loop + bias ----------------
// 16 lanes/node, uint = 2 bf16.
__global__ __launch_bounds__(256) void k_mlp_gather(
    const unsigned* __restrict__ m2p, const float* __restrict__ deg,
    const int* __restrict__ off, const int* __restrict__ csr_src, const float* __restrict__ csr_w,
    const float* __restrict__ mb, const float* __restrict__ lb,
    float* __restrict__ agg2)
{
    const int t = threadIdx.x;
    const int node = blockIdx.x * 16 + (t >> 4);   // grid = NN/16
    const int lane = t & 15;                        // feats 2*lane, 2*lane+1
    const int f0 = lane * 2, f1 = lane * 2 + 1;
    const float dg = deg[node];
    const float dinv = 1.0f / dg;
    const float b0 = (f0 < 16) ? mb[f0] : lb[f0 - 16];
    const float b1 = (f1 < 16) ? mb[f1] : lb[f1 - 16];
    const unsigned ps = m2p[(size_t)node * 16 + lane];
    float a0 = fmaf(b2f_lo(ps), dinv, b0);
    float a1 = fmaf(b2f_hi(ps), dinv, b1);
    const int beg = off[node];
    const int end = beg + ((int)dg - 1);
    for (int s = beg; s < end; ++s) {
        const int src = csr_src[s];
        const float w = csr_w[s];
        const unsigned p = m2p[(size_t)src * 16 + lane];
        a0 = fmaf(b2f_lo(p), w, a0);
        a1 = fmaf(b2f_hi(p), w, a1);
    }
    float2 o; o.x = a0; o.y = a1;
    *reinterpret_cast<float2*>(&agg2[(size_t)node * 32 + lane * 2]) = o;
}

// ---------------- finalize pre: mu/logvar/z writes, dec0 -> d0bf (bf16), q ----------------
__global__ __launch_bounds__(256) void k_final_pre(
    const float* __restrict__ feat, const float* __restrict__ agg2,
    const float* __restrict__ d0w, const float* __restrict__ d0b,
    const float* __restrict__ g, const float* __restrict__ bb,
    const float* __restrict__ m, const float* __restrict__ v,
    const float* __restrict__ cluster,
    short* __restrict__ d0bf,
    float* __restrict__ out)
{
    __shared__ float zs[8][80];
    __shared__ float qs[8][15];
    const int t = threadIdx.x;
    const int row0 = blockIdx.x * 8;

    for (int idx = t; idx < 512; idx += 256) {
        const int r = idx >> 6, k = idx & 63;
        zs[r][k] = feat[(size_t)(row0 + r) * 64 + k];
    }
    if (t < 128) {
        const int r = t >> 4, k = t & 15;
        const size_t rowi = row0 + r;
        const float muv = agg2[rowi * 32 + k];
        const float lv = agg2[rowi * 32 + 16 + k];
        zs[r][64 + k] = muv;
        out[OMU + rowi * 16 + k] = muv;
        out[OGZ + rowi * 16 + k] = muv;
        out[OZ + rowi * 80 + 64 + k] = muv;
        out[OLV + rowi * 16 + k] = lv;
    }
    __syncthreads();

    // dec0: d0 = ELU(BN(z @ d0w + d0b)) -> bf16 global
    for (int idx = t; idx < 512; idx += 256) {
        const int r = idx >> 6, n = idx & 63;
        float acc = 0.f;
        #pragma unroll
        for (int k = 0; k < 80; k += 4) {
            const float4 zv = *reinterpret_cast<const float4*>(&zs[r][k]);
            acc = fmaf(zv.x, d0w[(k + 0) * 64 + n], acc);
            acc = fmaf(zv.y, d0w[(k + 1) * 64 + n], acc);
            acc = fmaf(zv.z, d0w[(k + 2) * 64 + n], acc);
            acc = fmaf(zv.w, d0w[(k + 3) * 64 + n], acc);
        }
        acc += d0b[n];
        const float sc = rsqrtf(v[n] + BN_EPS) * g[n];
        const float y = elu_f((acc - m[n]) * sc + bb[n]);
        d0bf[(size_t)(row0 + r) * 64 + n] = f2bf(y);
    }

    // student-t q
    if (t < 120) {
        const int r = t / 15, c = t % 15;
        float zz = 0.f, cc = 0.f, dot = 0.f;
        #pragma unroll 1
        for (int k = 0; k < 80; ++k) {
            const float zv = zs[r][k];
            const float cv = cluster[c * 80 + k];
            zz = fmaf(zv, zv, zz);
            cc = fmaf(cv, cv, cc);
            dot = fmaf(zv, cv, dot);
        }
        const float dist = fmaxf(zz + cc - 2.f * dot, 0.f);
        qs[r][c] = powf(1.0f / (1.0f + dist / 0.9f + 1e-8f), 0.95f);
    }
    __syncthreads();
    if (t < 120) {
        const int r = t / 15, c = t % 15;
        float s = 0.f;
        #pragma unroll
        for (int c2 = 0; c2 < 15; ++c2) s += qs[r][c2];
        out[OQ + (size_t)(row0 + r) * 15 + c] = qs[r][c] / s;
    }
}

// ---------------- dec1 via MFMA: de_feat = d0 @ d1w + d1b ----------------
__global__ __launch_bounds__(256) void k_dec1_mfma(
    const short* __restrict__ d0bf, const short* __restrict__ wt2,
    const float* __restrict__ d1b, float* __restrict__ out)
{
    const int t = threadIdx.x;
    const int lane = t & 63;
    const int wave = t >> 6;
    const int wm = (wave >> 1) * 64;
    const int wn = (wave & 1) * 64;
    const int row0 = blockIdx.x * 128;
    const int col0 = blockIdx.y * 128;
    const int kc = lane >> 4;
    const int lr = lane & 15;

    f32x4 acc[4][4];
    #pragma unroll
    for (int mi = 0; mi < 4; ++mi)
        #pragma unroll
        for (int ni = 0; ni < 4; ++ni)
            acc[mi][ni] = (f32x4){0.f, 0.f, 0.f, 0.f};

    #pragma unroll
    for (int ks = 0; ks < 2; ++ks) {
        const int k0 = ks * 32 + kc * 8;
        short8v a[4], b[4];
        #pragma unroll
        for (int mi = 0; mi < 4; ++mi) {
            const int row = row0 + wm + mi * 16 + lr;
            if (row < NN)
                a[mi] = *reinterpret_cast<const short8v*>(&d0bf[(size_t)row * 64 + k0]);
            else
                a[mi] = (short8v){0, 0, 0, 0, 0, 0, 0, 0};
        }
        #pragma unroll
        for (int ni = 0; ni < 4; ++ni) {
            const int col = col0 + wn + ni * 16 + lr;
            b[ni] = *reinterpret_cast<const short8v*>(&wt2[(size_t)col * 64 + k0]);
        }
        #pragma unroll
        for (int mi = 0; mi < 4; ++mi)
            #pragma unroll
            for (int ni = 0; ni < 4; ++ni)
                acc[mi][ni] = __builtin_amdgcn_mfma_f32_16x16x32_bf16(a[mi], b[ni], acc[mi][ni], 0, 0, 0);
    }

    // epilogue: +bias, write de_feat (C/D: col=lane&15 within frag, row=(lane>>4)*4+j)
    #pragma unroll
    for (int ni = 0; ni < 4; ++ni) {
        const int col = col0 + wn + ni * 16 + lr;
        if (col < DIN) {
            const float bv = d1b[col];
            #pragma unroll
            for (int mi = 0; mi < 4; ++mi) {
                #pragma unroll
                for (int j = 0; j < 4; ++j) {
                    const int row = row0 + wm + mi * 16 + (lane >> 4) * 4 + j;
                    if (row < NN)
                        out[ODE + (size_t)row * DIN + col] = acc[mi][ni][j] + bv;
                }
            }
        }
    }
}

extern "C" void kernel_launch(void* const* d_in, const int* in_sizes, int n_in,
                              void* d_out, int out_size, void* d_ws, size_t ws_size,
                              hipStream_t stream)
{
    const float* x       = (const float*)d_in[0];
    const void*  ei      = d_in[1];
    const float* enc0_w  = (const float*)d_in[2];
    const float* enc0_b  = (const float*)d_in[3];
    const float* enc0_g  = (const float*)d_in[4];
    const float* enc0_bb = (const float*)d_in[5];
    const float* enc0_m  = (const float*)d_in[6];
    const float* enc0_v  = (const float*)d_in[7];
    const float* enc1_w  = (const float*)d_in[8];
    const float* enc1_b  = (const float*)d_in[9];
    const float* enc1_g  = (const float*)d_in[10];
    const float* enc1_bb = (const float*)d_in[11];
    const float* enc1_m  = (const float*)d_in[12];
    const float* enc1_v  = (const float*)d_in[13];
    const float* conv_w  = (const float*)d_in[14];
    const float* conv_b  = (const float*)d_in[15];
    const float* conv_g  = (const float*)d_in[16];
    const float* conv_bb = (const float*)d_in[17];
    const float* conv_m  = (const float*)d_in[18];
    const float* conv_v  = (const float*)d_in[19];
    const float* mean_w  = (const float*)d_in[20];
    const float* mean_b  = (const float*)d_in[21];
    const float* logvar_w = (const float*)d_in[22];
    const float* logvar_b = (const float*)d_in[23];
    const float* dec0_w  = (const float*)d_in[24];
    const float* dec0_b  = (const float*)d_in[25];
    const float* dec0_g  = (const float*)d_in[26];
    const float* dec0_bb = (const float*)d_in[27];
    const float* dec0_m  = (const float*)d_in[28];
    const float* dec0_v  = (const float*)d_in[29];
    const float* dec1_w  = (const float*)d_in[30];
    const float* dec1_b  = (const float*)d_in[31];
    const float* cluster = (const float*)d_in[32];

    float* ws = (float*)d_ws;
    float* deg  = ws;                              // N
    float* feat = ws + NN;                         // 64N
    float* A    = ws + (size_t)65 * NN;            // 256N region, multi-use
    size_t base = (size_t)321 * NN;
    int*   off     = (int*)(ws + base);                        // N
    int*   cursor  = (int*)(ws + base + NN);                   // N
    int*   bsum    = (int*)(ws + base + 2 * (size_t)NN);       // 512
    int*   csr_src = (int*)(ws + base + 2 * (size_t)NN + 512);             // E
    float* csr_w   = (float*)(ws + base + 2 * (size_t)NN + 512 + NE);      // E
    short* wt      = (short*)(ws + base + 2 * (size_t)NN + 512 + 2 * (size_t)NE);  // 256*1024 bf16
    int*   flag    = (int*)(ws + base + 2 * (size_t)NN + 512 + 2 * (size_t)NE + 131072); // 1

    short* h1bf   = (short*)A;                     // N x 256 bf16 (A[0..128N) floats)
    short* featbf = (short*)(A + (size_t)128 * NN); // N x 64 bf16 (dead after feat_gather; cmat overwrites)
    float* aggF   = A;                             // N x 64 f32 (after h1bf dead)
    float* cmat   = A + (size_t)128 * NN;          // N x 128 f32
    short* m2bf   = (short*)A;                     // N x 32 bf16 (after aggF dead)
    float* agg2   = A + (size_t)32 * NN;           // N x 32 f32
    short* d0bf   = (short*)(A + (size_t)64 * NN); // N x 64 bf16
    short* wt2    = wt;                            // 1024 x 64 bf16 (reuses enc0 wt)

    float* out = (float*)d_out;

    k_detect<<<1, 256, 0, stream>>>((const int*)ei, flag);
    k_deg_init<<<NB, 256, 0, stream>>>(deg);
    k_deg_accum<<<NE / 256, 256, 0, stream>>>(ei, flag, deg);

    // CSR build
    k_scan1<<<NB, 256, 0, stream>>>(deg, off, bsum, cursor);
    k_scan2<<<1, 512, 0, stream>>>(bsum);
    k_scan3<<<NB, 256, 0, stream>>>(off, bsum);
    k_fill<<<NE / 256, 256, 0, stream>>>(ei, flag, deg, off, cursor, csr_src, csr_w);

    // enc0 via MFMA (single pass over x, coalesced A-stage)
    k_wt<<<1024, 256, 0, stream>>>(enc0_w, wt);
    k_enc0_mfma<<<(NN + 127) / 128, 512, 0, stream>>>(x, wt, enc0_b, enc0_g, enc0_bb, enc0_m, enc0_v, h1bf);
    // dec1 weight prep (reuses wt buffer — enc0 done with it)
    k_wt2<<<256, 256, 0, stream>>>(dec1_w, wt2);

    k_enc1<<<NN / 32, 256, 0, stream>>>(h1bf, enc1_w, enc1_b, enc1_g, enc1_bb, enc1_m, enc1_v,
                                        feat, featbf, out);

    // GCN conv: aggregate bf16 feat first (linearity), then fused proj+BN+ReLU
    k_feat_gather<<<NN / 8, 256, 0, stream>>>((const unsigned*)featbf, deg, off, csr_src, csr_w, aggF);
    k_conv_proj<<<NN / 32, 256, 0, stream>>>(aggF, conv_w, conv_b,
                                             conv_g, conv_bb, conv_m, conv_v, cmat);

    k_mlp_proj<<<NN / 32, 256, 0, stream>>>(cmat, mean_w, logvar_w, m2bf);
    k_mlp_gather<<<NN / 16, 256, 0, stream>>>((const unsigned*)m2bf, deg, off, csr_src, csr_w,
                                              mean_b, logvar_b, agg2);

    k_final_pre<<<NN / 8, 256, 0, stream>>>(feat, agg2, dec0_w, dec0_b, dec0_g, dec0_bb, dec0_m, dec0_v,
                                            cluster, d0bf, out);
    {
        dim3 grid((NN + 127) / 128, 8);
        k_dec1_mfma<<<grid, 256, 0, stream>>>(d0bf, wt2, dec1_b, out);
    }
}

// Round 17
// 1052.674 us; speedup vs baseline: 1.2677x; 1.0376x over previous
//
#include <hip/hip_runtime.h>
#include <hip/hip_bf16.h>

#define NN 100000
#define NE 1600000
#define DIN 1000
#define BN_EPS 1e-3f
#define NB 391   // ceil(NN/256)

// output element offsets (concat of z, mu, logvar, de_feat, q, feat_x, gnn_z) — float32 out
#define OZ  ((size_t)0)
#define OMU ((size_t)NN*80)
#define OLV ((size_t)NN*96)
#define ODE ((size_t)NN*112)
#define OQ  ((size_t)NN*1112)
#define OFX ((size_t)NN*1127)
#define OGZ ((size_t)NN*1191)

typedef __attribute__((ext_vector_type(8))) short short8v;   // 8 bf16 (4 VGPRs)
typedef __attribute__((ext_vector_type(4))) short short4v;   // 4 bf16 (2 VGPRs)
typedef __attribute__((ext_vector_type(4))) float f32x4;     // MFMA accumulator

__device__ __forceinline__ float elu_f(float x) { return x > 0.f ? x : expf(x) - 1.f; }

// fp32 -> bf16 bits, round-to-nearest-even
__device__ __forceinline__ short f2bf(float f) {
    union { float f; unsigned u; } c; c.f = f;
    unsigned r = c.u + 0x7fffu + ((c.u >> 16) & 1u);
    return (short)(r >> 16);
}
// bf16 bits -> fp32
__device__ __forceinline__ float b2f(short s) {
    union { unsigned u; float f; } c; c.u = ((unsigned)(unsigned short)s) << 16; return c.f;
}
__device__ __forceinline__ float b2f_lo(unsigned p) {
    union { unsigned u; float f; } c; c.u = p << 16; return c.f;
}
__device__ __forceinline__ float b2f_hi(unsigned p) {
    union { unsigned u; float f; } c; c.u = p & 0xffff0000u; return c.f;
}

// Edge index may arrive as int32 or int64; logical element idx in flat (2*E) array.
__device__ __forceinline__ int edge_at(const void* ei, int is64, size_t idx) {
    if (is64) return (int)((const long long*)ei)[idx];
    return ((const int*)ei)[idx];
}

// ---------------- dtype detection ----------------
__global__ __launch_bounds__(256) void k_detect(const int* __restrict__ ei, int* __restrict__ flag) {
    __shared__ int nz;
    if (threadIdx.x == 0) nz = 0;
    __syncthreads();
    for (int i = threadIdx.x; i < 2048; i += 256)
        if (ei[2 * i + 1] != 0) nz = 1;
    __syncthreads();
    if (threadIdx.x == 0) flag[0] = (nz == 0) ? 1 : 0;  // 1 => int64
}

// ---------------- degree ----------------
__global__ __launch_bounds__(256) void k_deg_init(float* __restrict__ deg) {
    int i = blockIdx.x * 256 + threadIdx.x;
    if (i < NN) deg[i] = 1.0f;
}

__global__ __launch_bounds__(256) void k_deg_accum(const void* __restrict__ ei, const int* __restrict__ flag,
                                                   float* __restrict__ deg) {
    const int is64 = flag[0];
    int e = blockIdx.x * 256 + threadIdx.x;
    if (e < NE) atomicAdd(&deg[edge_at(ei, is64, (size_t)NE + e)], 1.0f);
}

// ---------------- CSR build: exclusive scan of in-edge counts ----------------
__global__ __launch_bounds__(256) void k_scan1(const float* __restrict__ deg, int* __restrict__ off,
                                               int* __restrict__ bsum, int* __restrict__ cursor) {
    __shared__ int s[256];
    const int t = threadIdx.x;
    const int i = blockIdx.x * 256 + t;
    const int vv = (i < NN) ? ((int)deg[i]) - 1 : 0;
    if (i < NN) cursor[i] = 0;
    s[t] = vv;
    __syncthreads();
    for (int d = 1; d < 256; d <<= 1) {
        const int u = (t >= d) ? s[t - d] : 0;
        __syncthreads();
        s[t] += u;
        __syncthreads();
    }
    if (i < NN) off[i] = s[t] - vv;           // exclusive, pre-block-offset
    if (t == 255) bsum[blockIdx.x] = s[t];    // block total
}

__global__ __launch_bounds__(512) void k_scan2(int* __restrict__ bsum) {
    __shared__ int s[512];
    const int t = threadIdx.x;
    const int vv = (t < NB) ? bsum[t] : 0;
    s[t] = vv;
    __syncthreads();
    for (int d = 1; d < 512; d <<= 1) {
        const int u = (t >= d) ? s[t - d] : 0;
        __syncthreads();
        s[t] += u;
        __syncthreads();
    }
    if (t < NB) bsum[t] = s[t] - vv;          // exclusive block prefix
}

__global__ __launch_bounds__(256) void k_scan3(int* __restrict__ off, const int* __restrict__ bsum) {
    const int i = blockIdx.x * 256 + threadIdx.x;
    if (i < NN) off[i] += bsum[blockIdx.x];
}

// interleaved CSR: one int2 {src, w_bits} per edge — single 8B scatter store
__global__ __launch_bounds__(256) void k_fill(const void* __restrict__ ei, const int* __restrict__ flag,
                                              const float* __restrict__ deg, const int* __restrict__ off,
                                              int* __restrict__ cursor, int2* __restrict__ csr_e) {
    const int is64 = flag[0];
    const int e = blockIdx.x * 256 + threadIdx.x;
    if (e >= NE) return;
    const int r = edge_at(ei, is64, e);
    const int c = edge_at(ei, is64, (size_t)NE + e);
    const float w = rsqrtf(deg[r]) * rsqrtf(deg[c]);
    const int p = atomicAdd(&cursor[c], 1);
    csr_e[off[c] + p] = make_int2(r, __float_as_int(w));
}

// ---------------- enc0 weight prep: w[1000][256] f32 -> k-major bf16 granules ----------------
__global__ __launch_bounds__(256) void k_wt(const float* __restrict__ w, short* __restrict__ wt) {
    const int tid = blockIdx.x * 256 + threadIdx.x;   // 256*1024 elements
    const int c = tid >> 10;
    const int k = tid & 1023;
    wt[((size_t)(k >> 3) * 256 + c) * 8 + (k & 7)] = (k < DIN) ? f2bf(w[(size_t)k * 256 + c]) : (short)0;
}

// ---------------- dec1 weight prep: w[64][1000] f32 -> wt2[1024][64] bf16 (cols zero-padded) ----------------
__global__ __launch_bounds__(256) void k_wt2(const float* __restrict__ w, short* __restrict__ wt2) {
    const int tid = blockIdx.x * 256 + threadIdx.x;   // 1024*64 elements
    const int c = tid >> 6;
    const int k = tid & 63;
    wt2[(size_t)c * 64 + k] = (c < DIN) ? f2bf(w[(size_t)k * DIN + c]) : (short)0;
}

// ---------------- encoder L0 via MFMA: h1bf = bf16(ELU(BN(x @ w))) ----------------
// Block tile 128x256, 8 waves (2 row x 4 col), wave tile 64x64, K_STEP=32.
// A-stage coalesced: thread t = (row t>>3, float4-slot t&7) for rows t>>3, t>>3+64.
__global__ __launch_bounds__(512, 2) void k_enc0_mfma(
    const float* __restrict__ x, const short* __restrict__ wt, const float* __restrict__ bias,
    const float* __restrict__ g, const float* __restrict__ bb,
    const float* __restrict__ m, const float* __restrict__ v,
    short* __restrict__ h1bf)
{
    __shared__ short As[4 * 128 * 8];
    __shared__ short Bs[4 * 256 * 8];
    const int t = threadIdx.x;           // 0..511
    const int lane = t & 63;
    const int wave = t >> 6;             // 0..7
    const int wm = (wave >> 2) * 64;     // 0,64
    const int wn = (wave & 3) * 64;      // 0,64,128,192
    const int row0 = blockIdx.x * 128;

    f32x4 acc[4][4];
    #pragma unroll
    for (int mi = 0; mi < 4; ++mi)
        #pragma unroll
        for (int ni = 0; ni < 4; ++ni)
            acc[mi][ni] = (f32x4){0.f, 0.f, 0.f, 0.f};

    const int kq = t & 7;
    const int rA0 = t >> 3;              // 0..63
    const int rA1 = rA0 + 64;            // 64..127
    const int gr0 = (row0 + rA0 < NN) ? (row0 + rA0) : (NN - 1);
    const int gr1 = (row0 + rA1 < NN) ? (row0 + rA1) : (NN - 1);
    const float* xb0 = x + (size_t)gr0 * DIN;
    const float* xb1 = x + (size_t)gr1 * DIN;
    short4v* aslot0 = reinterpret_cast<short4v*>(&As[(((kq >> 1) * 128) + rA0) * 8 + (kq & 1) * 4]);
    short4v* aslot1 = reinterpret_cast<short4v*>(&As[(((kq >> 1) * 128) + rA1) * 8 + (kq & 1) * 4]);

    const int colB = t & 255;
    const int kcB0 = t >> 8;
    const int kcB1 = 2 + (t >> 8);

    const int kc = lane >> 4;    // 0..3
    const int lr = lane & 15;

    float4 pf0 = *reinterpret_cast<const float4*>(xb0 + kq * 4);
    float4 pf1 = *reinterpret_cast<const float4*>(xb1 + kq * 4);

    for (int ks = 0; ks < 32; ++ks) {
        __syncthreads();
        {
            const int kb = ks * 32 + kq * 4;
            short4v p0, p1;
            if (kb + 4 <= DIN) {
                p0[0] = f2bf(pf0.x); p0[1] = f2bf(pf0.y); p0[2] = f2bf(pf0.z); p0[3] = f2bf(pf0.w);
                p1[0] = f2bf(pf1.x); p1[1] = f2bf(pf1.y); p1[2] = f2bf(pf1.z); p1[3] = f2bf(pf1.w);
            } else {
                p0 = (short4v){0, 0, 0, 0};
                p1 = (short4v){0, 0, 0, 0};
            }
            *aslot0 = p0;
            *aslot1 = p1;
        }
        {
            const int gbase = ks * 4;
            *reinterpret_cast<short8v*>(&Bs[((size_t)kcB0 * 256 + colB) * 8]) =
                *reinterpret_cast<const short8v*>(&wt[((size_t)(gbase + kcB0) * 256 + colB) * 8]);
            *reinterpret_cast<short8v*>(&Bs[((size_t)kcB1 * 256 + colB) * 8]) =
                *reinterpret_cast<const short8v*>(&wt[((size_t)(gbase + kcB1) * 256 + colB) * 8]);
        }
        if (ks + 1 < 32) {
            const int kb2 = (ks + 1) * 32 + kq * 4;
            const int ko = (kb2 + 4 <= DIN) ? kb2 : 0;
            pf0 = *reinterpret_cast<const float4*>(xb0 + ko);
            pf1 = *reinterpret_cast<const float4*>(xb1 + ko);
        }
        __syncthreads();
        short8v a[4], b[4];
        #pragma unroll
        for (int mi = 0; mi < 4; ++mi)
            a[mi] = *reinterpret_cast<const short8v*>(&As[((size_t)kc * 128 + wm + mi * 16 + lr) * 8]);
        #pragma unroll
        for (int ni = 0; ni < 4; ++ni)
            b[ni] = *reinterpret_cast<const short8v*>(&Bs[((size_t)kc * 256 + wn + ni * 16 + lr) * 8]);
        #pragma unroll
        for (int mi = 0; mi < 4; ++mi)
            #pragma unroll
            for (int ni = 0; ni < 4; ++ni)
                acc[mi][ni] = __builtin_amdgcn_mfma_f32_16x16x32_bf16(a[mi], b[ni], acc[mi][ni], 0, 0, 0);
    }

    float sc[4], sh[4];
    int cols[4];
    #pragma unroll
    for (int ni = 0; ni < 4; ++ni) {
        const int col = wn + ni * 16 + lr;
        cols[ni] = col;
        const float s = rsqrtf(v[col] + BN_EPS) * g[col];
        sc[ni] = s;
        sh[ni] = (bias[col] - m[col]) * s + bb[col];
    }
    #pragma unroll
    for (int mi = 0; mi < 4; ++mi) {
        #pragma unroll
        for (int j = 0; j < 4; ++j) {
            const int row = row0 + wm + mi * 16 + (lane >> 4) * 4 + j;
            if (row < NN) {
                #pragma unroll
                for (int ni = 0; ni < 4; ++ni) {
                    const float y = acc[mi][ni][j] * sc[ni] + sh[ni];
                    h1bf[(size_t)row * 256 + cols[ni]] = f2bf(elu_f(y));
                }
            }
        }
    }
}

// ---------------- encoder L1: h1bf[N,256] @ w[256,64] + BN + ELU -> feat, featbf, out ----------------
__global__ __launch_bounds__(256) void k_enc1(
    const short* __restrict__ h1bf, const float* __restrict__ w, const float* __restrict__ bias,
    const float* __restrict__ g, const float* __restrict__ bb,
    const float* __restrict__ m, const float* __restrict__ v,
    float* __restrict__ feat, short* __restrict__ featbf, float* __restrict__ out)
{
    __shared__ short hs[32 * 256];
    const int t = threadIdx.x;
    const int row0 = blockIdx.x * 32;
    const int j0 = t & 31;
    const int r0 = (t >> 5) * 4;
    float acc[4][2] = {};
    for (int idx = t; idx < 1024; idx += 256) {
        const int r = idx >> 5, c8 = idx & 31;
        *reinterpret_cast<short8v*>(&hs[r * 256 + c8 * 8]) =
            *reinterpret_cast<const short8v*>(&h1bf[(size_t)(row0 + r) * 256 + c8 * 8]);
    }
    __syncthreads();
    #pragma unroll 1
    for (int k = 0; k < 256; k += 8) {
        float wv[8][2];
        #pragma unroll
        for (int kk = 0; kk < 8; ++kk) {
            wv[kk][0] = w[(k + kk) * 64 + j0];
            wv[kk][1] = w[(k + kk) * 64 + j0 + 32];
        }
        #pragma unroll
        for (int r = 0; r < 4; ++r) {
            const short8v hv = *reinterpret_cast<const short8v*>(&hs[(r0 + r) * 256 + k]);
            #pragma unroll
            for (int kk = 0; kk < 8; ++kk) {
                const float xa = b2f(hv[kk]);
                acc[r][0] = fmaf(xa, wv[kk][0], acc[r][0]);
                acc[r][1] = fmaf(xa, wv[kk][1], acc[r][1]);
            }
        }
    }
    #pragma unroll
    for (int c = 0; c < 2; ++c) {
        const int j = j0 + 32 * c;
        const float sc = rsqrtf(v[j] + BN_EPS) * g[j];
        const float sh = (bias[j] - m[j]) * sc + bb[j];
        #pragma unroll
        for (int r = 0; r < 4; ++r) {
            const size_t rowi = row0 + r0 + r;
            const float y = elu_f(acc[r][c] * sc + sh);
            feat[rowi * 64 + j] = y;
            featbf[rowi * 64 + j] = f2bf(y);
            out[OFX + rowi * 64 + j] = y;
            out[OZ + rowi * 80 + j] = y;
        }
    }
}

// ---------------- GCN: gather featbf (64-dim bf16) FIRST (linearity) ----------------
__global__ __launch_bounds__(256) void k_feat_gather(
    const unsigned* __restrict__ featp, const float* __restrict__ deg,
    const int* __restrict__ off, const int2* __restrict__ csr_e,
    float* __restrict__ aggF)
{
    const int t = threadIdx.x;
    const int node = blockIdx.x * 8 + (t >> 5);   // grid = NN/8
    const int lane = t & 31;                       // feats 2*lane, 2*lane+1
    const float dg = deg[node];
    const float dinv = 1.0f / dg;
    const unsigned ps = featp[(size_t)node * 32 + lane];
    float a0 = b2f_lo(ps) * dinv;
    float a1 = b2f_hi(ps) * dinv;
    const int beg = off[node];
    const int end = beg + ((int)dg - 1);
    for (int s = beg; s < end; ++s) {
        const int2 e = csr_e[s];
        const float w = __int_as_float(e.y);
        const unsigned p = featp[(size_t)e.x * 32 + lane];
        a0 = fmaf(b2f_lo(p), w, a0);
        a1 = fmaf(b2f_hi(p), w, a1);
    }
    float2 o; o.x = a0; o.y = a1;
    *reinterpret_cast<float2*>(&aggF[(size_t)node * 64 + lane * 2]) = o;
}

// ---------------- fused conv+mlp projection: aggF -> (cmat in LDS) -> m2bf ----------------
// Phase 1: cmat_tile = ReLU(BN(aggF @ conv_w + cb)) into LDS.
// Phase 2: m2 = cmat_tile @ [mw|lw] -> bf16 global. cmat never hits HBM.
__global__ __launch_bounds__(256) void k_conv_mlp_proj(
    const float* __restrict__ aggF, const float* __restrict__ w, const float* __restrict__ cb,
    const float* __restrict__ g, const float* __restrict__ bb,
    const float* __restrict__ m, const float* __restrict__ v,
    const float* __restrict__ mw, const float* __restrict__ lw,
    short* __restrict__ m2bf)
{
    __shared__ float fs[32 * 64];
    __shared__ float cs[32 * 128];
    const int t = threadIdx.x;
    const int row0 = blockIdx.x * 32;
    // ---- phase 1: conv GEMM (K=64) + bias + BN + ReLU -> cs ----
    {
        const int j0 = t & 63;
        const int r0 = (t >> 6) * 8;
        float acc[8][2] = {};
        for (int idx = t; idx < 512; idx += 256) {
            const int r = idx >> 4, c4 = idx & 15;
            *reinterpret_cast<float4*>(&fs[r * 64 + c4 * 4]) =
                *reinterpret_cast<const float4*>(&aggF[(size_t)(row0 + r) * 64 + c4 * 4]);
        }
        __syncthreads();
        #pragma unroll 1
        for (int k = 0; k < 64; k += 4) {
            float wv[4][2];
            #pragma unroll
            for (int kk = 0; kk < 4; ++kk) {
                wv[kk][0] = w[(k + kk) * 128 + j0];
                wv[kk][1] = w[(k + kk) * 128 + j0 + 64];
            }
            #pragma unroll
            for (int r = 0; r < 8; ++r) {
                const float4 xv = *reinterpret_cast<const float4*>(&fs[(r0 + r) * 64 + k]);
                const float xa[4] = {xv.x, xv.y, xv.z, xv.w};
                #pragma unroll
                for (int kk = 0; kk < 4; ++kk) {
                    acc[r][0] = fmaf(xa[kk], wv[kk][0], acc[r][0]);
                    acc[r][1] = fmaf(xa[kk], wv[kk][1], acc[r][1]);
                }
            }
        }
        #pragma unroll
        for (int c = 0; c < 2; ++c) {
            const int j = j0 + 64 * c;
            const float sc = rsqrtf(v[j] + BN_EPS) * g[j];
            const float sh = bb[j] - m[j] * sc;
            const float cbj = cb[j];
            #pragma unroll
            for (int r = 0; r < 8; ++r) {
                const float val = acc[r][c] + cbj;
                cs[(r0 + r) * 128 + j] = fmaxf(fmaf(val, sc, sh), 0.f);
            }
        }
    }
    __syncthreads();
    // ---- phase 2: mlp GEMM (K=128) from cs -> m2bf ----
    {
        const int j0 = t & 15;
        const int r0 = (t >> 4) * 2;
        float acc[2][2] = {};
        #pragma unroll 1
        for (int k = 0; k < 128; k += 4) {
            float wv[4][2];
            #pragma unroll
            for (int kk = 0; kk < 4; ++kk) {
                wv[kk][0] = mw[(k + kk) * 16 + j0];
                wv[kk][1] = lw[(k + kk) * 16 + j0];
            }
            #pragma unroll
            for (int r = 0; r < 2; ++r) {
                const float4 xv = *reinterpret_cast<const float4*>(&cs[(r0 + r) * 128 + k]);
                const float xa[4] = {xv.x, xv.y, xv.z, xv.w};
                #pragma unroll
                for (int kk = 0; kk < 4; ++kk) {
                    acc[r][0] = fmaf(xa[kk], wv[kk][0], acc[r][0]);
                    acc[r][1] = fmaf(xa[kk], wv[kk][1], acc[r][1]);
                }
            }
        }
        #pragma unroll
        for (int r = 0; r < 2; ++r) {
            const size_t rowi = row0 + r0 + r;
            m2bf[rowi * 32 + j0] = f2bf(acc[r][0]);
            m2bf[rowi * 32 + 16 + j0] = f2bf(acc[r][1]);
        }
    }
}

// ---------------- CSR gather mean|logvar (32 bf16 feats) + self-loop + bias ----------------
__global__ __launch_bounds__(256) void k_mlp_gather(
    const unsigned* __restrict__ m2p, const float* __restrict__ deg,
    const int* __restrict__ off, const int2* __restrict__ csr_e,
    const float* __restrict__ mb, const float* __restrict__ lb,
    float* __restrict__ agg2)
{
    const int t = threadIdx.x;
    const int node = blockIdx.x * 16 + (t >> 4);   // grid = NN/16
    const int lane = t & 15;                        // feats 2*lane, 2*lane+1
    const int f0 = lane * 2, f1 = lane * 2 + 1;
    const float dg = deg[node];
    const float dinv = 1.0f / dg;
    const float b0 = (f0 < 16) ? mb[f0] : lb[f0 - 16];
    const float b1 = (f1 < 16) ? mb[f1] : lb[f1 - 16];
    const unsigned ps = m2p[(size_t)node * 16 + lane];
    float a0 = fmaf(b2f_lo(ps), dinv, b0);
    float a1 = fmaf(b2f_hi(ps), dinv, b1);
    const int beg = off[node];
    const int end = beg + ((int)dg - 1);
    for (int s = beg; s < end; ++s) {
        const int2 e = csr_e[s];
        const float w = __int_as_float(e.y);
        const unsigned p = m2p[(size_t)e.x * 16 + lane];
        a0 = fmaf(b2f_lo(p), w, a0);
        a1 = fmaf(b2f_hi(p), w, a1);
    }
    float2 o; o.x = a0; o.y = a1;
    *reinterpret_cast<float2*>(&agg2[(size_t)node * 32 + lane * 2]) = o;
}

// ---------------- finalize pre: mu/logvar/z writes, dec0 -> d0bf (bf16), q ----------------
__global__ __launch_bounds__(256) void k_final_pre(
    const float* __restrict__ feat, const float* __restrict__ agg2,
    const float* __restrict__ d0w, const float* __restrict__ d0b,
    const float* __restrict__ g, const float* __restrict__ bb,
    const float* __restrict__ m, const float* __restrict__ v,
    const float* __restrict__ cluster,
    short* __restrict__ d0bf,
    float* __restrict__ out)
{
    __shared__ float zs[8][80];
    __shared__ float qs[8][15];
    const int t = threadIdx.x;
    const int row0 = blockIdx.x * 8;

    for (int idx = t; idx < 512; idx += 256) {
        const int r = idx >> 6, k = idx & 63;
        zs[r][k] = feat[(size_t)(row0 + r) * 64 + k];
    }
    if (t < 128) {
        const int r = t >> 4, k = t & 15;
        const size_t rowi = row0 + r;
        const float muv = agg2[rowi * 32 + k];
        const float lv = agg2[rowi * 32 + 16 + k];
        zs[r][64 + k] = muv;
        out[OMU + rowi * 16 + k] = muv;
        out[OGZ + rowi * 16 + k] = muv;
        out[OZ + rowi * 80 + 64 + k] = muv;
        out[OLV + rowi * 16 + k] = lv;
    }
    __syncthreads();

    // dec0: d0 = ELU(BN(z @ d0w + d0b)) -> bf16 global
    for (int idx = t; idx < 512; idx += 256) {
        const int r = idx >> 6, n = idx & 63;
        float acc = 0.f;
        #pragma unroll
        for (int k = 0; k < 80; k += 4) {
            const float4 zv = *reinterpret_cast<const float4*>(&zs[r][k]);
            acc = fmaf(zv.x, d0w[(k + 0) * 64 + n], acc);
            acc = fmaf(zv.y, d0w[(k + 1) * 64 + n], acc);
            acc = fmaf(zv.z, d0w[(k + 2) * 64 + n], acc);
            acc = fmaf(zv.w, d0w[(k + 3) * 64 + n], acc);
        }
        acc += d0b[n];
        const float sc = rsqrtf(v[n] + BN_EPS) * g[n];
        const float y = elu_f((acc - m[n]) * sc + bb[n]);
        d0bf[(size_t)(row0 + r) * 64 + n] = f2bf(y);
    }

    // student-t q
    if (t < 120) {
        const int r = t / 15, c = t % 15;
        float zz = 0.f, cc = 0.f, dot = 0.f;
        #pragma unroll 1
        for (int k = 0; k < 80; ++k) {
            const float zv = zs[r][k];
            const float cv = cluster[c * 80 + k];
            zz = fmaf(zv, zv, zz);
            cc = fmaf(cv, cv, cc);
            dot = fmaf(zv, cv, dot);
        }
        const float dist = fmaxf(zz + cc - 2.f * dot, 0.f);
        qs[r][c] = powf(1.0f / (1.0f + dist / 0.9f + 1e-8f), 0.95f);
    }
    __syncthreads();
    if (t < 120) {
        const int r = t / 15, c = t % 15;
        float s = 0.f;
        #pragma unroll
        for (int c2 = 0; c2 < 15; ++c2) s += qs[r][c2];
        out[OQ + (size_t)(row0 + r) * 15 + c] = qs[r][c] / s;
    }
}

// ---------------- dec1 via MFMA: de_feat = d0 @ d1w + d1b ----------------
__global__ __launch_bounds__(256) void k_dec1_mfma(
    const short* __restrict__ d0bf, const short* __restrict__ wt2,
    const float* __restrict__ d1b, float* __restrict__ out)
{
    const int t = threadIdx.x;
    const int lane = t & 63;
    const int wave = t >> 6;
    const int wm = (wave >> 1) * 64;
    const int wn = (wave & 1) * 64;
    const int row0 = blockIdx.x * 128;
    const int col0 = blockIdx.y * 128;
    const int kc = lane >> 4;
    const int lr = lane & 15;

    f32x4 acc[4][4];
    #pragma unroll
    for (int mi = 0; mi < 4; ++mi)
        #pragma unroll
        for (int ni = 0; ni < 4; ++ni)
            acc[mi][ni] = (f32x4){0.f, 0.f, 0.f, 0.f};

    #pragma unroll
    for (int ks = 0; ks < 2; ++ks) {
        const int k0 = ks * 32 + kc * 8;
        short8v a[4], b[4];
        #pragma unroll
        for (int mi = 0; mi < 4; ++mi) {
            const int row = row0 + wm + mi * 16 + lr;
            if (row < NN)
                a[mi] = *reinterpret_cast<const short8v*>(&d0bf[(size_t)row * 64 + k0]);
            else
                a[mi] = (short8v){0, 0, 0, 0, 0, 0, 0, 0};
        }
        #pragma unroll
        for (int ni = 0; ni < 4; ++ni) {
            const int col = col0 + wn + ni * 16 + lr;
            b[ni] = *reinterpret_cast<const short8v*>(&wt2[(size_t)col * 64 + k0]);
        }
        #pragma unroll
        for (int mi = 0; mi < 4; ++mi)
            #pragma unroll
            for (int ni = 0; ni < 4; ++ni)
                acc[mi][ni] = __builtin_amdgcn_mfma_f32_16x16x32_bf16(a[mi], b[ni], acc[mi][ni], 0, 0, 0);
    }

    #pragma unroll
    for (int ni = 0; ni < 4; ++ni) {
        const int col = col0 + wn + ni * 16 + lr;
        if (col < DIN) {
            const float bv = d1b[col];
            #pragma unroll
            for (int mi = 0; mi < 4; ++mi) {
                #pragma unroll
                for (int j = 0; j < 4; ++j) {
                    const int row = row0 + wm + mi * 16 + (lane >> 4) * 4 + j;
                    if (row < NN)
                        out[ODE + (size_t)row * DIN + col] = acc[mi][ni][j] + bv;
                }
            }
        }
    }
}

extern "C" void kernel_launch(void* const* d_in, const int* in_sizes, int n_in,
                              void* d_out, int out_size, void* d_ws, size_t ws_size,
                              hipStream_t stream)
{
    const float* x       = (const float*)d_in[0];
    const void*  ei      = d_in[1];
    const float* enc0_w  = (const float*)d_in[2];
    const float* enc0_b  = (const float*)d_in[3];
    const float* enc0_g  = (const float*)d_in[4];
    const float* enc0_bb = (const float*)d_in[5];
    const float* enc0_m  = (const float*)d_in[6];
    const float* enc0_v  = (const float*)d_in[7];
    const float* enc1_w  = (const float*)d_in[8];
    const float* enc1_b  = (const float*)d_in[9];
    const float* enc1_g  = (const float*)d_in[10];
    const float* enc1_bb = (const float*)d_in[11];
    const float* enc1_m  = (const float*)d_in[12];
    const float* enc1_v  = (const float*)d_in[13];
    const float* conv_w  = (const float*)d_in[14];
    const float* conv_b  = (const float*)d_in[15];
    const float* conv_g  = (const float*)d_in[16];
    const float* conv_bb = (const float*)d_in[17];
    const float* conv_m  = (const float*)d_in[18];
    const float* conv_v  = (const float*)d_in[19];
    const float* mean_w  = (const float*)d_in[20];
    const float* mean_b  = (const float*)d_in[21];
    const float* logvar_w = (const float*)d_in[22];
    const float* logvar_b = (const float*)d_in[23];
    const float* dec0_w  = (const float*)d_in[24];
    const float* dec0_b  = (const float*)d_in[25];
    const float* dec0_g  = (const float*)d_in[26];
    const float* dec0_bb = (const float*)d_in[27];
    const float* dec0_m  = (const float*)d_in[28];
    const float* dec0_v  = (const float*)d_in[29];
    const float* dec1_w  = (const float*)d_in[30];
    const float* dec1_b  = (const float*)d_in[31];
    const float* cluster = (const float*)d_in[32];

    float* ws = (float*)d_ws;
    float* deg  = ws;                              // N
    float* feat = ws + NN;                         // 64N
    float* A    = ws + (size_t)65 * NN;            // 256N region, multi-use
    size_t base = (size_t)321 * NN;
    int*   off     = (int*)(ws + base);                        // N
    int*   cursor  = (int*)(ws + base + NN);                   // N
    int*   bsum    = (int*)(ws + base + 2 * (size_t)NN);       // 512
    int2*  csr_e   = (int2*)(ws + base + 2 * (size_t)NN + 512);            // E int2 (2E floats)
    short* wt      = (short*)(ws + base + 2 * (size_t)NN + 512 + 2 * (size_t)NE);  // 256*1024 bf16
    int*   flag    = (int*)(ws + base + 2 * (size_t)NN + 512 + 2 * (size_t)NE + 131072); // 1

    short* h1bf   = (short*)A;                      // N x 256 bf16 (A[0..128N) floats)
    short* featbf = (short*)(A + (size_t)128 * NN); // N x 64 bf16 (dead after feat_gather)
    float* aggF   = A;                              // N x 64 f32 (after h1bf dead)
    short* m2bf   = (short*)(A + (size_t)128 * NN); // N x 32 bf16 (featbf region, dead by then)
    float* agg2   = A + (size_t)32 * NN;            // N x 32 f32 (aggF dead after conv_mlp_proj)
    short* d0bf   = (short*)(A + (size_t)64 * NN);  // N x 64 bf16
    short* wt2    = wt;                             // 1024 x 64 bf16 (reuses enc0 wt)

    float* out = (float*)d_out;

    k_detect<<<1, 256, 0, stream>>>((const int*)ei, flag);
    k_deg_init<<<NB, 256, 0, stream>>>(deg);
    k_deg_accum<<<NE / 256, 256, 0, stream>>>(ei, flag, deg);

    // CSR build (interleaved int2 edges)
    k_scan1<<<NB, 256, 0, stream>>>(deg, off, bsum, cursor);
    k_scan2<<<1, 512, 0, stream>>>(bsum);
    k_scan3<<<NB, 256, 0, stream>>>(off, bsum);
    k_fill<<<NE / 256, 256, 0, stream>>>(ei, flag, deg, off, cursor, csr_e);

    // enc0 via MFMA (single pass over x, coalesced A-stage)
    k_wt<<<1024, 256, 0, stream>>>(enc0_w, wt);
    k_enc0_mfma<<<(NN + 127) / 128, 512, 0, stream>>>(x, wt, enc0_b, enc0_g, enc0_bb, enc0_m, enc0_v, h1bf);
    // dec1 weight prep (reuses wt buffer — enc0 done with it)
    k_wt2<<<256, 256, 0, stream>>>(dec1_w, wt2);

    k_enc1<<<NN / 32, 256, 0, stream>>>(h1bf, enc1_w, enc1_b, enc1_g, enc1_bb, enc1_m, enc1_v,
                                        feat, featbf, out);

    // GCN conv: aggregate bf16 feat first (linearity), then fused conv+mlp projections
    k_feat_gather<<<NN / 8, 256, 0, stream>>>((const unsigned*)featbf, deg, off, csr_e, aggF);
    k_conv_mlp_proj<<<NN / 32, 256, 0, stream>>>(aggF, conv_w, conv_b,
                                                 conv_g, conv_bb, conv_m, conv_v,
                                                 mean_w, logvar_w, m2bf);

    k_mlp_gather<<<NN / 16, 256, 0, stream>>>((const unsigned*)m2bf, deg, off, csr_e,
                                              mean_b, logvar_b, agg2);

    k_final_pre<<<NN / 8, 256, 0, stream>>>(feat, agg2, dec0_w, dec0_b, dec0_g, dec0_bb, dec0_m, dec0_v,
                                            cluster, d0bf, out);
    {
        dim3 grid((NN + 127) / 128, 8);
        k_dec1_mfma<<<grid, 256, 0, stream>>>(d0bf, wt2, dec1_b, out);
    }
}

// Round 18
// 1051.607 us; speedup vs baseline: 1.2690x; 1.0010x over previous
//
#include <hip/hip_runtime.h>
#include <hip/hip_bf16.h>

#define NN 100000
#define NE 1600000
#define DIN 1000
#define BN_EPS 1e-3f
#define NB 391   // ceil(NN/256)

// output element offsets (concat of z, mu, logvar, de_feat, q, feat_x, gnn_z) — float32 out
#define OZ  ((size_t)0)
#define OMU ((size_t)NN*80)
#define OLV ((size_t)NN*96)
#define ODE ((size_t)NN*112)
#define OQ  ((size_t)NN*1112)
#define OFX ((size_t)NN*1127)
#define OGZ ((size_t)NN*1191)

typedef __attribute__((ext_vector_type(8))) short short8v;   // 8 bf16 (4 VGPRs)
typedef __attribute__((ext_vector_type(4))) short short4v;   // 4 bf16 (2 VGPRs)
typedef __attribute__((ext_vector_type(4))) float f32x4;     // MFMA accumulator

__device__ __forceinline__ float elu_f(float x) { return x > 0.f ? x : expf(x) - 1.f; }

// fp32 -> bf16 bits, round-to-nearest-even
__device__ __forceinline__ short f2bf(float f) {
    union { float f; unsigned u; } c; c.f = f;
    unsigned r = c.u + 0x7fffu + ((c.u >> 16) & 1u);
    return (short)(r >> 16);
}
// bf16 bits -> fp32
__device__ __forceinline__ float b2f(short s) {
    union { unsigned u; float f; } c; c.u = ((unsigned)(unsigned short)s) << 16; return c.f;
}
__device__ __forceinline__ float b2f_lo(unsigned p) {
    union { unsigned u; float f; } c; c.u = p << 16; return c.f;
}
__device__ __forceinline__ float b2f_hi(unsigned p) {
    union { unsigned u; float f; } c; c.u = p & 0xffff0000u; return c.f;
}

// Edge index may arrive as int32 or int64; logical element idx in flat (2*E) array.
__device__ __forceinline__ int edge_at(const void* ei, int is64, size_t idx) {
    if (is64) return (int)((const long long*)ei)[idx];
    return ((const int*)ei)[idx];
}

// ---------------- dtype detection ----------------
__global__ __launch_bounds__(256) void k_detect(const int* __restrict__ ei, int* __restrict__ flag) {
    __shared__ int nz;
    if (threadIdx.x == 0) nz = 0;
    __syncthreads();
    for (int i = threadIdx.x; i < 2048; i += 256)
        if (ei[2 * i + 1] != 0) nz = 1;
    __syncthreads();
    if (threadIdx.x == 0) flag[0] = (nz == 0) ? 1 : 0;  // 1 => int64
}

// ---------------- degree ----------------
__global__ __launch_bounds__(256) void k_deg_init(float* __restrict__ deg) {
    int i = blockIdx.x * 256 + threadIdx.x;
    if (i < NN) deg[i] = 1.0f;
}

__global__ __launch_bounds__(256) void k_deg_accum(const void* __restrict__ ei, const int* __restrict__ flag,
                                                   float* __restrict__ deg) {
    const int is64 = flag[0];
    int e = blockIdx.x * 256 + threadIdx.x;
    if (e < NE) atomicAdd(&deg[edge_at(ei, is64, (size_t)NE + e)], 1.0f);
}

// ---------------- CSR build: exclusive scan of in-edge counts ----------------
__global__ __launch_bounds__(256) void k_scan1(const float* __restrict__ deg, int* __restrict__ off,
                                               int* __restrict__ bsum, int* __restrict__ cursor) {
    __shared__ int s[256];
    const int t = threadIdx.x;
    const int i = blockIdx.x * 256 + t;
    const int vv = (i < NN) ? ((int)deg[i]) - 1 : 0;
    if (i < NN) cursor[i] = 0;
    s[t] = vv;
    __syncthreads();
    for (int d = 1; d < 256; d <<= 1) {
        const int u = (t >= d) ? s[t - d] : 0;
        __syncthreads();
        s[t] += u;
        __syncthreads();
    }
    if (i < NN) off[i] = s[t] - vv;           // exclusive, pre-block-offset
    if (t == 255) bsum[blockIdx.x] = s[t];    // block total
}

__global__ __launch_bounds__(512) void k_scan2(int* __restrict__ bsum) {
    __shared__ int s[512];
    const int t = threadIdx.x;
    const int vv = (t < NB) ? bsum[t] : 0;
    s[t] = vv;
    __syncthreads();
    for (int d = 1; d < 512; d <<= 1) {
        const int u = (t >= d) ? s[t - d] : 0;
        __syncthreads();
        s[t] += u;
        __syncthreads();
    }
    if (t < NB) bsum[t] = s[t] - vv;          // exclusive block prefix
}

__global__ __launch_bounds__(256) void k_scan3(int* __restrict__ off, const int* __restrict__ bsum) {
    const int i = blockIdx.x * 256 + threadIdx.x;
    if (i < NN) off[i] += bsum[blockIdx.x];
}

// interleaved CSR: one int2 {src, w_bits} per edge — single 8B scatter store
__global__ __launch_bounds__(256) void k_fill(const void* __restrict__ ei, const int* __restrict__ flag,
                                              const float* __restrict__ deg, const int* __restrict__ off,
                                              int* __restrict__ cursor, int2* __restrict__ csr_e) {
    const int is64 = flag[0];
    const int e = blockIdx.x * 256 + threadIdx.x;
    if (e >= NE) return;
    const int r = edge_at(ei, is64, e);
    const int c = edge_at(ei, is64, (size_t)NE + e);
    const float w = rsqrtf(deg[r]) * rsqrtf(deg[c]);
    const int p = atomicAdd(&cursor[c], 1);
    csr_e[off[c] + p] = make_int2(r, __float_as_int(w));
}

// ---------------- enc0 weight prep: w[1000][256] f32 -> k-major bf16 granules ----------------
__global__ __launch_bounds__(256) void k_wt(const float* __restrict__ w, short* __restrict__ wt) {
    const int tid = blockIdx.x * 256 + threadIdx.x;   // 256*1024 elements
    const int c = tid >> 10;
    const int k = tid & 1023;
    wt[((size_t)(k >> 3) * 256 + c) * 8 + (k & 7)] = (k < DIN) ? f2bf(w[(size_t)k * 256 + c]) : (short)0;
}

// ---------------- dec1 weight prep: w[64][1000] f32 -> wt2[1024][64] bf16 (cols zero-padded) ----------------
__global__ __launch_bounds__(256) void k_wt2(const float* __restrict__ w, short* __restrict__ wt2) {
    const int tid = blockIdx.x * 256 + threadIdx.x;   // 1024*64 elements
    const int c = tid >> 6;
    const int k = tid & 63;
    wt2[(size_t)c * 64 + k] = (c < DIN) ? f2bf(w[(size_t)k * DIN + c]) : (short)0;
}

// ---------------- encoder L0 via MFMA: h1bf = bf16(ELU(BN(x @ w))) ----------------
// Block tile 128x256, 8 waves (2 row x 4 col), wave tile 64x64, K_STEP=32.
// DOUBLE-BUFFERED single-barrier K-loop (T3 minimum 2-phase): per iteration
// {issue ks+1 global loads -> ds_read+MFMA buf[cur] -> ds_write buf[cur^1] ->
// barrier}. Loads stay in flight across the whole MFMA phase (no barrier
// between issue and compute), so HBM latency hides under compute.
__global__ __launch_bounds__(512, 2) void k_enc0_mfma(
    const float* __restrict__ x, const short* __restrict__ wt, const float* __restrict__ bias,
    const float* __restrict__ g, const float* __restrict__ bb,
    const float* __restrict__ m, const float* __restrict__ v,
    short* __restrict__ h1bf)
{
    __shared__ short As[2][4 * 128 * 8];
    __shared__ short Bs[2][4 * 256 * 8];
    const int t = threadIdx.x;           // 0..511
    const int lane = t & 63;
    const int wave = t >> 6;             // 0..7
    const int wm = (wave >> 2) * 64;     // 0,64
    const int wn = (wave & 3) * 64;      // 0,64,128,192
    const int row0 = blockIdx.x * 128;

    f32x4 acc[4][4];
    #pragma unroll
    for (int mi = 0; mi < 4; ++mi)
        #pragma unroll
        for (int ni = 0; ni < 4; ++ni)
            acc[mi][ni] = (f32x4){0.f, 0.f, 0.f, 0.f};

    // A staging (coalesced): thread t = (row t>>3, float4-slot t&7), rows rA0, rA0+64
    const int kq = t & 7;
    const int rA0 = t >> 3;              // 0..63
    const int rA1 = rA0 + 64;            // 64..127
    const int gr0 = (row0 + rA0 < NN) ? (row0 + rA0) : (NN - 1);
    const int gr1 = (row0 + rA1 < NN) ? (row0 + rA1) : (NN - 1);
    const float* xb0 = x + (size_t)gr0 * DIN;
    const float* xb1 = x + (size_t)gr1 * DIN;
    const size_t aoff0 = (((kq >> 1) * 128) + rA0) * 8 + (kq & 1) * 4;
    const size_t aoff1 = (((kq >> 1) * 128) + rA1) * 8 + (kq & 1) * 4;

    // B staging: granules colB with kcB0 (0..1) and kcB1 (2..3)
    const int colB = t & 255;
    const int kcB0 = t >> 8;
    const int kcB1 = 2 + (t >> 8);
    const size_t boff0 = ((size_t)kcB0 * 256 + colB) * 8;
    const size_t boff1 = ((size_t)kcB1 * 256 + colB) * 8;

    const int kc = lane >> 4;    // 0..3
    const int lr = lane & 15;

    // ---- prologue: stage ks=0 into buf 0 ----
    {
        const float4 f0 = *reinterpret_cast<const float4*>(xb0 + kq * 4);
        const float4 f1 = *reinterpret_cast<const float4*>(xb1 + kq * 4);
        short4v p0, p1;
        p0[0] = f2bf(f0.x); p0[1] = f2bf(f0.y); p0[2] = f2bf(f0.z); p0[3] = f2bf(f0.w);
        p1[0] = f2bf(f1.x); p1[1] = f2bf(f1.y); p1[2] = f2bf(f1.z); p1[3] = f2bf(f1.w);
        *reinterpret_cast<short4v*>(&As[0][aoff0]) = p0;
        *reinterpret_cast<short4v*>(&As[0][aoff1]) = p1;
        *reinterpret_cast<short8v*>(&Bs[0][boff0]) =
            *reinterpret_cast<const short8v*>(&wt[((size_t)kcB0 * 256 + colB) * 8]);
        *reinterpret_cast<short8v*>(&Bs[0][boff1]) =
            *reinterpret_cast<const short8v*>(&wt[((size_t)kcB1 * 256 + colB) * 8]);
    }
    __syncthreads();

    for (int ks = 0; ks < 32; ++ks) {
        const int cur = ks & 1;
        const int nxt = cur ^ 1;
        // ---- 1) issue ks+1 global loads (no waits yet) ----
        float4 pf0, pf1;
        short8v wb0, wb1;
        const bool have_next = (ks + 1) < 32;
        bool next_a_ok = false;
        if (have_next) {
            const int kb2 = (ks + 1) * 32 + kq * 4;
            next_a_ok = (kb2 + 4 <= DIN);
            const int ko = next_a_ok ? kb2 : 0;
            pf0 = *reinterpret_cast<const float4*>(xb0 + ko);
            pf1 = *reinterpret_cast<const float4*>(xb1 + ko);
            const int gbase = (ks + 1) * 4;
            wb0 = *reinterpret_cast<const short8v*>(&wt[((size_t)(gbase + kcB0) * 256 + colB) * 8]);
            wb1 = *reinterpret_cast<const short8v*>(&wt[((size_t)(gbase + kcB1) * 256 + colB) * 8]);
        }
        // ---- 2) fragments + MFMA from buf[cur] ----
        short8v a[4], b[4];
        #pragma unroll
        for (int mi = 0; mi < 4; ++mi)
            a[mi] = *reinterpret_cast<const short8v*>(&As[cur][((size_t)kc * 128 + wm + mi * 16 + lr) * 8]);
        #pragma unroll
        for (int ni = 0; ni < 4; ++ni)
            b[ni] = *reinterpret_cast<const short8v*>(&Bs[cur][((size_t)kc * 256 + wn + ni * 16 + lr) * 8]);
        #pragma unroll
        for (int mi = 0; mi < 4; ++mi)
            #pragma unroll
            for (int ni = 0; ni < 4; ++ni)
                acc[mi][ni] = __builtin_amdgcn_mfma_f32_16x16x32_bf16(a[mi], b[ni], acc[mi][ni], 0, 0, 0);
        // ---- 3) convert + ds_write stage data into buf[nxt] ----
        if (have_next) {
            short4v p0, p1;
            if (next_a_ok) {
                p0[0] = f2bf(pf0.x); p0[1] = f2bf(pf0.y); p0[2] = f2bf(pf0.z); p0[3] = f2bf(pf0.w);
                p1[0] = f2bf(pf1.x); p1[1] = f2bf(pf1.y); p1[2] = f2bf(pf1.z); p1[3] = f2bf(pf1.w);
            } else {
                p0 = (short4v){0, 0, 0, 0};
                p1 = (short4v){0, 0, 0, 0};
            }
            *reinterpret_cast<short4v*>(&As[nxt][aoff0]) = p0;
            *reinterpret_cast<short4v*>(&As[nxt][aoff1]) = p1;
            *reinterpret_cast<short8v*>(&Bs[nxt][boff0]) = wb0;
            *reinterpret_cast<short8v*>(&Bs[nxt][boff1]) = wb1;
        }
        // ---- 4) single barrier per K-step ----
        __syncthreads();
    }

    // ---- epilogue: BN + ELU -> bf16, C/D layout col=lane&15, row=(lane>>4)*4+reg ----
    float sc[4], sh[4];
    int cols[4];
    #pragma unroll
    for (int ni = 0; ni < 4; ++ni) {
        const int col = wn + ni * 16 + lr;
        cols[ni] = col;
        const float s = rsqrtf(v[col] + BN_EPS) * g[col];
        sc[ni] = s;
        sh[ni] = (bias[col] - m[col]) * s + bb[col];
    }
    #pragma unroll
    for (int mi = 0; mi < 4; ++mi) {
        #pragma unroll
        for (int j = 0; j < 4; ++j) {
            const int row = row0 + wm + mi * 16 + (lane >> 4) * 4 + j;
            if (row < NN) {
                #pragma unroll
                for (int ni = 0; ni < 4; ++ni) {
                    const float y = acc[mi][ni][j] * sc[ni] + sh[ni];
                    h1bf[(size_t)row * 256 + cols[ni]] = f2bf(elu_f(y));
                }
            }
        }
    }
}

// ---------------- encoder L1: h1bf[N,256] @ w[256,64] + BN + ELU -> feat, featbf, out ----------------
__global__ __launch_bounds__(256) void k_enc1(
    const short* __restrict__ h1bf, const float* __restrict__ w, const float* __restrict__ bias,
    const float* __restrict__ g, const float* __restrict__ bb,
    const float* __restrict__ m, const float* __restrict__ v,
    float* __restrict__ feat, short* __restrict__ featbf, float* __restrict__ out)
{
    __shared__ short hs[32 * 256];
    const int t = threadIdx.x;
    const int row0 = blockIdx.x * 32;
    const int j0 = t & 31;
    const int r0 = (t >> 5) * 4;
    float acc[4][2] = {};
    for (int idx = t; idx < 1024; idx += 256) {
        const int r = idx >> 5, c8 = idx & 31;
        *reinterpret_cast<short8v*>(&hs[r * 256 + c8 * 8]) =
            *reinterpret_cast<const short8v*>(&h1bf[(size_t)(row0 + r) * 256 + c8 * 8]);
    }
    __syncthreads();
    #pragma unroll 1
    for (int k = 0; k < 256; k += 8) {
        float wv[8][2];
        #pragma unroll
        for (int kk = 0; kk < 8; ++kk) {
            wv[kk][0] = w[(k + kk) * 64 + j0];
            wv[kk][1] = w[(k + kk) * 64 + j0 + 32];
        }
        #pragma unroll
        for (int r = 0; r < 4; ++r) {
            const short8v hv = *reinterpret_cast<const short8v*>(&hs[(r0 + r) * 256 + k]);
            #pragma unroll
            for (int kk = 0; kk < 8; ++kk) {
                const float xa = b2f(hv[kk]);
                acc[r][0] = fmaf(xa, wv[kk][0], acc[r][0]);
                acc[r][1] = fmaf(xa, wv[kk][1], acc[r][1]);
            }
        }
    }
    #pragma unroll
    for (int c = 0; c < 2; ++c) {
        const int j = j0 + 32 * c;
        const float sc = rsqrtf(v[j] + BN_EPS) * g[j];
        const float sh = (bias[j] - m[j]) * sc + bb[j];
        #pragma unroll
        for (int r = 0; r < 4; ++r) {
            const size_t rowi = row0 + r0 + r;
            const float y = elu_f(acc[r][c] * sc + sh);
            feat[rowi * 64 + j] = y;
            featbf[rowi * 64 + j] = f2bf(y);
            out[OFX + rowi * 64 + j] = y;
            out[OZ + rowi * 80 + j] = y;
        }
    }
}

// ---------------- GCN: gather featbf (64-dim bf16) FIRST (linearity) ----------------
__global__ __launch_bounds__(256) void k_feat_gather(
    const unsigned* __restrict__ featp, const float* __restrict__ deg,
    const int* __restrict__ off, const int2* __restrict__ csr_e,
    float* __restrict__ aggF)
{
    const int t = threadIdx.x;
    const int node = blockIdx.x * 8 + (t >> 5);   // grid = NN/8
    const int lane = t & 31;                       // feats 2*lane, 2*lane+1
    const float dg = deg[node];
    const float dinv = 1.0f / dg;
    const unsigned ps = featp[(size_t)node * 32 + lane];
    float a0 = b2f_lo(ps) * dinv;
    float a1 = b2f_hi(ps) * dinv;
    const int beg = off[node];
    const int end = beg + ((int)dg - 1);
    for (int s = beg; s < end; ++s) {
        const int2 e = csr_e[s];
        const float w = __int_as_float(e.y);
        const unsigned p = featp[(size_t)e.x * 32 + lane];
        a0 = fmaf(b2f_lo(p), w, a0);
        a1 = fmaf(b2f_hi(p), w, a1);
    }
    float2 o; o.x = a0; o.y = a1;
    *reinterpret_cast<float2*>(&aggF[(size_t)node * 64 + lane * 2]) = o;
}

// ---------------- fused conv+mlp projection: aggF -> (cmat in LDS) -> m2bf ----------------
__global__ __launch_bounds__(256) void k_conv_mlp_proj(
    const float* __restrict__ aggF, const float* __restrict__ w, const float* __restrict__ cb,
    const float* __restrict__ g, const float* __restrict__ bb,
    const float* __restrict__ m, const float* __restrict__ v,
    const float* __restrict__ mw, const float* __restrict__ lw,
    short* __restrict__ m2bf)
{
    __shared__ float fs[32 * 64];
    __shared__ float cs[32 * 128];
    const int t = threadIdx.x;
    const int row0 = blockIdx.x * 32;
    // ---- phase 1: conv GEMM (K=64) + bias + BN + ReLU -> cs ----
    {
        const int j0 = t & 63;
        const int r0 = (t >> 6) * 8;
        float acc[8][2] = {};
        for (int idx = t; idx < 512; idx += 256) {
            const int r = idx >> 4, c4 = idx & 15;
            *reinterpret_cast<float4*>(&fs[r * 64 + c4 * 4]) =
                *reinterpret_cast<const float4*>(&aggF[(size_t)(row0 + r) * 64 + c4 * 4]);
        }
        __syncthreads();
        #pragma unroll 1
        for (int k = 0; k < 64; k += 4) {
            float wv[4][2];
            #pragma unroll
            for (int kk = 0; kk < 4; ++kk) {
                wv[kk][0] = w[(k + kk) * 128 + j0];
                wv[kk][1] = w[(k + kk) * 128 + j0 + 64];
            }
            #pragma unroll
            for (int r = 0; r < 8; ++r) {
                const float4 xv = *reinterpret_cast<const float4*>(&fs[(r0 + r) * 64 + k]);
                const float xa[4] = {xv.x, xv.y, xv.z, xv.w};
                #pragma unroll
                for (int kk = 0; kk < 4; ++kk) {
                    acc[r][0] = fmaf(xa[kk], wv[kk][0], acc[r][0]);
                    acc[r][1] = fmaf(xa[kk], wv[kk][1], acc[r][1]);
                }
            }
        }
        #pragma unroll
        for (int c = 0; c < 2; ++c) {
            const int j = j0 + 64 * c;
            const float sc = rsqrtf(v[j] + BN_EPS) * g[j];
            const float sh = bb[j] - m[j] * sc;
            const float cbj = cb[j];
            #pragma unroll
            for (int r = 0; r < 8; ++r) {
                const float val = acc[r][c] + cbj;
                cs[(r0 + r) * 128 + j] = fmaxf(fmaf(val, sc, sh), 0.f);
            }
        }
    }
    __syncthreads();
    // ---- phase 2: mlp GEMM (K=128) from cs -> m2bf ----
    {
        const int j0 = t & 15;
        const int r0 = (t >> 4) * 2;
        float acc[2][2] = {};
        #pragma unroll 1
        for (int k = 0; k < 128; k += 4) {
            float wv[4][2];
            #pragma unroll
            for (int kk = 0; kk < 4; ++kk) {
                wv[kk][0] = mw[(k + kk) * 16 + j0];
                wv[kk][1] = lw[(k + kk) * 16 + j0];
            }
            #pragma unroll
            for (int r = 0; r < 2; ++r) {
                const float4 xv = *reinterpret_cast<const float4*>(&cs[(r0 + r) * 128 + k]);
                const float xa[4] = {xv.x, xv.y, xv.z, xv.w};
                #pragma unroll
                for (int kk = 0; kk < 4; ++kk) {
                    acc[r][0] = fmaf(xa[kk], wv[kk][0], acc[r][0]);
                    acc[r][1] = fmaf(xa[kk], wv[kk][1], acc[r][1]);
                }
            }
        }
        #pragma unroll
        for (int r = 0; r < 2; ++r) {
            const size_t rowi = row0 + r0 + r;
            m2bf[rowi * 32 + j0] = f2bf(acc[r][0]);
            m2bf[rowi * 32 + 16 + j0] = f2bf(acc[r][1]);
        }
    }
}

// ---------------- CSR gather mean|logvar (32 bf16 feats) + self-loop + bias ----------------
__global__ __launch_bounds__(256) void k_mlp_gather(
    const unsigned* __restrict__ m2p, const float* __restrict__ deg,
    const int* __restrict__ off, const int2* __restrict__ csr_e,
    const float* __restrict__ mb, const float* __restrict__ lb,
    float* __restrict__ agg2)
{
    const int t = threadIdx.x;
    const int node = blockIdx.x * 16 + (t >> 4);   // grid = NN/16
    const int lane = t & 15;                        // feats 2*lane, 2*lane+1
    const int f0 = lane * 2, f1 = lane * 2 + 1;
    const float dg = deg[node];
    const float dinv = 1.0f / dg;
    const float b0 = (f0 < 16) ? mb[f0] : lb[f0 - 16];
    const float b1 = (f1 < 16) ? mb[f1] : lb[f1 - 16];
    const unsigned ps = m2p[(size_t)node * 16 + lane];
    float a0 = fmaf(b2f_lo(ps), dinv, b0);
    float a1 = fmaf(b2f_hi(ps), dinv, b1);
    const int beg = off[node];
    const int end = beg + ((int)dg - 1);
    for (int s = beg; s < end; ++s) {
        const int2 e = csr_e[s];
        const float w = __int_as_float(e.y);
        const unsigned p = m2p[(size_t)e.x * 16 + lane];
        a0 = fmaf(b2f_lo(p), w, a0);
        a1 = fmaf(b2f_hi(p), w, a1);
    }
    float2 o; o.x = a0; o.y = a1;
    *reinterpret_cast<float2*>(&agg2[(size_t)node * 32 + lane * 2]) = o;
}

// ---------------- finalize pre: mu/logvar/z writes, dec0 -> d0bf (bf16), q ----------------
__global__ __launch_bounds__(256) void k_final_pre(
    const float* __restrict__ feat, const float* __restrict__ agg2,
    const float* __restrict__ d0w, const float* __restrict__ d0b,
    const float* __restrict__ g, const float* __restrict__ bb,
    const float* __restrict__ m, const float* __restrict__ v,
    const float* __restrict__ cluster,
    short* __restrict__ d0bf,
    float* __restrict__ out)
{
    __shared__ float zs[8][80];
    __shared__ float qs[8][15];
    const int t = threadIdx.x;
    const int row0 = blockIdx.x * 8;

    for (int idx = t; idx < 512; idx += 256) {
        const int r = idx >> 6, k = idx & 63;
        zs[r][k] = feat[(size_t)(row0 + r) * 64 + k];
    }
    if (t < 128) {
        const int r = t >> 4, k = t & 15;
        const size_t rowi = row0 + r;
        const float muv = agg2[rowi * 32 + k];
        const float lv = agg2[rowi * 32 + 16 + k];
        zs[r][64 + k] = muv;
        out[OMU + rowi * 16 + k] = muv;
        out[OGZ + rowi * 16 + k] = muv;
        out[OZ + rowi * 80 + 64 + k] = muv;
        out[OLV + rowi * 16 + k] = lv;
    }
    __syncthreads();

    // dec0: d0 = ELU(BN(z @ d0w + d0b)) -> bf16 global
    for (int idx = t; idx < 512; idx += 256) {
        const int r = idx >> 6, n = idx & 63;
        float acc = 0.f;
        #pragma unroll
        for (int k = 0; k < 80; k += 4) {
            const float4 zv = *reinterpret_cast<const float4*>(&zs[r][k]);
            acc = fmaf(zv.x, d0w[(k + 0) * 64 + n], acc);
            acc = fmaf(zv.y, d0w[(k + 1) * 64 + n], acc);
            acc = fmaf(zv.z, d0w[(k + 2) * 64 + n], acc);
            acc = fmaf(zv.w, d0w[(k + 3) * 64 + n], acc);
        }
        acc += d0b[n];
        const float sc = rsqrtf(v[n] + BN_EPS) * g[n];
        const float y = elu_f((acc - m[n]) * sc + bb[n]);
        d0bf[(size_t)(row0 + r) * 64 + n] = f2bf(y);
    }

    // student-t q
    if (t < 120) {
        const int r = t / 15, c = t % 15;
        float zz = 0.f, cc = 0.f, dot = 0.f;
        #pragma unroll 1
        for (int k = 0; k < 80; ++k) {
            const float zv = zs[r][k];
            const float cv = cluster[c * 80 + k];
            zz = fmaf(zv, zv, zz);
            cc = fmaf(cv, cv, cc);
            dot = fmaf(zv, cv, dot);
        }
        const float dist = fmaxf(zz + cc - 2.f * dot, 0.f);
        qs[r][c] = powf(1.0f / (1.0f + dist / 0.9f + 1e-8f), 0.95f);
    }
    __syncthreads();
    if (t < 120) {
        const int r = t / 15, c = t % 15;
        float s = 0.f;
        #pragma unroll
        for (int c2 = 0; c2 < 15; ++c2) s += qs[r][c2];
        out[OQ + (size_t)(row0 + r) * 15 + c] = qs[r][c] / s;
    }
}

// ---------------- dec1 via MFMA: de_feat = d0 @ d1w + d1b ----------------
__global__ __launch_bounds__(256) void k_dec1_mfma(
    const short* __restrict__ d0bf, const short* __restrict__ wt2,
    const float* __restrict__ d1b, float* __restrict__ out)
{
    const int t = threadIdx.x;
    const int lane = t & 63;
    const int wave = t >> 6;
    const int wm = (wave >> 1) * 64;
    const int wn = (wave & 1) * 64;
    const int row0 = blockIdx.x * 128;
    const int col0 = blockIdx.y * 128;
    const int kc = lane >> 4;
    const int lr = lane & 15;

    f32x4 acc[4][4];
    #pragma unroll
    for (int mi = 0; mi < 4; ++mi)
        #pragma unroll
        for (int ni = 0; ni < 4; ++ni)
            acc[mi][ni] = (f32x4){0.f, 0.f, 0.f, 0.f};

    #pragma unroll
    for (int ks = 0; ks < 2; ++ks) {
        const int k0 = ks * 32 + kc * 8;
        short8v a[4], b[4];
        #pragma unroll
        for (int mi = 0; mi < 4; ++mi) {
            const int row = row0 + wm + mi * 16 + lr;
            if (row < NN)
                a[mi] = *reinterpret_cast<const short8v*>(&d0bf[(size_t)row * 64 + k0]);
            else
                a[mi] = (short8v){0, 0, 0, 0, 0, 0, 0, 0};
        }
        #pragma unroll
        for (int ni = 0; ni < 4; ++ni) {
            const int col = col0 + wn + ni * 16 + lr;
            b[ni] = *reinterpret_cast<const short8v*>(&wt2[(size_t)col * 64 + k0]);
        }
        #pragma unroll
        for (int mi = 0; mi < 4; ++mi)
            #pragma unroll
            for (int ni = 0; ni < 4; ++ni)
                acc[mi][ni] = __builtin_amdgcn_mfma_f32_16x16x32_bf16(a[mi], b[ni], acc[mi][ni], 0, 0, 0);
    }

    #pragma unroll
    for (int ni = 0; ni < 4; ++ni) {
        const int col = col0 + wn + ni * 16 + lr;
        if (col < DIN) {
            const float bv = d1b[col];
            #pragma unroll
            for (int mi = 0; mi < 4; ++mi) {
                #pragma unroll
                for (int j = 0; j < 4; ++j) {
                    const int row = row0 + wm + mi * 16 + (lane >> 4) * 4 + j;
                    if (row < NN)
                        out[ODE + (size_t)row * DIN + col] = acc[mi][ni][j] + bv;
                }
            }
        }
    }
}

extern "C" void kernel_launch(void* const* d_in, const int* in_sizes, int n_in,
                              void* d_out, int out_size, void* d_ws, size_t ws_size,
                              hipStream_t stream)
{
    const float* x       = (const float*)d_in[0];
    const void*  ei      = d_in[1];
    const float* enc0_w  = (const float*)d_in[2];
    const float* enc0_b  = (const float*)d_in[3];
    const float* enc0_g  = (const float*)d_in[4];
    const float* enc0_bb = (const float*)d_in[5];
    const float* enc0_m  = (const float*)d_in[6];
    const float* enc0_v  = (const float*)d_in[7];
    const float* enc1_w  = (const float*)d_in[8];
    const float* enc1_b  = (const float*)d_in[9];
    const float* enc1_g  = (const float*)d_in[10];
    const float* enc1_bb = (const float*)d_in[11];
    const float* enc1_m  = (const float*)d_in[12];
    const float* enc1_v  = (const float*)d_in[13];
    const float* conv_w  = (const float*)d_in[14];
    const float* conv_b  = (const float*)d_in[15];
    const float* conv_g  = (const float*)d_in[16];
    const float* conv_bb = (const float*)d_in[17];
    const float* conv_m  = (const float*)d_in[18];
    const float* conv_v  = (const float*)d_in[19];
    const float* mean_w  = (const float*)d_in[20];
    const float* mean_b  = (const float*)d_in[21];
    const float* logvar_w = (const float*)d_in[22];
    const float* logvar_b = (const float*)d_in[23];
    const float* dec0_w  = (const float*)d_in[24];
    const float* dec0_b  = (const float*)d_in[25];
    const float* dec0_g  = (const float*)d_in[26];
    const float* dec0_bb = (const float*)d_in[27];
    const float* dec0_m  = (const float*)d_in[28];
    const float* dec0_v  = (const float*)d_in[29];
    const float* dec1_w  = (const float*)d_in[30];
    const float* dec1_b  = (const float*)d_in[31];
    const float* cluster = (const float*)d_in[32];

    float* ws = (float*)d_ws;
    float* deg  = ws;                              // N
    float* feat = ws + NN;                         // 64N
    float* A    = ws + (size_t)65 * NN;            // 256N region, multi-use
    size_t base = (size_t)321 * NN;
    int*   off     = (int*)(ws + base);                        // N
    int*   cursor  = (int*)(ws + base + NN);                   // N
    int*   bsum    = (int*)(ws + base + 2 * (size_t)NN);       // 512
    int2*  csr_e   = (int2*)(ws + base + 2 * (size_t)NN + 512);            // E int2 (2E floats)
    short* wt      = (short*)(ws + base + 2 * (size_t)NN + 512 + 2 * (size_t)NE);  // 256*1024 bf16
    int*   flag    = (int*)(ws + base + 2 * (size_t)NN + 512 + 2 * (size_t)NE + 131072); // 1

    short* h1bf   = (short*)A;                      // N x 256 bf16 (A[0..128N) floats)
    short* featbf = (short*)(A + (size_t)128 * NN); // N x 64 bf16 (dead after feat_gather)
    float* aggF   = A;                              // N x 64 f32 (after h1bf dead)
    short* m2bf   = (short*)(A + (size_t)128 * NN); // N x 32 bf16 (featbf region, dead by then)
    float* agg2   = A + (size_t)32 * NN;            // N x 32 f32 (aggF dead after conv_mlp_proj)
    short* d0bf   = (short*)(A + (size_t)64 * NN);  // N x 64 bf16
    short* wt2    = wt;                             // 1024 x 64 bf16 (reuses enc0 wt)

    float* out = (float*)d_out;

    k_detect<<<1, 256, 0, stream>>>((const int*)ei, flag);
    k_deg_init<<<NB, 256, 0, stream>>>(deg);
    k_deg_accum<<<NE / 256, 256, 0, stream>>>(ei, flag, deg);

    // CSR build (interleaved int2 edges)
    k_scan1<<<NB, 256, 0, stream>>>(deg, off, bsum, cursor);
    k_scan2<<<1, 512, 0, stream>>>(bsum);
    k_scan3<<<NB, 256, 0, stream>>>(off, bsum);
    k_fill<<<NE / 256, 256, 0, stream>>>(ei, flag, deg, off, cursor, csr_e);

    // enc0 via MFMA (single pass over x, dbuf single-barrier K-loop)
    k_wt<<<1024, 256, 0, stream>>>(enc0_w, wt);
    k_enc0_mfma<<<(NN + 127) / 128, 512, 0, stream>>>(x, wt, enc0_b, enc0_g, enc0_bb, enc0_m, enc0_v, h1bf);
    // dec1 weight prep (reuses wt buffer — enc0 done with it)
    k_wt2<<<256, 256, 0, stream>>>(dec1_w, wt2);

    k_enc1<<<NN / 32, 256, 0, stream>>>(h1bf, enc1_w, enc1_b, enc1_g, enc1_bb, enc1_m, enc1_v,
                                        feat, featbf, out);

    // GCN conv: aggregate bf16 feat first (linearity), then fused conv+mlp projections
    k_feat_gather<<<NN / 8, 256, 0, stream>>>((const unsigned*)featbf, deg, off, csr_e, aggF);
    k_conv_mlp_proj<<<NN / 32, 256, 0, stream>>>(aggF, conv_w, conv_b,
                                                 conv_g, conv_bb, conv_m, conv_v,
                                                 mean_w, logvar_w, m2bf);

    k_mlp_gather<<<NN / 16, 256, 0, stream>>>((const unsigned*)m2bf, deg, off, csr_e,
                                              mean_b, logvar_b, agg2);

    k_final_pre<<<NN / 8, 256, 0, stream>>>(feat, agg2, dec0_w, dec0_b, dec0_g, dec0_bb, dec0_m, dec0_v,
                                            cluster, d0bf, out);
    {
        dim3 grid((NN + 127) / 128, 8);
        k_dec1_mfma<<<grid, 256, 0, stream>>>(d0bf, wt2, dec1_b, out);
    }
}